// Round 12
// baseline (3716.468 us; speedup 1.0000x reference)
//
#include <hip/hip_runtime.h>
#include <math.h>

#define N_MEM 100000
#define NP    100352      // 98 * 1024 (padded)
#define JBLK  1024
#define NJB   98
#define QCAP  1024        // per-query survivor buffer (expected ~390)
#define NCAND 128         // max re-rank set size

__device__ __forceinline__ float softplusf_(float x){ return log1pf(expf(x)); }

__device__ __forceinline__ double wave_sum_d(double v){
  #pragma unroll
  for (int o=32;o;o>>=1) v += __shfl_xor(v, o, 64);
  return v;
}
__device__ __forceinline__ int wave_sum_i(int v){
  #pragma unroll
  for (int o=32;o;o>>=1) v += __shfl_xor(v, o, 64);
  return v;
}

// argmax carrying (value, global-index tie-break, position meta)
__device__ __forceinline__ void wave_argmax3(float& v, int& j, int& p){
  #pragma unroll
  for (int o=32;o;o>>=1){
    float ov = __shfl_xor(v, o, 64);
    int   oj = __shfl_xor(j, o, 64);
    int   op = __shfl_xor(p, o, 64);
    if (ov > v || (ov == v && oj < j)) { v = ov; j = oj; p = op; }
  }
}

// full ascending bitonic sort across 64 lanes; lane 48 = 16th-largest
__device__ __forceinline__ float bitonic_sort64(float v, int lane){
  #pragma unroll
  for (int k=2;k<=64;k<<=1){
    #pragma unroll
    for (int j=k>>1;j>0;j>>=1){
      float o = __shfl_xor(v, j, 64);
      float mn = fminf(v,o), mx = fmaxf(v,o);
      bool upper = (lane & j) != 0;
      bool asc   = ((lane & k) == 0);
      v = (upper == asc) ? mx : mn;
    }
  }
  return v;
}

// 16q x 4j score accumulation over 64 d; per-(q,j) chain sequential in d
// (bit-identical ordering shared by k_tau and k3)
#define SCORE_LOOP_16x4() { \
  _Pragma("unroll 4") \
  for (int d=0; d<64; d++){ \
    float4 mv4 = *(const float4*)(rowbase + (size_t)d*NP); \
    const float* qp_ = qs + d*16; \
    float4 qv0 = *(const float4*)qp_; \
    float4 qv1 = *(const float4*)(qp_+4); \
    float4 qv2 = *(const float4*)(qp_+8); \
    float4 qv3 = *(const float4*)(qp_+12); \
    float qarr[16]={qv0.x,qv0.y,qv0.z,qv0.w,qv1.x,qv1.y,qv1.z,qv1.w, \
                    qv2.x,qv2.y,qv2.z,qv2.w,qv3.x,qv3.y,qv3.z,qv3.w}; \
    float marr[4]={mv4.x,mv4.y,mv4.z,mv4.w}; \
    _Pragma("unroll") \
    for (int qi_=0;qi_<16;qi_++){ \
      _Pragma("unroll") \
      for (int jj_=0;jj_<4;jj_++) s[qi_][jj_] = fmaf(qarr[qi_], marr[jj_], s[qi_][jj_]); \
    } \
  } }

// qs staging: qs[d*16+qi] = qw[(q0+qi)*64+d]
#define STAGE_QS() { \
  for (int i=t; i<1024; i+=256){ \
    int qi_ = i & 15, d_ = i >> 4; \
    qs[i] = qw[(q0+qi_)*64 + d_]; \
  } }

// ---------------- K1: memory embeddings -> mwT (64 x NP), mm (fp32 stream path)
__global__ __launch_bounds__(128) void k1_mem(
    const float* __restrict__ mi,
    const float* __restrict__ w1, const float* __restrict__ b1,
    const float* __restrict__ w2, const float* __restrict__ b2,
    const float* __restrict__ fw,
    float* __restrict__ mwT, float* __restrict__ mm)
{
  __shared__ float xs[64*128];
  int t = threadIdx.x;
  int j = blockIdx.x*128 + t;
  bool real = (j < N_MEM);
  {
    const float4* xp = (const float4*)(mi + (size_t)(real ? j : 0)*64);
    #pragma unroll
    for (int k=0;k<16;k++){
      float4 v = xp[k];
      xs[(4*k+0)*128 + t] = v.x;
      xs[(4*k+1)*128 + t] = v.y;
      xs[(4*k+2)*128 + t] = v.z;
      xs[(4*k+3)*128 + t] = v.w;
    }
  }
  float h[64];
  #pragma unroll
  for (int e=0;e<64;e++) h[e] = b1[e];
  for (int d=0; d<64; d++){
    float xv = xs[d*128 + t];
    #pragma unroll
    for (int e=0;e<64;e++) h[e] = fmaf(xv, w1[d*64+e], h[e]);
  }
  #pragma unroll
  for (int e=0;e<64;e++){ h[e] = fmaxf(h[e], 0.f); xs[e*128 + t] = h[e]; }
  float o[64];
  #pragma unroll
  for (int e=0;e<64;e++) o[e] = b2[e];
  for (int d=0; d<64; d++){
    float hv = xs[d*128 + t];
    #pragma unroll
    for (int e=0;e<64;e++) o[e] = fmaf(hv, w2[d*64+e], o[e]);
  }
  float s2 = 0.f;
  #pragma unroll
  for (int e=0;e<64;e++){
    float sw = sqrtf(softplusf_(fw[e]) + 1e-9f);
    float v = real ? o[e]*sw : 0.f;
    s2 = fmaf(v, v, s2);
    mwT[(size_t)e*NP + j] = v;
  }
  mm[j] = real ? s2 : 3.0e38f;
}

// ---------------- K2: per-query f64 embedding/global/gate (ILP-4 chains); zero qcnt
__global__ __launch_bounds__(64) void k2_query(
  const float* __restrict__ x,
  const float* __restrict__ le_w1, const float* __restrict__ le_b1,
  const float* __restrict__ le_w2, const float* __restrict__ le_b2,
  const float* __restrict__ fw,
  const float* __restrict__ ge_w1, const float* __restrict__ ge_b1,
  const float* __restrict__ ge_w2, const float* __restrict__ ge_b2,
  const float* __restrict__ ge_w3, const float* __restrict__ ge_b3,
  const float* __restrict__ gr_w1, const float* __restrict__ gr_b1,
  const float* __restrict__ gr_w2, const float* __restrict__ gr_b2,
  const float* __restrict__ ga_w1, const float* __restrict__ ga_b1,
  const float* __restrict__ ga_w2, const float* __restrict__ ga_b2,
  float* __restrict__ qwf, double* __restrict__ qwd,
  double* __restrict__ qqd, double* __restrict__ ggd, double* __restrict__ gpd,
  int* __restrict__ qcnt)
{
  int l = threadIdx.x, q = blockIdx.x;
  if (l==0) qcnt[q] = 0;
  __shared__ double xs[64], qe[64], h1[128], t1[64], t2[64];
  xs[l] = (double)x[q*64+l];
  __syncthreads();
  double a0,a1,a2,a3,a;
  a0=a1=a2=a3=0.0;
  for (int d=0; d<64; d+=4){
    a0 = fma(xs[d  ], (double)le_w1[(d  )*64+l], a0);
    a1 = fma(xs[d+1], (double)le_w1[(d+1)*64+l], a1);
    a2 = fma(xs[d+2], (double)le_w1[(d+2)*64+l], a2);
    a3 = fma(xs[d+3], (double)le_w1[(d+3)*64+l], a3);
  }
  a = ((a0+a1)+(a2+a3)) + (double)le_b1[l];
  t1[l] = a > 0.0 ? a : 0.0;
  __syncthreads();
  a0=a1=a2=a3=0.0;
  for (int d=0; d<64; d+=4){
    a0 = fma(t1[d  ], (double)le_w2[(d  )*64+l], a0);
    a1 = fma(t1[d+1], (double)le_w2[(d+1)*64+l], a1);
    a2 = fma(t1[d+2], (double)le_w2[(d+2)*64+l], a2);
    a3 = fma(t1[d+3], (double)le_w2[(d+3)*64+l], a3);
  }
  a = ((a0+a1)+(a2+a3)) + (double)le_b2[l];
  qe[l] = a;
  double sw = sqrt(log1p(exp((double)fw[l])) + 1e-9);
  double qv = a * sw;
  qwd[q*64+l] = qv;
  qwf[q*64+l] = (float)qv;
  double ss = wave_sum_d(qv*qv);
  if (l==0) qqd[q] = ss;
  double b0=0,b1v=0,c0=0,c1=0;
  for (int d=0; d<64; d+=2){
    double x0 = xs[d], x1 = xs[d+1];
    b0  = fma(x0, (double)ge_w1[(d  )*128+l],    b0);
    b1v = fma(x1, (double)ge_w1[(d+1)*128+l],    b1v);
    c0  = fma(x0, (double)ge_w1[(d  )*128+64+l], c0);
    c1  = fma(x1, (double)ge_w1[(d+1)*128+64+l], c1);
  }
  a = (b0+b1v) + (double)ge_b1[l];
  double c = (c0+c1) + (double)ge_b1[64+l];
  h1[l] = a>0.0?a:0.0; h1[64+l] = c>0.0?c:0.0;
  __syncthreads();
  a0=a1=a2=a3=0.0;
  for (int d=0; d<128; d+=4){
    a0 = fma(h1[d  ], (double)ge_w2[(d  )*64+l], a0);
    a1 = fma(h1[d+1], (double)ge_w2[(d+1)*64+l], a1);
    a2 = fma(h1[d+2], (double)ge_w2[(d+2)*64+l], a2);
    a3 = fma(h1[d+3], (double)ge_w2[(d+3)*64+l], a3);
  }
  a = ((a0+a1)+(a2+a3)) + (double)ge_b2[l];
  __syncthreads();
  t1[l] = a>0.0?a:0.0;
  __syncthreads();
  a0=a1=a2=a3=0.0;
  for (int d=0; d<64; d+=4){
    a0 = fma(t1[d  ], (double)ge_w3[(d  )*64+l], a0);
    a1 = fma(t1[d+1], (double)ge_w3[(d+1)*64+l], a1);
    a2 = fma(t1[d+2], (double)ge_w3[(d+2)*64+l], a2);
    a3 = fma(t1[d+3], (double)ge_w3[(d+3)*64+l], a3);
  }
  a = ((a0+a1)+(a2+a3)) + (double)ge_b3[l];
  t2[l] = a;                // global_repr
  __syncthreads();
  a0=a1=a2=a3=0.0;
  for (int d=0; d<64; d+=4){
    a0 = fma(t2[d  ], (double)gr_w1[(d  )*64+l], a0);
    a1 = fma(t2[d+1], (double)gr_w1[(d+1)*64+l], a1);
    a2 = fma(t2[d+2], (double)gr_w1[(d+2)*64+l], a2);
    a3 = fma(t2[d+3], (double)gr_w1[(d+3)*64+l], a3);
  }
  a = ((a0+a1)+(a2+a3)) + (double)gr_b1[l];
  __syncthreads();
  t1[l] = a>0.0?a:0.0;
  __syncthreads();
  if (l < 8){
    a0=a1=a2=a3=0.0;
    for (int d=0; d<64; d+=4){
      a0 = fma(t1[d  ], (double)gr_w2[(d  )*8+l], a0);
      a1 = fma(t1[d+1], (double)gr_w2[(d+1)*8+l], a1);
      a2 = fma(t1[d+2], (double)gr_w2[(d+2)*8+l], a2);
      a3 = fma(t1[d+3], (double)gr_w2[(d+3)*8+l], a3);
    }
    gpd[q*8+l] = ((a0+a1)+(a2+a3)) + (double)gr_b2[l];
  }
  a0=a1=a2=a3=0.0;
  for (int d=0; d<64; d+=4){
    a0 = fma(t2[d  ], (double)ga_w1[(d  )*64+l], a0);
    a1 = fma(t2[d+1], (double)ga_w1[(d+1)*64+l], a1);
    a2 = fma(t2[d+2], (double)ga_w1[(d+2)*64+l], a2);
    a3 = fma(t2[d+3], (double)ga_w1[(d+3)*64+l], a3);
  }
  for (int d=0; d<64; d+=4){
    a0 = fma(qe[d  ], (double)ga_w1[(64+d  )*64+l], a0);
    a1 = fma(qe[d+1], (double)ga_w1[(64+d+1)*64+l], a1);
    a2 = fma(qe[d+2], (double)ga_w1[(64+d+2)*64+l], a2);
    a3 = fma(qe[d+3], (double)ga_w1[(64+d+3)*64+l], a3);
  }
  a = ((a0+a1)+(a2+a3)) + (double)ga_b1[l];
  a = a>0.0?a:0.0;
  double p = wave_sum_d(a * (double)ga_w2[l]);
  if (l==0) ggd[q] = 1.0/(1.0 + exp(-(p + (double)ga_b2[0])));
}

// ---------------- K_tau: dump sample scores (j in [0,4096)) bit-identical to k3
// block: 16 queries x 1024 j (wave w covers j-slice w*256)
__global__ __launch_bounds__(256, 8) void k_tau(
    const float* __restrict__ mwT, const float* __restrict__ mm,
    const float* __restrict__ qw, float* __restrict__ ssc)
{
  int t = threadIdx.x, w = t>>6, lane = t&63;
  int q0 = blockIdx.x*16;
  int jb = blockIdx.y*JBLK;
  __shared__ float qs[1024];
  STAGE_QS();
  __syncthreads();
  int jw = jb + w*256 + 4*lane;
  const float* rowbase = mwT + jw;
  float s[16][4];
  #pragma unroll
  for (int a=0;a<16;a++){
    #pragma unroll
    for (int b=0;b<4;b++) s[a][b]=0.f;
  }
  SCORE_LOOP_16x4();
  float4 mmv4 = *(const float4*)(mm + jw);
  float mmv[4] = {mmv4.x, mmv4.y, mmv4.z, mmv4.w};
  #pragma unroll
  for (int qi=0;qi<16;qi++){
    int qg = q0 + qi;
    float4 o0;
    o0.x = 2.f*s[qi][0]-mmv[0]; o0.y = 2.f*s[qi][1]-mmv[1];
    o0.z = 2.f*s[qi][2]-mmv[2]; o0.w = 2.f*s[qi][3]-mmv[3];
    *(float4*)(ssc + (size_t)qg*4096 + jw) = o0;
  }
}

// ---------------- K_tau_sel: exact 16th-largest of the 4096 sample scores per query
__global__ __launch_bounds__(256) void k_tau_sel(
    const float* __restrict__ ssc, float* __restrict__ tau)
{
  int t = threadIdx.x, w = t>>6, l = t&63, q = blockIdx.x;
  __shared__ unsigned su[4096];
  __shared__ int rs[4];
  const float* base = ssc + (size_t)q*4096;
  for (int i=t; i<4096; i+=256){
    unsigned f = __float_as_uint(base[i]);
    su[i] = f ^ ((f >> 31) ? 0xFFFFFFFFu : 0x80000000u);   // monotone key
  }
  __syncthreads();
  unsigned T = 0u;
  for (int b=31; b>=0; b--){
    unsigned cand = T | (1u<<b);
    int c = 0;
    for (int i=t; i<4096; i+=256) c += (su[i] >= cand) ? 1 : 0;
    c = wave_sum_i(c);
    if (l==0) rs[w] = c;
    __syncthreads();
    int tot = rs[0]+rs[1]+rs[2]+rs[3];
    if (tot >= 16) T = cand;
    __syncthreads();
  }
  if (t==0){
    unsigned f = (T & 0x80000000u) ? (T ^ 0x80000000u) : ~T;
    tau[q] = __uint_as_float(f);
  }
}

// ---------------- K3: all 98 j-blocks, filter >= tau - margin, append to buffer
// block: 16 queries x 1024 j (wave w covers j-slice w*256)
__global__ __launch_bounds__(256, 8) void k3_main(
    const float* __restrict__ mwT, const float* __restrict__ mm,
    const float* __restrict__ qw,  const float* __restrict__ tau,
    int* __restrict__ qcnt, float* __restrict__ qcv, int* __restrict__ qci)
{
  int t=threadIdx.x, w=t>>6, lane=t&63;
  int q0 = blockIdx.x*16;
  int jb = blockIdx.y*JBLK;
  __shared__ float qs[1024];
  __shared__ float taus[16];
  STAGE_QS();
  if (t < 16){ taus[t] = tau[q0+t] - 5e-6f; }
  __syncthreads();
  int jw = jb + w*256 + 4*lane;
  const float* rowbase = mwT + jw;
  float s[16][4];
  #pragma unroll
  for (int a=0;a<16;a++){
    #pragma unroll
    for (int b=0;b<4;b++) s[a][b]=0.f;
  }
  SCORE_LOOP_16x4();
  float4 mmv4 = *(const float4*)(mm + jw);
  float mmv[4] = {mmv4.x, mmv4.y, mmv4.z, mmv4.w};
  #pragma unroll
  for (int qi=0;qi<16;qi++){
    float tq = taus[qi];
    int qg = q0 + qi;
    #pragma unroll
    for (int jj=0;jj<4;jj++){
      float sc = 2.f*s[qi][jj] - mmv[jj];
      if (sc >= tq){
        int p = atomicAdd(&qcnt[qg], 1);
        if (p < QCAP){
          qcv[(size_t)qg*QCAP+p] = sc;
          qci[(size_t)qg*QCAP+p] = jw + jj;
        }
      }
    }
  }
}

// ---------------- K4: v16 (lane-max bitonic, safe-approx) -> threshold compaction ->
// multi-wave f64 re-rank -> f32-quantized select -> softmax/blend/refine
__global__ __launch_bounds__(256) void k4_final(
    const int* __restrict__ qcnt, const float* __restrict__ qcv, const int* __restrict__ qci,
    const double* __restrict__ qwd_g, const double* __restrict__ qqd_g,
    const double* __restrict__ ggd_g, const double* __restrict__ gpd_g,
    const float* __restrict__ mi, const float* __restrict__ mt,
    const float* __restrict__ le_w1, const float* __restrict__ le_b1,
    const float* __restrict__ le_w2, const float* __restrict__ le_b2,
    const float* __restrict__ fw, const float* __restrict__ itp,
    const float* __restrict__ rw1, const float* __restrict__ rb1,
    const float* __restrict__ rw2, const float* __restrict__ rb2,
    float* __restrict__ out)
{
  int t = threadIdx.x, w = t>>6, l = t&63, q = blockIdx.x;
  __shared__ float  svv[QCAP];
  __shared__ int    sii[QCAP];
  __shared__ float  v16s;
  __shared__ int    ncnt2;
  __shared__ int    candj[NCAND];
  __shared__ double cd2[NCAND];
  __shared__ double mdw[4][64], hdw[4][64];
  __shared__ float  selr[16];
  __shared__ int    selj[16];
  __shared__ double hh[32];
  int NC = qcnt[q]; NC = NC < QCAP ? NC : QCAP;
  for (int i=t; i<NC; i+=256){ svv[i]=qcv[(size_t)q*QCAP+i]; sii[i]=qci[(size_t)q*QCAP+i]; }
  if (t==0) ncnt2 = 0;
  __syncthreads();
  if (t < 64){
    float vm = -3.0e38f;
    for (int i=l; i<NC; i+=64) vm = fmaxf(vm, svv[i]);
    vm = bitonic_sort64(vm, l);
    if (l == 48) v16s = vm;
  }
  __syncthreads();
  {
    float thr = v16s - 1e-5f;
    for (int i=t; i<NC; i+=256){
      if (svv[i] >= thr && (unsigned)sii[i] < (unsigned)N_MEM){
        int p = atomicAdd(&ncnt2, 1);
        if (p < NCAND) candj[p] = sii[i];
      }
    }
  }
  __syncthreads();
  int NC2 = ncnt2 < NCAND ? ncnt2 : NCAND;
  double qwl = qwd_g[q*64+l];
  double swl = sqrt(log1p(exp((double)fw[l])) + 1e-9);
  double qq  = qqd_g[q];
  int CM = (NC2 + 3) >> 2;
  for (int it=0; it<CM; it++){
    int c = it*4 + w;
    bool act = (c < NC2);
    if (act){
      int j = candj[c];
      mdw[w][l] = (double)mi[(size_t)j*64 + l];
    }
    __syncthreads();
    if (act){
      double a0=0,a1=0,a2=0,a3=0;
      for (int d=0; d<64; d+=4){
        a0 = fma(mdw[w][d  ], (double)le_w1[(d  )*64+l], a0);
        a1 = fma(mdw[w][d+1], (double)le_w1[(d+1)*64+l], a1);
        a2 = fma(mdw[w][d+2], (double)le_w1[(d+2)*64+l], a2);
        a3 = fma(mdw[w][d+3], (double)le_w1[(d+3)*64+l], a3);
      }
      double h = (a0+a1)+(a2+a3) + (double)le_b1[l];
      hdw[w][l] = h>0.0 ? h : 0.0;
    }
    __syncthreads();
    if (act){
      double a0=0,a1=0,a2=0,a3=0;
      for (int d=0; d<64; d+=4){
        a0 = fma(hdw[w][d  ], (double)le_w2[(d  )*64+l], a0);
        a1 = fma(hdw[w][d+1], (double)le_w2[(d+1)*64+l], a1);
        a2 = fma(hdw[w][d+2], (double)le_w2[(d+2)*64+l], a2);
        a3 = fma(hdw[w][d+3], (double)le_w2[(d+3)*64+l], a3);
      }
      double o  = (a0+a1)+(a2+a3) + (double)le_b2[l];
      double mw = o * swl;
      double mm2 = wave_sum_d(mw*mw);
      double dt  = wave_sum_d(mw*qwl);
      if (l==0) cd2[c] = qq + mm2 - 2.0*dt;
    }
    __syncthreads();
  }
  if (t < 64){
    float e32  = (float)exp((double)itp[0]);
    float sp32 = (float)log1p((double)e32);
    float t32  = __fadd_rn(sp32, 1e-9f);
    float dn32 = __fadd_rn(t32, 1e-9f);
    double denom = (double)dn32;
    float r0=-2.f, r1=-2.f; int j0=0x7fffffff, j1=0x7fffffff;
    if (l < NC2){
      double d2 = cd2[l]; if (d2 < 0.0) d2 = 0.0;
      float ratio32 = (float)(d2 / denom);
      r0 = (float)exp(-(double)ratio32);
      j0 = candj[l];
    }
    if (l+64 < NC2){
      double d2 = cd2[l+64]; if (d2 < 0.0) d2 = 0.0;
      float ratio32 = (float)(d2 / denom);
      r1 = (float)exp(-(double)ratio32);
      j1 = candj[l+64];
    }
    bool u0=false, u1=false;
    for (int it=0; it<16; it++){
      float a0 = u0 ? -2.f : r0;
      float a1 = u1 ? -2.f : r1;
      float v; int j; int p;
      if (a0 > a1 || (a0 == a1 && j0 <= j1)) { v=a0; j=j0; p=l*2; }
      else                                   { v=a1; j=j1; p=l*2+1; }
      wave_argmax3(v, j, p);
      if ((p>>1) == l){ if (p&1) u1=true; else u0=true; }
      if (l == it){ selr[it]=v; selj[it]=j; }
    }
  }
  __syncthreads();
  if (t < 64){
    double raw = (l<16) ? (double)selr[l] : -1.0e300;
    double mv = raw;
    #pragma unroll
    for (int o=32;o;o>>=1){ double ov = __shfl_xor(mv,o,64); mv = ov>mv?ov:mv; }
    double e  = (l<16) ? exp(raw - mv) : 0.0;
    double se = wave_sum_d(e);
    double wgt = e / se;
    double lp[8] = {0,0,0,0,0,0,0,0};
    if (l < 16){
      const float* tr = mt + (size_t)selj[l]*8;
      #pragma unroll
      for (int tt=0; tt<8; tt++) lp[tt] = wgt * (double)tr[tt];
    }
    #pragma unroll
    for (int tt=0; tt<8; tt++) lp[tt] = wave_sum_d(lp[tt]);
    double g = ggd_g[q];
    double bl[8];
    #pragma unroll
    for (int tt=0; tt<8; tt++) bl[tt] = g*lp[tt] + (1.0-g)*gpd_g[q*8+tt];
    if (l < 32){
      double a = (double)rb1[l];
      #pragma unroll
      for (int tt=0; tt<8; tt++) a = fma(bl[tt], (double)rw1[tt*32+l], a);
      hh[l] = a>0.0?a:0.0;
    }
  }
  __syncthreads();
  if (t < 8){
    double a = (double)rb2[t];
    #pragma unroll
    for (int i=0; i<32; i++) a = fma(hh[i], (double)rw2[i*8+t], a);
    out[q*8+t] = (float)a;
  }
}

extern "C" void kernel_launch(void* const* d_in, const int* in_sizes, int n_in,
                              void* d_out, int out_size, void* d_ws, size_t ws_size,
                              hipStream_t stream)
{
  const float* x     = (const float*)d_in[0];
  const float* mi    = (const float*)d_in[1];
  const float* mt    = (const float*)d_in[2];
  const float* le_w1 = (const float*)d_in[3];
  const float* le_b1 = (const float*)d_in[4];
  const float* le_w2 = (const float*)d_in[5];
  const float* le_b2 = (const float*)d_in[6];
  const float* fw    = (const float*)d_in[7];
  const float* itp   = (const float*)d_in[8];
  const float* ge_w1 = (const float*)d_in[9];
  const float* ge_b1 = (const float*)d_in[10];
  const float* ge_w2 = (const float*)d_in[11];
  const float* ge_b2 = (const float*)d_in[12];
  const float* ge_w3 = (const float*)d_in[13];
  const float* ge_b3 = (const float*)d_in[14];
  const float* gr_w1 = (const float*)d_in[15];
  const float* gr_b1 = (const float*)d_in[16];
  const float* gr_w2 = (const float*)d_in[17];
  const float* gr_b2 = (const float*)d_in[18];
  const float* ga_w1 = (const float*)d_in[19];
  const float* ga_b1 = (const float*)d_in[20];
  const float* ga_w2 = (const float*)d_in[21];
  const float* ga_b2 = (const float*)d_in[22];
  const float* rh_w1 = (const float*)d_in[23];
  const float* rh_b1 = (const float*)d_in[24];
  const float* rh_w2 = (const float*)d_in[25];
  const float* rh_b2 = (const float*)d_in[26];

  double* dws = (double*)d_ws;
  double* qwd = dws;                                // 1024*64
  double* qqd = qwd + (size_t)1024*64;              // 1024
  double* ggd = qqd + 1024;                         // 1024
  double* gpd = ggd + 1024;                         // 8192
  float*  fws = (float*)(gpd + 8192);
  float* mwT = fws;                                 // 64*NP
  float* mm  = mwT + (size_t)64*NP;                 // NP
  float* qwf = mm  + NP;                            // 1024*64
  float* tau = qwf + (size_t)1024*64;               // 1024
  float* ssc = tau + 1024;                          // 1024*4096
  int*   qcnt= (int*)(ssc + (size_t)1024*4096);     // 1024
  float* qcv = (float*)(qcnt + 1024);               // 1024*QCAP
  int*   qci = (int*)(qcv + (size_t)1024*QCAP);     // 1024*QCAP

  k1_mem    <<<dim3(NP/128), dim3(128), 0, stream>>>(mi, le_w1, le_b1, le_w2, le_b2, fw, mwT, mm);
  k2_query  <<<dim3(1024),   dim3(64),  0, stream>>>(x, le_w1, le_b1, le_w2, le_b2, fw,
                ge_w1, ge_b1, ge_w2, ge_b2, ge_w3, ge_b3,
                gr_w1, gr_b1, gr_w2, gr_b2,
                ga_w1, ga_b1, ga_w2, ga_b2,
                qwf, qwd, qqd, ggd, gpd, qcnt);
  k_tau     <<<dim3(64,4),   dim3(256), 0, stream>>>(mwT, mm, qwf, ssc);
  k_tau_sel <<<dim3(1024),   dim3(256), 0, stream>>>(ssc, tau);
  k3_main   <<<dim3(64,NJB), dim3(256), 0, stream>>>(mwT, mm, qwf, tau, qcnt, qcv, qci);
  k4_final  <<<dim3(1024),   dim3(256), 0, stream>>>(qcnt, qcv, qci, qwd, qqd, ggd, gpd, mi, mt,
                le_w1, le_b1, le_w2, le_b2, fw, itp,
                rh_w1, rh_b1, rh_w2, rh_b2, (float*)d_out);
}

// Round 13
// 587.013 us; speedup vs baseline: 6.3312x; 6.3312x over previous
//
#include <hip/hip_runtime.h>
#include <math.h>

#define N_MEM 100000
#define NP    100352      // 98 * 1024 (padded)
#define JBLK  1024
#define NJB   98
#define QCAP  1024        // per-query survivor buffer (expected ~390)
#define NCAND 128         // max re-rank set size

__device__ __forceinline__ float softplusf_(float x){ return log1pf(expf(x)); }

__device__ __forceinline__ double wave_sum_d(double v){
  #pragma unroll
  for (int o=32;o;o>>=1) v += __shfl_xor(v, o, 64);
  return v;
}
__device__ __forceinline__ int wave_sum_i(int v){
  #pragma unroll
  for (int o=32;o;o>>=1) v += __shfl_xor(v, o, 64);
  return v;
}

// argmax carrying (value, global-index tie-break, position meta)
__device__ __forceinline__ void wave_argmax3(float& v, int& j, int& p){
  #pragma unroll
  for (int o=32;o;o>>=1){
    float ov = __shfl_xor(v, o, 64);
    int   oj = __shfl_xor(j, o, 64);
    int   op = __shfl_xor(p, o, 64);
    if (ov > v || (ov == v && oj < j)) { v = ov; j = oj; p = op; }
  }
}

// full ascending bitonic sort across 64 lanes; lane 48 = 16th-largest
__device__ __forceinline__ float bitonic_sort64(float v, int lane){
  #pragma unroll
  for (int k=2;k<=64;k<<=1){
    #pragma unroll
    for (int j=k>>1;j>0;j>>=1){
      float o = __shfl_xor(v, j, 64);
      float mn = fminf(v,o), mx = fmaxf(v,o);
      bool upper = (lane & j) != 0;
      bool asc   = ((lane & k) == 0);
      v = (upper == asc) ? mx : mn;
    }
  }
  return v;
}

// 16q x 4j score accumulation over 64 d; q operand is WAVE-UNIFORM, read from
// global (scalar-cache s_load path); per-(q,j) fmaf chain sequential in d.
// Bit-identical ordering shared by k_tau and k3.
#define SCORE_LOOP_16x4_SQ() { \
  _Pragma("unroll 4") \
  for (int d=0; d<64; d++){ \
    float4 mv4 = *(const float4*)(rowbase + (size_t)d*NP); \
    float marr[4]={mv4.x,mv4.y,mv4.z,mv4.w}; \
    _Pragma("unroll") \
    for (int qi_=0;qi_<16;qi_++){ \
      float qv_ = qbase[qi_*64 + d]; \
      _Pragma("unroll") \
      for (int jj_=0;jj_<4;jj_++) s[qi_][jj_] = fmaf(qv_, marr[jj_], s[qi_][jj_]); \
    } \
  } }

// ---------------- K1: memory embeddings -> mwT (64 x NP), mm (fp32 stream path)
__global__ __launch_bounds__(128) void k1_mem(
    const float* __restrict__ mi,
    const float* __restrict__ w1, const float* __restrict__ b1,
    const float* __restrict__ w2, const float* __restrict__ b2,
    const float* __restrict__ fw,
    float* __restrict__ mwT, float* __restrict__ mm)
{
  __shared__ float xs[64*128];
  int t = threadIdx.x;
  int j = blockIdx.x*128 + t;
  bool real = (j < N_MEM);
  {
    const float4* xp = (const float4*)(mi + (size_t)(real ? j : 0)*64);
    #pragma unroll
    for (int k=0;k<16;k++){
      float4 v = xp[k];
      xs[(4*k+0)*128 + t] = v.x;
      xs[(4*k+1)*128 + t] = v.y;
      xs[(4*k+2)*128 + t] = v.z;
      xs[(4*k+3)*128 + t] = v.w;
    }
  }
  float h[64];
  #pragma unroll
  for (int e=0;e<64;e++) h[e] = b1[e];
  for (int d=0; d<64; d++){
    float xv = xs[d*128 + t];
    #pragma unroll
    for (int e=0;e<64;e++) h[e] = fmaf(xv, w1[d*64+e], h[e]);
  }
  #pragma unroll
  for (int e=0;e<64;e++){ h[e] = fmaxf(h[e], 0.f); xs[e*128 + t] = h[e]; }
  float o[64];
  #pragma unroll
  for (int e=0;e<64;e++) o[e] = b2[e];
  for (int d=0; d<64; d++){
    float hv = xs[d*128 + t];
    #pragma unroll
    for (int e=0;e<64;e++) o[e] = fmaf(hv, w2[d*64+e], o[e]);
  }
  float s2 = 0.f;
  #pragma unroll
  for (int e=0;e<64;e++){
    float sw = sqrtf(softplusf_(fw[e]) + 1e-9f);
    float v = real ? o[e]*sw : 0.f;
    s2 = fmaf(v, v, s2);
    mwT[(size_t)e*NP + j] = v;
  }
  mm[j] = real ? s2 : 3.0e38f;
}

// ---------------- K2: per-query f64 embedding/global/gate (ILP-4 chains); zero qcnt
__global__ __launch_bounds__(64) void k2_query(
  const float* __restrict__ x,
  const float* __restrict__ le_w1, const float* __restrict__ le_b1,
  const float* __restrict__ le_w2, const float* __restrict__ le_b2,
  const float* __restrict__ fw,
  const float* __restrict__ ge_w1, const float* __restrict__ ge_b1,
  const float* __restrict__ ge_w2, const float* __restrict__ ge_b2,
  const float* __restrict__ ge_w3, const float* __restrict__ ge_b3,
  const float* __restrict__ gr_w1, const float* __restrict__ gr_b1,
  const float* __restrict__ gr_w2, const float* __restrict__ gr_b2,
  const float* __restrict__ ga_w1, const float* __restrict__ ga_b1,
  const float* __restrict__ ga_w2, const float* __restrict__ ga_b2,
  float* __restrict__ qwf, double* __restrict__ qwd,
  double* __restrict__ qqd, double* __restrict__ ggd, double* __restrict__ gpd,
  int* __restrict__ qcnt)
{
  int l = threadIdx.x, q = blockIdx.x;
  if (l==0) qcnt[q] = 0;
  __shared__ double xs[64], qe[64], h1[128], t1[64], t2[64];
  xs[l] = (double)x[q*64+l];
  __syncthreads();
  double a0,a1,a2,a3,a;
  a0=a1=a2=a3=0.0;
  for (int d=0; d<64; d+=4){
    a0 = fma(xs[d  ], (double)le_w1[(d  )*64+l], a0);
    a1 = fma(xs[d+1], (double)le_w1[(d+1)*64+l], a1);
    a2 = fma(xs[d+2], (double)le_w1[(d+2)*64+l], a2);
    a3 = fma(xs[d+3], (double)le_w1[(d+3)*64+l], a3);
  }
  a = ((a0+a1)+(a2+a3)) + (double)le_b1[l];
  t1[l] = a > 0.0 ? a : 0.0;
  __syncthreads();
  a0=a1=a2=a3=0.0;
  for (int d=0; d<64; d+=4){
    a0 = fma(t1[d  ], (double)le_w2[(d  )*64+l], a0);
    a1 = fma(t1[d+1], (double)le_w2[(d+1)*64+l], a1);
    a2 = fma(t1[d+2], (double)le_w2[(d+2)*64+l], a2);
    a3 = fma(t1[d+3], (double)le_w2[(d+3)*64+l], a3);
  }
  a = ((a0+a1)+(a2+a3)) + (double)le_b2[l];
  qe[l] = a;
  double sw = sqrt(log1p(exp((double)fw[l])) + 1e-9);
  double qv = a * sw;
  qwd[q*64+l] = qv;
  qwf[q*64+l] = (float)qv;
  double ss = wave_sum_d(qv*qv);
  if (l==0) qqd[q] = ss;
  double b0=0,b1v=0,c0=0,c1=0;
  for (int d=0; d<64; d+=2){
    double x0 = xs[d], x1 = xs[d+1];
    b0  = fma(x0, (double)ge_w1[(d  )*128+l],    b0);
    b1v = fma(x1, (double)ge_w1[(d+1)*128+l],    b1v);
    c0  = fma(x0, (double)ge_w1[(d  )*128+64+l], c0);
    c1  = fma(x1, (double)ge_w1[(d+1)*128+64+l], c1);
  }
  a = (b0+b1v) + (double)ge_b1[l];
  double c = (c0+c1) + (double)ge_b1[64+l];
  h1[l] = a>0.0?a:0.0; h1[64+l] = c>0.0?c:0.0;
  __syncthreads();
  a0=a1=a2=a3=0.0;
  for (int d=0; d<128; d+=4){
    a0 = fma(h1[d  ], (double)ge_w2[(d  )*64+l], a0);
    a1 = fma(h1[d+1], (double)ge_w2[(d+1)*64+l], a1);
    a2 = fma(h1[d+2], (double)ge_w2[(d+2)*64+l], a2);
    a3 = fma(h1[d+3], (double)ge_w2[(d+3)*64+l], a3);
  }
  a = ((a0+a1)+(a2+a3)) + (double)ge_b2[l];
  __syncthreads();
  t1[l] = a>0.0?a:0.0;
  __syncthreads();
  a0=a1=a2=a3=0.0;
  for (int d=0; d<64; d+=4){
    a0 = fma(t1[d  ], (double)ge_w3[(d  )*64+l], a0);
    a1 = fma(t1[d+1], (double)ge_w3[(d+1)*64+l], a1);
    a2 = fma(t1[d+2], (double)ge_w3[(d+2)*64+l], a2);
    a3 = fma(t1[d+3], (double)ge_w3[(d+3)*64+l], a3);
  }
  a = ((a0+a1)+(a2+a3)) + (double)ge_b3[l];
  t2[l] = a;                // global_repr
  __syncthreads();
  a0=a1=a2=a3=0.0;
  for (int d=0; d<64; d+=4){
    a0 = fma(t2[d  ], (double)gr_w1[(d  )*64+l], a0);
    a1 = fma(t2[d+1], (double)gr_w1[(d+1)*64+l], a1);
    a2 = fma(t2[d+2], (double)gr_w1[(d+2)*64+l], a2);
    a3 = fma(t2[d+3], (double)gr_w1[(d+3)*64+l], a3);
  }
  a = ((a0+a1)+(a2+a3)) + (double)gr_b1[l];
  __syncthreads();
  t1[l] = a>0.0?a:0.0;
  __syncthreads();
  if (l < 8){
    a0=a1=a2=a3=0.0;
    for (int d=0; d<64; d+=4){
      a0 = fma(t1[d  ], (double)gr_w2[(d  )*8+l], a0);
      a1 = fma(t1[d+1], (double)gr_w2[(d+1)*8+l], a1);
      a2 = fma(t1[d+2], (double)gr_w2[(d+2)*8+l], a2);
      a3 = fma(t1[d+3], (double)gr_w2[(d+3)*8+l], a3);
    }
    gpd[q*8+l] = ((a0+a1)+(a2+a3)) + (double)gr_b2[l];
  }
  a0=a1=a2=a3=0.0;
  for (int d=0; d<64; d+=4){
    a0 = fma(t2[d  ], (double)ga_w1[(d  )*64+l], a0);
    a1 = fma(t2[d+1], (double)ga_w1[(d+1)*64+l], a1);
    a2 = fma(t2[d+2], (double)ga_w1[(d+2)*64+l], a2);
    a3 = fma(t2[d+3], (double)ga_w1[(d+3)*64+l], a3);
  }
  for (int d=0; d<64; d+=4){
    a0 = fma(qe[d  ], (double)ga_w1[(64+d  )*64+l], a0);
    a1 = fma(qe[d+1], (double)ga_w1[(64+d+1)*64+l], a1);
    a2 = fma(qe[d+2], (double)ga_w1[(64+d+2)*64+l], a2);
    a3 = fma(qe[d+3], (double)ga_w1[(64+d+3)*64+l], a3);
  }
  a = ((a0+a1)+(a2+a3)) + (double)ga_b1[l];
  a = a>0.0?a:0.0;
  double p = wave_sum_d(a * (double)ga_w2[l]);
  if (l==0) ggd[q] = 1.0/(1.0 + exp(-(p + (double)ga_b2[0])));
}

// ---------------- K_tau: dump sample scores (j in [0,4096)) bit-identical to k3
// block: 16 queries x 1024 j (wave w covers j-slice w*256)
__global__ __launch_bounds__(256) void k_tau(
    const float* __restrict__ mwT, const float* __restrict__ mm,
    const float* __restrict__ qw, float* __restrict__ ssc)
{
  int t = threadIdx.x, w = t>>6, lane = t&63;
  int q0 = blockIdx.x*16;
  int jb = blockIdx.y*JBLK;
  const float* qbase = qw + (size_t)q0*64;   // wave-uniform -> scalar loads
  int jw = jb + w*256 + 4*lane;
  const float* rowbase = mwT + jw;
  float s[16][4];
  #pragma unroll
  for (int a=0;a<16;a++){
    #pragma unroll
    for (int b=0;b<4;b++) s[a][b]=0.f;
  }
  SCORE_LOOP_16x4_SQ();
  float4 mmv4 = *(const float4*)(mm + jw);
  float mmv[4] = {mmv4.x, mmv4.y, mmv4.z, mmv4.w};
  #pragma unroll
  for (int qi=0;qi<16;qi++){
    int qg = q0 + qi;
    float4 o0;
    o0.x = 2.f*s[qi][0]-mmv[0]; o0.y = 2.f*s[qi][1]-mmv[1];
    o0.z = 2.f*s[qi][2]-mmv[2]; o0.w = 2.f*s[qi][3]-mmv[3];
    *(float4*)(ssc + (size_t)qg*4096 + jw) = o0;
  }
}

// ---------------- K_tau_sel: exact 16th-largest of the 4096 sample scores per query
__global__ __launch_bounds__(256) void k_tau_sel(
    const float* __restrict__ ssc, float* __restrict__ tau)
{
  int t = threadIdx.x, w = t>>6, l = t&63, q = blockIdx.x;
  __shared__ unsigned su[4096];
  __shared__ int rs[4];
  const float* base = ssc + (size_t)q*4096;
  for (int i=t; i<4096; i+=256){
    unsigned f = __float_as_uint(base[i]);
    su[i] = f ^ ((f >> 31) ? 0xFFFFFFFFu : 0x80000000u);   // monotone key
  }
  __syncthreads();
  unsigned T = 0u;
  for (int b=31; b>=0; b--){
    unsigned cand = T | (1u<<b);
    int c = 0;
    for (int i=t; i<4096; i+=256) c += (su[i] >= cand) ? 1 : 0;
    c = wave_sum_i(c);
    if (l==0) rs[w] = c;
    __syncthreads();
    int tot = rs[0]+rs[1]+rs[2]+rs[3];
    if (tot >= 16) T = cand;
    __syncthreads();
  }
  if (t==0){
    unsigned f = (T & 0x80000000u) ? (T ^ 0x80000000u) : ~T;
    tau[q] = __uint_as_float(f);
  }
}

// ---------------- K3: all 98 j-blocks, filter >= tau - margin, append to buffer
// block: 16 queries x 1024 j (wave w covers j-slice w*256)
__global__ __launch_bounds__(256) void k3_main(
    const float* __restrict__ mwT, const float* __restrict__ mm,
    const float* __restrict__ qw,  const float* __restrict__ tau,
    int* __restrict__ qcnt, float* __restrict__ qcv, int* __restrict__ qci)
{
  int t=threadIdx.x, w=t>>6, lane=t&63;
  int q0 = blockIdx.x*16;
  int jb = blockIdx.y*JBLK;
  __shared__ float taus[16];
  const float* qbase = qw + (size_t)q0*64;   // wave-uniform -> scalar loads
  if (t < 16){ taus[t] = tau[q0+t] - 5e-6f; }
  __syncthreads();
  int jw = jb + w*256 + 4*lane;
  const float* rowbase = mwT + jw;
  float s[16][4];
  #pragma unroll
  for (int a=0;a<16;a++){
    #pragma unroll
    for (int b=0;b<4;b++) s[a][b]=0.f;
  }
  SCORE_LOOP_16x4_SQ();
  float4 mmv4 = *(const float4*)(mm + jw);
  float mmv[4] = {mmv4.x, mmv4.y, mmv4.z, mmv4.w};
  #pragma unroll
  for (int qi=0;qi<16;qi++){
    float tq = taus[qi];
    int qg = q0 + qi;
    #pragma unroll
    for (int jj=0;jj<4;jj++){
      float sc = 2.f*s[qi][jj] - mmv[jj];
      if (sc >= tq){
        int p = atomicAdd(&qcnt[qg], 1);
        if (p < QCAP){
          qcv[(size_t)qg*QCAP+p] = sc;
          qci[(size_t)qg*QCAP+p] = jw + jj;
        }
      }
    }
  }
}

// ---------------- K4: v16 (lane-max bitonic, safe-approx) -> threshold compaction ->
// multi-wave f64 re-rank -> f32-quantized select -> softmax/blend/refine
__global__ __launch_bounds__(256) void k4_final(
    const int* __restrict__ qcnt, const float* __restrict__ qcv, const int* __restrict__ qci,
    const double* __restrict__ qwd_g, const double* __restrict__ qqd_g,
    const double* __restrict__ ggd_g, const double* __restrict__ gpd_g,
    const float* __restrict__ mi, const float* __restrict__ mt,
    const float* __restrict__ le_w1, const float* __restrict__ le_b1,
    const float* __restrict__ le_w2, const float* __restrict__ le_b2,
    const float* __restrict__ fw, const float* __restrict__ itp,
    const float* __restrict__ rw1, const float* __restrict__ rb1,
    const float* __restrict__ rw2, const float* __restrict__ rb2,
    float* __restrict__ out)
{
  int t = threadIdx.x, w = t>>6, l = t&63, q = blockIdx.x;
  __shared__ float  svv[QCAP];
  __shared__ int    sii[QCAP];
  __shared__ float  v16s;
  __shared__ int    ncnt2;
  __shared__ int    candj[NCAND];
  __shared__ double cd2[NCAND];
  __shared__ double mdw[4][64], hdw[4][64];
  __shared__ float  selr[16];
  __shared__ int    selj[16];
  __shared__ double hh[32];
  int NC = qcnt[q]; NC = NC < QCAP ? NC : QCAP;
  for (int i=t; i<NC; i+=256){ svv[i]=qcv[(size_t)q*QCAP+i]; sii[i]=qci[(size_t)q*QCAP+i]; }
  if (t==0) ncnt2 = 0;
  __syncthreads();
  if (t < 64){
    float vm = -3.0e38f;
    for (int i=l; i<NC; i+=64) vm = fmaxf(vm, svv[i]);
    vm = bitonic_sort64(vm, l);
    if (l == 48) v16s = vm;
  }
  __syncthreads();
  {
    float thr = v16s - 1e-5f;
    for (int i=t; i<NC; i+=256){
      if (svv[i] >= thr && (unsigned)sii[i] < (unsigned)N_MEM){
        int p = atomicAdd(&ncnt2, 1);
        if (p < NCAND) candj[p] = sii[i];
      }
    }
  }
  __syncthreads();
  int NC2 = ncnt2 < NCAND ? ncnt2 : NCAND;
  double qwl = qwd_g[q*64+l];
  double swl = sqrt(log1p(exp((double)fw[l])) + 1e-9);
  double qq  = qqd_g[q];
  int CM = (NC2 + 3) >> 2;
  for (int it=0; it<CM; it++){
    int c = it*4 + w;
    bool act = (c < NC2);
    if (act){
      int j = candj[c];
      mdw[w][l] = (double)mi[(size_t)j*64 + l];
    }
    __syncthreads();
    if (act){
      double a0=0,a1=0,a2=0,a3=0;
      for (int d=0; d<64; d+=4){
        a0 = fma(mdw[w][d  ], (double)le_w1[(d  )*64+l], a0);
        a1 = fma(mdw[w][d+1], (double)le_w1[(d+1)*64+l], a1);
        a2 = fma(mdw[w][d+2], (double)le_w1[(d+2)*64+l], a2);
        a3 = fma(mdw[w][d+3], (double)le_w1[(d+3)*64+l], a3);
      }
      double h = (a0+a1)+(a2+a3) + (double)le_b1[l];
      hdw[w][l] = h>0.0 ? h : 0.0;
    }
    __syncthreads();
    if (act){
      double a0=0,a1=0,a2=0,a3=0;
      for (int d=0; d<64; d+=4){
        a0 = fma(hdw[w][d  ], (double)le_w2[(d  )*64+l], a0);
        a1 = fma(hdw[w][d+1], (double)le_w2[(d+1)*64+l], a1);
        a2 = fma(hdw[w][d+2], (double)le_w2[(d+2)*64+l], a2);
        a3 = fma(hdw[w][d+3], (double)le_w2[(d+3)*64+l], a3);
      }
      double o  = (a0+a1)+(a2+a3) + (double)le_b2[l];
      double mw = o * swl;
      double mm2 = wave_sum_d(mw*mw);
      double dt  = wave_sum_d(mw*qwl);
      if (l==0) cd2[c] = qq + mm2 - 2.0*dt;
    }
    __syncthreads();
  }
  if (t < 64){
    float e32  = (float)exp((double)itp[0]);
    float sp32 = (float)log1p((double)e32);
    float t32  = __fadd_rn(sp32, 1e-9f);
    float dn32 = __fadd_rn(t32, 1e-9f);
    double denom = (double)dn32;
    float r0=-2.f, r1=-2.f; int j0=0x7fffffff, j1=0x7fffffff;
    if (l < NC2){
      double d2 = cd2[l]; if (d2 < 0.0) d2 = 0.0;
      float ratio32 = (float)(d2 / denom);
      r0 = (float)exp(-(double)ratio32);
      j0 = candj[l];
    }
    if (l+64 < NC2){
      double d2 = cd2[l+64]; if (d2 < 0.0) d2 = 0.0;
      float ratio32 = (float)(d2 / denom);
      r1 = (float)exp(-(double)ratio32);
      j1 = candj[l+64];
    }
    bool u0=false, u1=false;
    for (int it=0; it<16; it++){
      float a0 = u0 ? -2.f : r0;
      float a1 = u1 ? -2.f : r1;
      float v; int j; int p;
      if (a0 > a1 || (a0 == a1 && j0 <= j1)) { v=a0; j=j0; p=l*2; }
      else                                   { v=a1; j=j1; p=l*2+1; }
      wave_argmax3(v, j, p);
      if ((p>>1) == l){ if (p&1) u1=true; else u0=true; }
      if (l == it){ selr[it]=v; selj[it]=j; }
    }
  }
  __syncthreads();
  if (t < 64){
    double raw = (l<16) ? (double)selr[l] : -1.0e300;
    double mv = raw;
    #pragma unroll
    for (int o=32;o;o>>=1){ double ov = __shfl_xor(mv,o,64); mv = ov>mv?ov:mv; }
    double e  = (l<16) ? exp(raw - mv) : 0.0;
    double se = wave_sum_d(e);
    double wgt = e / se;
    double lp[8] = {0,0,0,0,0,0,0,0};
    if (l < 16){
      const float* tr = mt + (size_t)selj[l]*8;
      #pragma unroll
      for (int tt=0; tt<8; tt++) lp[tt] = wgt * (double)tr[tt];
    }
    #pragma unroll
    for (int tt=0; tt<8; tt++) lp[tt] = wave_sum_d(lp[tt]);
    double g = ggd_g[q];
    double bl[8];
    #pragma unroll
    for (int tt=0; tt<8; tt++) bl[tt] = g*lp[tt] + (1.0-g)*gpd_g[q*8+tt];
    if (l < 32){
      double a = (double)rb1[l];
      #pragma unroll
      for (int tt=0; tt<8; tt++) a = fma(bl[tt], (double)rw1[tt*32+l], a);
      hh[l] = a>0.0?a:0.0;
    }
  }
  __syncthreads();
  if (t < 8){
    double a = (double)rb2[t];
    #pragma unroll
    for (int i=0; i<32; i++) a = fma(hh[i], (double)rw2[i*8+t], a);
    out[q*8+t] = (float)a;
  }
}

extern "C" void kernel_launch(void* const* d_in, const int* in_sizes, int n_in,
                              void* d_out, int out_size, void* d_ws, size_t ws_size,
                              hipStream_t stream)
{
  const float* x     = (const float*)d_in[0];
  const float* mi    = (const float*)d_in[1];
  const float* mt    = (const float*)d_in[2];
  const float* le_w1 = (const float*)d_in[3];
  const float* le_b1 = (const float*)d_in[4];
  const float* le_w2 = (const float*)d_in[5];
  const float* le_b2 = (const float*)d_in[6];
  const float* fw    = (const float*)d_in[7];
  const float* itp   = (const float*)d_in[8];
  const float* ge_w1 = (const float*)d_in[9];
  const float* ge_b1 = (const float*)d_in[10];
  const float* ge_w2 = (const float*)d_in[11];
  const float* ge_b2 = (const float*)d_in[12];
  const float* ge_w3 = (const float*)d_in[13];
  const float* ge_b3 = (const float*)d_in[14];
  const float* gr_w1 = (const float*)d_in[15];
  const float* gr_b1 = (const float*)d_in[16];
  const float* gr_w2 = (const float*)d_in[17];
  const float* gr_b2 = (const float*)d_in[18];
  const float* ga_w1 = (const float*)d_in[19];
  const float* ga_b1 = (const float*)d_in[20];
  const float* ga_w2 = (const float*)d_in[21];
  const float* ga_b2 = (const float*)d_in[22];
  const float* rh_w1 = (const float*)d_in[23];
  const float* rh_b1 = (const float*)d_in[24];
  const float* rh_w2 = (const float*)d_in[25];
  const float* rh_b2 = (const float*)d_in[26];

  double* dws = (double*)d_ws;
  double* qwd = dws;                                // 1024*64
  double* qqd = qwd + (size_t)1024*64;              // 1024
  double* ggd = qqd + 1024;                         // 1024
  double* gpd = ggd + 1024;                         // 8192
  float*  fws = (float*)(gpd + 8192);
  float* mwT = fws;                                 // 64*NP
  float* mm  = mwT + (size_t)64*NP;                 // NP
  float* qwf = mm  + NP;                            // 1024*64
  float* tau = qwf + (size_t)1024*64;               // 1024
  float* ssc = tau + 1024;                          // 1024*4096
  int*   qcnt= (int*)(ssc + (size_t)1024*4096);     // 1024
  float* qcv = (float*)(qcnt + 1024);               // 1024*QCAP
  int*   qci = (int*)(qcv + (size_t)1024*QCAP);     // 1024*QCAP

  k1_mem    <<<dim3(NP/128), dim3(128), 0, stream>>>(mi, le_w1, le_b1, le_w2, le_b2, fw, mwT, mm);
  k2_query  <<<dim3(1024),   dim3(64),  0, stream>>>(x, le_w1, le_b1, le_w2, le_b2, fw,
                ge_w1, ge_b1, ge_w2, ge_b2, ge_w3, ge_b3,
                gr_w1, gr_b1, gr_w2, gr_b2,
                ga_w1, ga_b1, ga_w2, ga_b2,
                qwf, qwd, qqd, ggd, gpd, qcnt);
  k_tau     <<<dim3(64,4),   dim3(256), 0, stream>>>(mwT, mm, qwf, ssc);
  k_tau_sel <<<dim3(1024),   dim3(256), 0, stream>>>(ssc, tau);
  k3_main   <<<dim3(64,NJB), dim3(256), 0, stream>>>(mwT, mm, qwf, tau, qcnt, qcv, qci);
  k4_final  <<<dim3(1024),   dim3(256), 0, stream>>>(qcnt, qcv, qci, qwd, qqd, ggd, gpd, mi, mt,
                le_w1, le_b1, le_w2, le_b2, fw, itp,
                rh_w1, rh_b1, rh_w2, rh_b2, (float*)d_out);
}

// Round 14
// 574.269 us; speedup vs baseline: 6.4717x; 1.0222x over previous
//
#include <hip/hip_runtime.h>
#include <math.h>

#define N_MEM 100000
#define NP    100352      // 98 * 1024 (padded)
#define JBLK  1024
#define NJB   98
#define QCAP  1024        // per-query survivor buffer (expected ~390)
#define NCAND 128         // max re-rank set size

__device__ __forceinline__ float softplusf_(float x){ return log1pf(expf(x)); }

__device__ __forceinline__ double wave_sum_d(double v){
  #pragma unroll
  for (int o=32;o;o>>=1) v += __shfl_xor(v, o, 64);
  return v;
}
__device__ __forceinline__ int wave_sum_i(int v){
  #pragma unroll
  for (int o=32;o;o>>=1) v += __shfl_xor(v, o, 64);
  return v;
}

// argmax carrying (value, global-index tie-break, position meta)
__device__ __forceinline__ void wave_argmax3(float& v, int& j, int& p){
  #pragma unroll
  for (int o=32;o;o>>=1){
    float ov = __shfl_xor(v, o, 64);
    int   oj = __shfl_xor(j, o, 64);
    int   op = __shfl_xor(p, o, 64);
    if (ov > v || (ov == v && oj < j)) { v = ov; j = oj; p = op; }
  }
}

// full ascending bitonic sort across 64 lanes; lane 48 = 16th-largest
__device__ __forceinline__ float bitonic_sort64(float v, int lane){
  #pragma unroll
  for (int k=2;k<=64;k<<=1){
    #pragma unroll
    for (int j=k>>1;j>0;j>>=1){
      float o = __shfl_xor(v, j, 64);
      float mn = fminf(v,o), mx = fmaxf(v,o);
      bool upper = (lane & j) != 0;
      bool asc   = ((lane & k) == 0);
      v = (upper == asc) ? mx : mn;
    }
  }
  return v;
}

// 16q x 4j score accumulation over 64 d; q operand is WAVE-UNIFORM, read from
// global (scalar-cache s_load path); per-(q,j) fmaf chain sequential in d.
// Bit-identical ordering shared by k_tau and k3.
#define SCORE_LOOP_16x4_SQ() { \
  _Pragma("unroll 4") \
  for (int d=0; d<64; d++){ \
    float4 mv4 = *(const float4*)(rowbase + (size_t)d*NP); \
    float marr[4]={mv4.x,mv4.y,mv4.z,mv4.w}; \
    _Pragma("unroll") \
    for (int qi_=0;qi_<16;qi_++){ \
      float qv_ = qbase[qi_*64 + d]; \
      _Pragma("unroll") \
      for (int jj_=0;jj_<4;jj_++) s[qi_][jj_] = fmaf(qv_, marr[jj_], s[qi_][jj_]); \
    } \
  } }

// ---------------- K1: memory embeddings -> mwT (64 x NP), mm (fp32 stream path)
__global__ __launch_bounds__(128) void k1_mem(
    const float* __restrict__ mi,
    const float* __restrict__ w1, const float* __restrict__ b1,
    const float* __restrict__ w2, const float* __restrict__ b2,
    const float* __restrict__ fw,
    float* __restrict__ mwT, float* __restrict__ mm)
{
  __shared__ float xs[64*128];
  int t = threadIdx.x;
  int j = blockIdx.x*128 + t;
  bool real = (j < N_MEM);
  {
    const float4* xp = (const float4*)(mi + (size_t)(real ? j : 0)*64);
    #pragma unroll
    for (int k=0;k<16;k++){
      float4 v = xp[k];
      xs[(4*k+0)*128 + t] = v.x;
      xs[(4*k+1)*128 + t] = v.y;
      xs[(4*k+2)*128 + t] = v.z;
      xs[(4*k+3)*128 + t] = v.w;
    }
  }
  float h[64];
  #pragma unroll
  for (int e=0;e<64;e++) h[e] = b1[e];
  for (int d=0; d<64; d++){
    float xv = xs[d*128 + t];
    #pragma unroll
    for (int e=0;e<64;e++) h[e] = fmaf(xv, w1[d*64+e], h[e]);
  }
  #pragma unroll
  for (int e=0;e<64;e++){ h[e] = fmaxf(h[e], 0.f); xs[e*128 + t] = h[e]; }
  float o[64];
  #pragma unroll
  for (int e=0;e<64;e++) o[e] = b2[e];
  for (int d=0; d<64; d++){
    float hv = xs[d*128 + t];
    #pragma unroll
    for (int e=0;e<64;e++) o[e] = fmaf(hv, w2[d*64+e], o[e]);
  }
  float s2 = 0.f;
  #pragma unroll
  for (int e=0;e<64;e++){
    float sw = sqrtf(softplusf_(fw[e]) + 1e-9f);
    float v = real ? o[e]*sw : 0.f;
    s2 = fmaf(v, v, s2);
    mwT[(size_t)e*NP + j] = v;
  }
  mm[j] = real ? s2 : 3.0e38f;
}

// ---------------- K2: per-query f64 embedding/global/gate (ILP-4 chains); zero qcnt
__global__ __launch_bounds__(64) void k2_query(
  const float* __restrict__ x,
  const float* __restrict__ le_w1, const float* __restrict__ le_b1,
  const float* __restrict__ le_w2, const float* __restrict__ le_b2,
  const float* __restrict__ fw,
  const float* __restrict__ ge_w1, const float* __restrict__ ge_b1,
  const float* __restrict__ ge_w2, const float* __restrict__ ge_b2,
  const float* __restrict__ ge_w3, const float* __restrict__ ge_b3,
  const float* __restrict__ gr_w1, const float* __restrict__ gr_b1,
  const float* __restrict__ gr_w2, const float* __restrict__ gr_b2,
  const float* __restrict__ ga_w1, const float* __restrict__ ga_b1,
  const float* __restrict__ ga_w2, const float* __restrict__ ga_b2,
  float* __restrict__ qwf, double* __restrict__ qwd,
  double* __restrict__ qqd, double* __restrict__ ggd, double* __restrict__ gpd,
  int* __restrict__ qcnt)
{
  int l = threadIdx.x, q = blockIdx.x;
  if (l==0) qcnt[q] = 0;
  __shared__ double xs[64], qe[64], h1[128], t1[64], t2[64];
  xs[l] = (double)x[q*64+l];
  __syncthreads();
  double a0,a1,a2,a3,a;
  a0=a1=a2=a3=0.0;
  for (int d=0; d<64; d+=4){
    a0 = fma(xs[d  ], (double)le_w1[(d  )*64+l], a0);
    a1 = fma(xs[d+1], (double)le_w1[(d+1)*64+l], a1);
    a2 = fma(xs[d+2], (double)le_w1[(d+2)*64+l], a2);
    a3 = fma(xs[d+3], (double)le_w1[(d+3)*64+l], a3);
  }
  a = ((a0+a1)+(a2+a3)) + (double)le_b1[l];
  t1[l] = a > 0.0 ? a : 0.0;
  __syncthreads();
  a0=a1=a2=a3=0.0;
  for (int d=0; d<64; d+=4){
    a0 = fma(t1[d  ], (double)le_w2[(d  )*64+l], a0);
    a1 = fma(t1[d+1], (double)le_w2[(d+1)*64+l], a1);
    a2 = fma(t1[d+2], (double)le_w2[(d+2)*64+l], a2);
    a3 = fma(t1[d+3], (double)le_w2[(d+3)*64+l], a3);
  }
  a = ((a0+a1)+(a2+a3)) + (double)le_b2[l];
  qe[l] = a;
  double sw = sqrt(log1p(exp((double)fw[l])) + 1e-9);
  double qv = a * sw;
  qwd[q*64+l] = qv;
  qwf[q*64+l] = (float)qv;
  double ss = wave_sum_d(qv*qv);
  if (l==0) qqd[q] = ss;
  double b0=0,b1v=0,c0=0,c1=0;
  for (int d=0; d<64; d+=2){
    double x0 = xs[d], x1 = xs[d+1];
    b0  = fma(x0, (double)ge_w1[(d  )*128+l],    b0);
    b1v = fma(x1, (double)ge_w1[(d+1)*128+l],    b1v);
    c0  = fma(x0, (double)ge_w1[(d  )*128+64+l], c0);
    c1  = fma(x1, (double)ge_w1[(d+1)*128+64+l], c1);
  }
  a = (b0+b1v) + (double)ge_b1[l];
  double c = (c0+c1) + (double)ge_b1[64+l];
  h1[l] = a>0.0?a:0.0; h1[64+l] = c>0.0?c:0.0;
  __syncthreads();
  a0=a1=a2=a3=0.0;
  for (int d=0; d<128; d+=4){
    a0 = fma(h1[d  ], (double)ge_w2[(d  )*64+l], a0);
    a1 = fma(h1[d+1], (double)ge_w2[(d+1)*64+l], a1);
    a2 = fma(h1[d+2], (double)ge_w2[(d+2)*64+l], a2);
    a3 = fma(h1[d+3], (double)ge_w2[(d+3)*64+l], a3);
  }
  a = ((a0+a1)+(a2+a3)) + (double)ge_b2[l];
  __syncthreads();
  t1[l] = a>0.0?a:0.0;
  __syncthreads();
  a0=a1=a2=a3=0.0;
  for (int d=0; d<64; d+=4){
    a0 = fma(t1[d  ], (double)ge_w3[(d  )*64+l], a0);
    a1 = fma(t1[d+1], (double)ge_w3[(d+1)*64+l], a1);
    a2 = fma(t1[d+2], (double)ge_w3[(d+2)*64+l], a2);
    a3 = fma(t1[d+3], (double)ge_w3[(d+3)*64+l], a3);
  }
  a = ((a0+a1)+(a2+a3)) + (double)ge_b3[l];
  t2[l] = a;                // global_repr
  __syncthreads();
  a0=a1=a2=a3=0.0;
  for (int d=0; d<64; d+=4){
    a0 = fma(t2[d  ], (double)gr_w1[(d  )*64+l], a0);
    a1 = fma(t2[d+1], (double)gr_w1[(d+1)*64+l], a1);
    a2 = fma(t2[d+2], (double)gr_w1[(d+2)*64+l], a2);
    a3 = fma(t2[d+3], (double)gr_w1[(d+3)*64+l], a3);
  }
  a = ((a0+a1)+(a2+a3)) + (double)gr_b1[l];
  __syncthreads();
  t1[l] = a>0.0?a:0.0;
  __syncthreads();
  if (l < 8){
    a0=a1=a2=a3=0.0;
    for (int d=0; d<64; d+=4){
      a0 = fma(t1[d  ], (double)gr_w2[(d  )*8+l], a0);
      a1 = fma(t1[d+1], (double)gr_w2[(d+1)*8+l], a1);
      a2 = fma(t1[d+2], (double)gr_w2[(d+2)*8+l], a2);
      a3 = fma(t1[d+3], (double)gr_w2[(d+3)*8+l], a3);
    }
    gpd[q*8+l] = ((a0+a1)+(a2+a3)) + (double)gr_b2[l];
  }
  a0=a1=a2=a3=0.0;
  for (int d=0; d<64; d+=4){
    a0 = fma(t2[d  ], (double)ga_w1[(d  )*64+l], a0);
    a1 = fma(t2[d+1], (double)ga_w1[(d+1)*64+l], a1);
    a2 = fma(t2[d+2], (double)ga_w1[(d+2)*64+l], a2);
    a3 = fma(t2[d+3], (double)ga_w1[(d+3)*64+l], a3);
  }
  for (int d=0; d<64; d+=4){
    a0 = fma(qe[d  ], (double)ga_w1[(64+d  )*64+l], a0);
    a1 = fma(qe[d+1], (double)ga_w1[(64+d+1)*64+l], a1);
    a2 = fma(qe[d+2], (double)ga_w1[(64+d+2)*64+l], a2);
    a3 = fma(qe[d+3], (double)ga_w1[(64+d+3)*64+l], a3);
  }
  a = ((a0+a1)+(a2+a3)) + (double)ga_b1[l];
  a = a>0.0?a:0.0;
  double p = wave_sum_d(a * (double)ga_w2[l]);
  if (l==0) ggd[q] = 1.0/(1.0 + exp(-(p + (double)ga_b2[0])));
}

// ---------------- K_tau: dump sample scores (j in [0,4096)) bit-identical to k3
// block: 16 queries x 1024 j (wave w covers j-slice w*256)
__global__ __launch_bounds__(256) void k_tau(
    const float* __restrict__ mwT, const float* __restrict__ mm,
    const float* __restrict__ qw, float* __restrict__ ssc)
{
  int t = threadIdx.x, w = t>>6, lane = t&63;
  int q0 = blockIdx.x*16;
  int jb = blockIdx.y*JBLK;
  const float* qbase = qw + (size_t)q0*64;   // wave-uniform -> scalar loads
  int jw = jb + w*256 + 4*lane;
  const float* rowbase = mwT + jw;
  float s[16][4];
  #pragma unroll
  for (int a=0;a<16;a++){
    #pragma unroll
    for (int b=0;b<4;b++) s[a][b]=0.f;
  }
  SCORE_LOOP_16x4_SQ();
  float4 mmv4 = *(const float4*)(mm + jw);
  float mmv[4] = {mmv4.x, mmv4.y, mmv4.z, mmv4.w};
  #pragma unroll
  for (int qi=0;qi<16;qi++){
    int qg = q0 + qi;
    float4 o0;
    o0.x = 2.f*s[qi][0]-mmv[0]; o0.y = 2.f*s[qi][1]-mmv[1];
    o0.z = 2.f*s[qi][2]-mmv[2]; o0.w = 2.f*s[qi][3]-mmv[3];
    *(float4*)(ssc + (size_t)qg*4096 + jw) = o0;
  }
}

// ---------------- K_tau_sel: exact 16th-largest of the 4096 sample scores per query
__global__ __launch_bounds__(256) void k_tau_sel(
    const float* __restrict__ ssc, float* __restrict__ tau)
{
  int t = threadIdx.x, w = t>>6, l = t&63, q = blockIdx.x;
  __shared__ unsigned su[4096];
  __shared__ int rs[4];
  const float* base = ssc + (size_t)q*4096;
  for (int i=t; i<4096; i+=256){
    unsigned f = __float_as_uint(base[i]);
    su[i] = f ^ ((f >> 31) ? 0xFFFFFFFFu : 0x80000000u);   // monotone key
  }
  __syncthreads();
  unsigned T = 0u;
  for (int b=31; b>=0; b--){
    unsigned cand = T | (1u<<b);
    int c = 0;
    for (int i=t; i<4096; i+=256) c += (su[i] >= cand) ? 1 : 0;
    c = wave_sum_i(c);
    if (l==0) rs[w] = c;
    __syncthreads();
    int tot = rs[0]+rs[1]+rs[2]+rs[3];
    if (tot >= 16) T = cand;
    __syncthreads();
  }
  if (t==0){
    unsigned f = (T & 0x80000000u) ? (T ^ 0x80000000u) : ~T;
    tau[q] = __uint_as_float(f);
  }
}

// ---------------- K3: all 98 j-blocks, filter >= tau - margin, append to buffer
// block: 16 queries x 1024 j (wave w covers j-slice w*256)
__global__ __launch_bounds__(256) void k3_main(
    const float* __restrict__ mwT, const float* __restrict__ mm,
    const float* __restrict__ qw,  const float* __restrict__ tau,
    int* __restrict__ qcnt, float* __restrict__ qcv, int* __restrict__ qci)
{
  int t=threadIdx.x, w=t>>6, lane=t&63;
  int q0 = blockIdx.x*16;
  int jb = blockIdx.y*JBLK;
  __shared__ float taus[16];
  const float* qbase = qw + (size_t)q0*64;   // wave-uniform -> scalar loads
  if (t < 16){ taus[t] = tau[q0+t] - 5e-6f; }
  __syncthreads();
  int jw = jb + w*256 + 4*lane;
  const float* rowbase = mwT + jw;
  float s[16][4];
  #pragma unroll
  for (int a=0;a<16;a++){
    #pragma unroll
    for (int b=0;b<4;b++) s[a][b]=0.f;
  }
  SCORE_LOOP_16x4_SQ();
  float4 mmv4 = *(const float4*)(mm + jw);
  float mmv[4] = {mmv4.x, mmv4.y, mmv4.z, mmv4.w};
  #pragma unroll
  for (int qi=0;qi<16;qi++){
    float tq = taus[qi];
    int qg = q0 + qi;
    #pragma unroll
    for (int jj=0;jj<4;jj++){
      float sc = 2.f*s[qi][jj] - mmv[jj];
      if (sc >= tq){
        int p = atomicAdd(&qcnt[qg], 1);
        if (p < QCAP){
          qcv[(size_t)qg*QCAP+p] = sc;
          qci[(size_t)qg*QCAP+p] = jw + jj;
        }
      }
    }
  }
}

// ---------------- K4: v16 (lane-max bitonic, safe-approx) -> threshold compaction ->
// barrier-free per-wave f64 re-rank -> f32-quantized select -> softmax/blend/refine
__global__ __launch_bounds__(256) void k4_final(
    const int* __restrict__ qcnt, const float* __restrict__ qcv, const int* __restrict__ qci,
    const double* __restrict__ qwd_g, const double* __restrict__ qqd_g,
    const double* __restrict__ ggd_g, const double* __restrict__ gpd_g,
    const float* __restrict__ mi, const float* __restrict__ mt,
    const float* __restrict__ le_w1, const float* __restrict__ le_b1,
    const float* __restrict__ le_w2, const float* __restrict__ le_b2,
    const float* __restrict__ fw, const float* __restrict__ itp,
    const float* __restrict__ rw1, const float* __restrict__ rb1,
    const float* __restrict__ rw2, const float* __restrict__ rb2,
    float* __restrict__ out)
{
  int t = threadIdx.x, w = t>>6, l = t&63, q = blockIdx.x;
  __shared__ float  svv[QCAP];
  __shared__ int    sii[QCAP];
  __shared__ float  v16s;
  __shared__ int    ncnt2;
  __shared__ int    candj[NCAND];
  __shared__ double cd2[NCAND];
  __shared__ double hdw[4][64];
  __shared__ float  selr[16];
  __shared__ int    selj[16];
  __shared__ double hh[32];
  int NC = qcnt[q]; NC = NC < QCAP ? NC : QCAP;
  for (int i=t; i<NC; i+=256){ svv[i]=qcv[(size_t)q*QCAP+i]; sii[i]=qci[(size_t)q*QCAP+i]; }
  if (t==0) ncnt2 = 0;
  __syncthreads();
  if (t < 64){
    float vm = -3.0e38f;
    for (int i=l; i<NC; i+=64) vm = fmaxf(vm, svv[i]);
    vm = bitonic_sort64(vm, l);
    if (l == 48) v16s = vm;
  }
  __syncthreads();
  {
    float thr = v16s - 2e-6f;   // covers f32-stream vs f64 score discrepancy (~5e-7 worst)
    for (int i=t; i<NC; i+=256){
      if (svv[i] >= thr && (unsigned)sii[i] < (unsigned)N_MEM){
        int p = atomicAdd(&ncnt2, 1);
        if (p < NCAND) candj[p] = sii[i];
      }
    }
  }
  __syncthreads();
  int NC2 = ncnt2 < NCAND ? ncnt2 : NCAND;
  // Phase D: barrier-free, one candidate per wave, scalar layer-1 loads, 8-acc ILP.
  // (f64 summation order is free: d2 noise ~1e-15 << 6e-8 quantization bin)
  double qwl = qwd_g[q*64+l];
  double swl = sqrt(log1p(exp((double)fw[l])) + 1e-9);
  double qq  = qqd_g[q];
  for (int c = w; c < NC2; c += 4){
    int jc = __builtin_amdgcn_readfirstlane(candj[c]);
    const float* mrow = mi + (size_t)jc*64;   // wave-uniform -> s_load
    double b0=0,b1=0,b2=0,b3=0,b4=0,b5=0,b6=0,b7=0;
    #pragma unroll
    for (int d=0; d<64; d+=8){
      b0 = fma((double)mrow[d  ], (double)le_w1[(d  )*64+l], b0);
      b1 = fma((double)mrow[d+1], (double)le_w1[(d+1)*64+l], b1);
      b2 = fma((double)mrow[d+2], (double)le_w1[(d+2)*64+l], b2);
      b3 = fma((double)mrow[d+3], (double)le_w1[(d+3)*64+l], b3);
      b4 = fma((double)mrow[d+4], (double)le_w1[(d+4)*64+l], b4);
      b5 = fma((double)mrow[d+5], (double)le_w1[(d+5)*64+l], b5);
      b6 = fma((double)mrow[d+6], (double)le_w1[(d+6)*64+l], b6);
      b7 = fma((double)mrow[d+7], (double)le_w1[(d+7)*64+l], b7);
    }
    double h = (((b0+b1)+(b2+b3)) + ((b4+b5)+(b6+b7))) + (double)le_b1[l];
    h = h>0.0 ? h : 0.0;
    hdw[w][l] = h;   // wave-private region; lockstep + lgkmcnt ordering suffice
    double c0=0,c1=0,c2=0,c3=0,c4=0,c5=0,c6=0,c7=0;
    #pragma unroll
    for (int d=0; d<64; d+=8){
      c0 = fma(hdw[w][d  ], (double)le_w2[(d  )*64+l], c0);
      c1 = fma(hdw[w][d+1], (double)le_w2[(d+1)*64+l], c1);
      c2 = fma(hdw[w][d+2], (double)le_w2[(d+2)*64+l], c2);
      c3 = fma(hdw[w][d+3], (double)le_w2[(d+3)*64+l], c3);
      c4 = fma(hdw[w][d+4], (double)le_w2[(d+4)*64+l], c4);
      c5 = fma(hdw[w][d+5], (double)le_w2[(d+5)*64+l], c5);
      c6 = fma(hdw[w][d+6], (double)le_w2[(d+6)*64+l], c6);
      c7 = fma(hdw[w][d+7], (double)le_w2[(d+7)*64+l], c7);
    }
    double o  = (((c0+c1)+(c2+c3)) + ((c4+c5)+(c6+c7))) + (double)le_b2[l];
    double mw = o * swl;
    double sc = wave_sum_d(mw*(mw - 2.0*qwl));
    if (l==0) cd2[c] = qq + sc;
  }
  __syncthreads();
  if (t < 64){
    float e32  = (float)exp((double)itp[0]);
    float sp32 = (float)log1p((double)e32);
    float t32  = __fadd_rn(sp32, 1e-9f);
    float dn32 = __fadd_rn(t32, 1e-9f);
    double denom = (double)dn32;
    float r0=-2.f, r1=-2.f; int j0=0x7fffffff, j1=0x7fffffff;
    if (l < NC2){
      double d2 = cd2[l]; if (d2 < 0.0) d2 = 0.0;
      float ratio32 = (float)(d2 / denom);
      r0 = (float)exp(-(double)ratio32);
      j0 = candj[l];
    }
    if (l+64 < NC2){
      double d2 = cd2[l+64]; if (d2 < 0.0) d2 = 0.0;
      float ratio32 = (float)(d2 / denom);
      r1 = (float)exp(-(double)ratio32);
      j1 = candj[l+64];
    }
    bool u0=false, u1=false;
    for (int it=0; it<16; it++){
      float a0 = u0 ? -2.f : r0;
      float a1 = u1 ? -2.f : r1;
      float v; int j; int p;
      if (a0 > a1 || (a0 == a1 && j0 <= j1)) { v=a0; j=j0; p=l*2; }
      else                                   { v=a1; j=j1; p=l*2+1; }
      wave_argmax3(v, j, p);
      if ((p>>1) == l){ if (p&1) u1=true; else u0=true; }
      if (l == it){ selr[it]=v; selj[it]=j; }
    }
  }
  __syncthreads();
  if (t < 64){
    double raw = (l<16) ? (double)selr[l] : -1.0e300;
    double mv = raw;
    #pragma unroll
    for (int o=32;o;o>>=1){ double ov = __shfl_xor(mv,o,64); mv = ov>mv?ov:mv; }
    double e  = (l<16) ? exp(raw - mv) : 0.0;
    double se = wave_sum_d(e);
    double wgt = e / se;
    double lp[8] = {0,0,0,0,0,0,0,0};
    if (l < 16){
      const float* tr = mt + (size_t)selj[l]*8;
      #pragma unroll
      for (int tt=0; tt<8; tt++) lp[tt] = wgt * (double)tr[tt];
    }
    #pragma unroll
    for (int tt=0; tt<8; tt++) lp[tt] = wave_sum_d(lp[tt]);
    double g = ggd_g[q];
    double bl[8];
    #pragma unroll
    for (int tt=0; tt<8; tt++) bl[tt] = g*lp[tt] + (1.0-g)*gpd_g[q*8+tt];
    if (l < 32){
      double a = (double)rb1[l];
      #pragma unroll
      for (int tt=0; tt<8; tt++) a = fma(bl[tt], (double)rw1[tt*32+l], a);
      hh[l] = a>0.0?a:0.0;
    }
  }
  __syncthreads();
  if (t < 8){
    double a = (double)rb2[t];
    #pragma unroll
    for (int i=0; i<32; i++) a = fma(hh[i], (double)rw2[i*8+t], a);
    out[q*8+t] = (float)a;
  }
}

extern "C" void kernel_launch(void* const* d_in, const int* in_sizes, int n_in,
                              void* d_out, int out_size, void* d_ws, size_t ws_size,
                              hipStream_t stream)
{
  const float* x     = (const float*)d_in[0];
  const float* mi    = (const float*)d_in[1];
  const float* mt    = (const float*)d_in[2];
  const float* le_w1 = (const float*)d_in[3];
  const float* le_b1 = (const float*)d_in[4];
  const float* le_w2 = (const float*)d_in[5];
  const float* le_b2 = (const float*)d_in[6];
  const float* fw    = (const float*)d_in[7];
  const float* itp   = (const float*)d_in[8];
  const float* ge_w1 = (const float*)d_in[9];
  const float* ge_b1 = (const float*)d_in[10];
  const float* ge_w2 = (const float*)d_in[11];
  const float* ge_b2 = (const float*)d_in[12];
  const float* ge_w3 = (const float*)d_in[13];
  const float* ge_b3 = (const float*)d_in[14];
  const float* gr_w1 = (const float*)d_in[15];
  const float* gr_b1 = (const float*)d_in[16];
  const float* gr_w2 = (const float*)d_in[17];
  const float* gr_b2 = (const float*)d_in[18];
  const float* ga_w1 = (const float*)d_in[19];
  const float* ga_b1 = (const float*)d_in[20];
  const float* ga_w2 = (const float*)d_in[21];
  const float* ga_b2 = (const float*)d_in[22];
  const float* rh_w1 = (const float*)d_in[23];
  const float* rh_b1 = (const float*)d_in[24];
  const float* rh_w2 = (const float*)d_in[25];
  const float* rh_b2 = (const float*)d_in[26];

  double* dws = (double*)d_ws;
  double* qwd = dws;                                // 1024*64
  double* qqd = qwd + (size_t)1024*64;              // 1024
  double* ggd = qqd + 1024;                         // 1024
  double* gpd = ggd + 1024;                         // 8192
  float*  fws = (float*)(gpd + 8192);
  float* mwT = fws;                                 // 64*NP
  float* mm  = mwT + (size_t)64*NP;                 // NP
  float* qwf = mm  + NP;                            // 1024*64
  float* tau = qwf + (size_t)1024*64;               // 1024
  float* ssc = tau + 1024;                          // 1024*4096
  int*   qcnt= (int*)(ssc + (size_t)1024*4096);     // 1024
  float* qcv = (float*)(qcnt + 1024);               // 1024*QCAP
  int*   qci = (int*)(qcv + (size_t)1024*QCAP);     // 1024*QCAP

  k1_mem    <<<dim3(NP/128), dim3(128), 0, stream>>>(mi, le_w1, le_b1, le_w2, le_b2, fw, mwT, mm);
  k2_query  <<<dim3(1024),   dim3(64),  0, stream>>>(x, le_w1, le_b1, le_w2, le_b2, fw,
                ge_w1, ge_b1, ge_w2, ge_b2, ge_w3, ge_b3,
                gr_w1, gr_b1, gr_w2, gr_b2,
                ga_w1, ga_b1, ga_w2, ga_b2,
                qwf, qwd, qqd, ggd, gpd, qcnt);
  k_tau     <<<dim3(64,4),   dim3(256), 0, stream>>>(mwT, mm, qwf, ssc);
  k_tau_sel <<<dim3(1024),   dim3(256), 0, stream>>>(ssc, tau);
  k3_main   <<<dim3(64,NJB), dim3(256), 0, stream>>>(mwT, mm, qwf, tau, qcnt, qcv, qci);
  k4_final  <<<dim3(1024),   dim3(256), 0, stream>>>(qcnt, qcv, qci, qwd, qqd, ggd, gpd, mi, mt,
                le_w1, le_b1, le_w2, le_b2, fw, itp,
                rh_w1, rh_b1, rh_w2, rh_b2, (float*)d_out);
}

// Round 15
// 517.866 us; speedup vs baseline: 7.1765x; 1.1089x over previous
//
#include <hip/hip_runtime.h>
#include <math.h>

#define N_MEM 100000
#define NP    100352      // 98 * 1024 (padded)
#define JBLK  1024
#define NJB   98
#define QCAP  1024        // per-query survivor buffer (expected ~390)
#define NCAND 128         // max re-rank set size

__device__ __forceinline__ float softplusf_(float x){ return log1pf(expf(x)); }

__device__ __forceinline__ double wave_sum_d(double v){
  #pragma unroll
  for (int o=32;o;o>>=1) v += __shfl_xor(v, o, 64);
  return v;
}
__device__ __forceinline__ int wave_sum_i(int v){
  #pragma unroll
  for (int o=32;o;o>>=1) v += __shfl_xor(v, o, 64);
  return v;
}

// argmax carrying (value, global-index tie-break, position meta)
__device__ __forceinline__ void wave_argmax3(float& v, int& j, int& p){
  #pragma unroll
  for (int o=32;o;o>>=1){
    float ov = __shfl_xor(v, o, 64);
    int   oj = __shfl_xor(j, o, 64);
    int   op = __shfl_xor(p, o, 64);
    if (ov > v || (ov == v && oj < j)) { v = ov; j = oj; p = op; }
  }
}

// full ascending bitonic sort across 64 lanes; lane 48 = 16th-largest
__device__ __forceinline__ float bitonic_sort64(float v, int lane){
  #pragma unroll
  for (int k=2;k<=64;k<<=1){
    #pragma unroll
    for (int j=k>>1;j>0;j>>=1){
      float o = __shfl_xor(v, j, 64);
      float mn = fminf(v,o), mx = fmaxf(v,o);
      bool upper = (lane & j) != 0;
      bool asc   = ((lane & k) == 0);
      v = (upper == asc) ? mx : mn;
    }
  }
  return v;
}

// 16q x 4j score accumulation over 64 d; q operand is WAVE-UNIFORM, read from
// global (scalar-cache s_load path); per-(q,j) fmaf chain sequential in d.
// Bit-identical ordering shared by k_tau and k3.
#define SCORE_LOOP_16x4_SQ() { \
  _Pragma("unroll 4") \
  for (int d=0; d<64; d++){ \
    float4 mv4 = *(const float4*)(rowbase + (size_t)d*NP); \
    float marr[4]={mv4.x,mv4.y,mv4.z,mv4.w}; \
    _Pragma("unroll") \
    for (int qi_=0;qi_<16;qi_++){ \
      float qv_ = qbase[qi_*64 + d]; \
      _Pragma("unroll") \
      for (int jj_=0;jj_<4;jj_++) s[qi_][jj_] = fmaf(qv_, marr[jj_], s[qi_][jj_]); \
    } \
  } }

// ---------------- K1: memory embeddings -> mwT (64 x NP), mm (fp32 stream path)
__global__ __launch_bounds__(128) void k1_mem(
    const float* __restrict__ mi,
    const float* __restrict__ w1, const float* __restrict__ b1,
    const float* __restrict__ w2, const float* __restrict__ b2,
    const float* __restrict__ fw,
    float* __restrict__ mwT, float* __restrict__ mm)
{
  __shared__ float xs[64*128];
  int t = threadIdx.x;
  int j = blockIdx.x*128 + t;
  bool real = (j < N_MEM);
  {
    const float4* xp = (const float4*)(mi + (size_t)(real ? j : 0)*64);
    #pragma unroll
    for (int k=0;k<16;k++){
      float4 v = xp[k];
      xs[(4*k+0)*128 + t] = v.x;
      xs[(4*k+1)*128 + t] = v.y;
      xs[(4*k+2)*128 + t] = v.z;
      xs[(4*k+3)*128 + t] = v.w;
    }
  }
  float h[64];
  #pragma unroll
  for (int e=0;e<64;e++) h[e] = b1[e];
  for (int d=0; d<64; d++){
    float xv = xs[d*128 + t];
    #pragma unroll
    for (int e=0;e<64;e++) h[e] = fmaf(xv, w1[d*64+e], h[e]);
  }
  #pragma unroll
  for (int e=0;e<64;e++){ h[e] = fmaxf(h[e], 0.f); xs[e*128 + t] = h[e]; }
  float o[64];
  #pragma unroll
  for (int e=0;e<64;e++) o[e] = b2[e];
  for (int d=0; d<64; d++){
    float hv = xs[d*128 + t];
    #pragma unroll
    for (int e=0;e<64;e++) o[e] = fmaf(hv, w2[d*64+e], o[e]);
  }
  float s2 = 0.f;
  #pragma unroll
  for (int e=0;e<64;e++){
    float sw = sqrtf(softplusf_(fw[e]) + 1e-9f);
    float v = real ? o[e]*sw : 0.f;
    s2 = fmaf(v, v, s2);
    mwT[(size_t)e*NP + j] = v;
  }
  mm[j] = real ? s2 : 3.0e38f;
}

// ---------------- K2: per-query f64 embedding/global/gate (ILP-4 chains); zero qcnt
__global__ __launch_bounds__(64) void k2_query(
  const float* __restrict__ x,
  const float* __restrict__ le_w1, const float* __restrict__ le_b1,
  const float* __restrict__ le_w2, const float* __restrict__ le_b2,
  const float* __restrict__ fw,
  const float* __restrict__ ge_w1, const float* __restrict__ ge_b1,
  const float* __restrict__ ge_w2, const float* __restrict__ ge_b2,
  const float* __restrict__ ge_w3, const float* __restrict__ ge_b3,
  const float* __restrict__ gr_w1, const float* __restrict__ gr_b1,
  const float* __restrict__ gr_w2, const float* __restrict__ gr_b2,
  const float* __restrict__ ga_w1, const float* __restrict__ ga_b1,
  const float* __restrict__ ga_w2, const float* __restrict__ ga_b2,
  float* __restrict__ qwf, double* __restrict__ qwd,
  double* __restrict__ qqd, double* __restrict__ ggd, double* __restrict__ gpd,
  int* __restrict__ qcnt)
{
  int l = threadIdx.x, q = blockIdx.x;
  if (l==0) qcnt[q] = 0;
  __shared__ double xs[64], qe[64], h1[128], t1[64], t2[64];
  xs[l] = (double)x[q*64+l];
  __syncthreads();
  double a0,a1,a2,a3,a;
  a0=a1=a2=a3=0.0;
  for (int d=0; d<64; d+=4){
    a0 = fma(xs[d  ], (double)le_w1[(d  )*64+l], a0);
    a1 = fma(xs[d+1], (double)le_w1[(d+1)*64+l], a1);
    a2 = fma(xs[d+2], (double)le_w1[(d+2)*64+l], a2);
    a3 = fma(xs[d+3], (double)le_w1[(d+3)*64+l], a3);
  }
  a = ((a0+a1)+(a2+a3)) + (double)le_b1[l];
  t1[l] = a > 0.0 ? a : 0.0;
  __syncthreads();
  a0=a1=a2=a3=0.0;
  for (int d=0; d<64; d+=4){
    a0 = fma(t1[d  ], (double)le_w2[(d  )*64+l], a0);
    a1 = fma(t1[d+1], (double)le_w2[(d+1)*64+l], a1);
    a2 = fma(t1[d+2], (double)le_w2[(d+2)*64+l], a2);
    a3 = fma(t1[d+3], (double)le_w2[(d+3)*64+l], a3);
  }
  a = ((a0+a1)+(a2+a3)) + (double)le_b2[l];
  qe[l] = a;
  double sw = sqrt(log1p(exp((double)fw[l])) + 1e-9);
  double qv = a * sw;
  qwd[q*64+l] = qv;
  qwf[q*64+l] = (float)qv;
  double ss = wave_sum_d(qv*qv);
  if (l==0) qqd[q] = ss;
  double b0=0,b1v=0,c0=0,c1=0;
  for (int d=0; d<64; d+=2){
    double x0 = xs[d], x1 = xs[d+1];
    b0  = fma(x0, (double)ge_w1[(d  )*128+l],    b0);
    b1v = fma(x1, (double)ge_w1[(d+1)*128+l],    b1v);
    c0  = fma(x0, (double)ge_w1[(d  )*128+64+l], c0);
    c1  = fma(x1, (double)ge_w1[(d+1)*128+64+l], c1);
  }
  a = (b0+b1v) + (double)ge_b1[l];
  double c = (c0+c1) + (double)ge_b1[64+l];
  h1[l] = a>0.0?a:0.0; h1[64+l] = c>0.0?c:0.0;
  __syncthreads();
  a0=a1=a2=a3=0.0;
  for (int d=0; d<128; d+=4){
    a0 = fma(h1[d  ], (double)ge_w2[(d  )*64+l], a0);
    a1 = fma(h1[d+1], (double)ge_w2[(d+1)*64+l], a1);
    a2 = fma(h1[d+2], (double)ge_w2[(d+2)*64+l], a2);
    a3 = fma(h1[d+3], (double)ge_w2[(d+3)*64+l], a3);
  }
  a = ((a0+a1)+(a2+a3)) + (double)ge_b2[l];
  __syncthreads();
  t1[l] = a>0.0?a:0.0;
  __syncthreads();
  a0=a1=a2=a3=0.0;
  for (int d=0; d<64; d+=4){
    a0 = fma(t1[d  ], (double)ge_w3[(d  )*64+l], a0);
    a1 = fma(t1[d+1], (double)ge_w3[(d+1)*64+l], a1);
    a2 = fma(t1[d+2], (double)ge_w3[(d+2)*64+l], a2);
    a3 = fma(t1[d+3], (double)ge_w3[(d+3)*64+l], a3);
  }
  a = ((a0+a1)+(a2+a3)) + (double)ge_b3[l];
  t2[l] = a;                // global_repr
  __syncthreads();
  a0=a1=a2=a3=0.0;
  for (int d=0; d<64; d+=4){
    a0 = fma(t2[d  ], (double)gr_w1[(d  )*64+l], a0);
    a1 = fma(t2[d+1], (double)gr_w1[(d+1)*64+l], a1);
    a2 = fma(t2[d+2], (double)gr_w1[(d+2)*64+l], a2);
    a3 = fma(t2[d+3], (double)gr_w1[(d+3)*64+l], a3);
  }
  a = ((a0+a1)+(a2+a3)) + (double)gr_b1[l];
  __syncthreads();
  t1[l] = a>0.0?a:0.0;
  __syncthreads();
  if (l < 8){
    a0=a1=a2=a3=0.0;
    for (int d=0; d<64; d+=4){
      a0 = fma(t1[d  ], (double)gr_w2[(d  )*8+l], a0);
      a1 = fma(t1[d+1], (double)gr_w2[(d+1)*8+l], a1);
      a2 = fma(t1[d+2], (double)gr_w2[(d+2)*8+l], a2);
      a3 = fma(t1[d+3], (double)gr_w2[(d+3)*8+l], a3);
    }
    gpd[q*8+l] = ((a0+a1)+(a2+a3)) + (double)gr_b2[l];
  }
  a0=a1=a2=a3=0.0;
  for (int d=0; d<64; d+=4){
    a0 = fma(t2[d  ], (double)ga_w1[(d  )*64+l], a0);
    a1 = fma(t2[d+1], (double)ga_w1[(d+1)*64+l], a1);
    a2 = fma(t2[d+2], (double)ga_w1[(d+2)*64+l], a2);
    a3 = fma(t2[d+3], (double)ga_w1[(d+3)*64+l], a3);
  }
  for (int d=0; d<64; d+=4){
    a0 = fma(qe[d  ], (double)ga_w1[(64+d  )*64+l], a0);
    a1 = fma(qe[d+1], (double)ga_w1[(64+d+1)*64+l], a1);
    a2 = fma(qe[d+2], (double)ga_w1[(64+d+2)*64+l], a2);
    a3 = fma(qe[d+3], (double)ga_w1[(64+d+3)*64+l], a3);
  }
  a = ((a0+a1)+(a2+a3)) + (double)ga_b1[l];
  a = a>0.0?a:0.0;
  double p = wave_sum_d(a * (double)ga_w2[l]);
  if (l==0) ggd[q] = 1.0/(1.0 + exp(-(p + (double)ga_b2[0])));
}

// ---------------- K_tau: dump sample scores (j in [0,4096)) bit-identical to k3
__global__ __launch_bounds__(256) void k_tau(
    const float* __restrict__ mwT, const float* __restrict__ mm,
    const float* __restrict__ qw, float* __restrict__ ssc)
{
  int t = threadIdx.x, w = t>>6, lane = t&63;
  int q0 = blockIdx.x*16;
  int jb = blockIdx.y*JBLK;
  const float* qbase = qw + (size_t)q0*64;   // wave-uniform -> scalar loads
  int jw = jb + w*256 + 4*lane;
  const float* rowbase = mwT + jw;
  float s[16][4];
  #pragma unroll
  for (int a=0;a<16;a++){
    #pragma unroll
    for (int b=0;b<4;b++) s[a][b]=0.f;
  }
  SCORE_LOOP_16x4_SQ();
  float4 mmv4 = *(const float4*)(mm + jw);
  float mmv[4] = {mmv4.x, mmv4.y, mmv4.z, mmv4.w};
  #pragma unroll
  for (int qi=0;qi<16;qi++){
    int qg = q0 + qi;
    float4 o0;
    o0.x = 2.f*s[qi][0]-mmv[0]; o0.y = 2.f*s[qi][1]-mmv[1];
    o0.z = 2.f*s[qi][2]-mmv[2]; o0.w = 2.f*s[qi][3]-mmv[3];
    *(float4*)(ssc + (size_t)qg*4096 + jw) = o0;
  }
}

// ---------------- K_tau_sel: exact 16th-largest of the 4096 sample scores per query
__global__ __launch_bounds__(256) void k_tau_sel(
    const float* __restrict__ ssc, float* __restrict__ tau)
{
  int t = threadIdx.x, w = t>>6, l = t&63, q = blockIdx.x;
  __shared__ unsigned su[4096];
  __shared__ int rs[4];
  const float* base = ssc + (size_t)q*4096;
  for (int i=t; i<4096; i+=256){
    unsigned f = __float_as_uint(base[i]);
    su[i] = f ^ ((f >> 31) ? 0xFFFFFFFFu : 0x80000000u);   // monotone key
  }
  __syncthreads();
  unsigned T = 0u;
  for (int b=31; b>=0; b--){
    unsigned cand = T | (1u<<b);
    int c = 0;
    for (int i=t; i<4096; i+=256) c += (su[i] >= cand) ? 1 : 0;
    c = wave_sum_i(c);
    if (l==0) rs[w] = c;
    __syncthreads();
    int tot = rs[0]+rs[1]+rs[2]+rs[3];
    if (tot >= 16) T = cand;
    __syncthreads();
  }
  if (t==0){
    unsigned f = (T & 0x80000000u) ? (T ^ 0x80000000u) : ~T;
    tau[q] = __uint_as_float(f);
  }
}

// ---------------- K3: all 98 j-blocks, filter >= tau - margin, append to buffer
__global__ __launch_bounds__(256) void k3_main(
    const float* __restrict__ mwT, const float* __restrict__ mm,
    const float* __restrict__ qw,  const float* __restrict__ tau,
    int* __restrict__ qcnt, float* __restrict__ qcv, int* __restrict__ qci)
{
  int t=threadIdx.x, w=t>>6, lane=t&63;
  int q0 = blockIdx.x*16;
  int jb = blockIdx.y*JBLK;
  __shared__ float taus[16];
  const float* qbase = qw + (size_t)q0*64;   // wave-uniform -> scalar loads
  if (t < 16){ taus[t] = tau[q0+t] - 5e-6f; }
  __syncthreads();
  int jw = jb + w*256 + 4*lane;
  const float* rowbase = mwT + jw;
  float s[16][4];
  #pragma unroll
  for (int a=0;a<16;a++){
    #pragma unroll
    for (int b=0;b<4;b++) s[a][b]=0.f;
  }
  SCORE_LOOP_16x4_SQ();
  float4 mmv4 = *(const float4*)(mm + jw);
  float mmv[4] = {mmv4.x, mmv4.y, mmv4.z, mmv4.w};
  #pragma unroll
  for (int qi=0;qi<16;qi++){
    float tq = taus[qi];
    int qg = q0 + qi;
    #pragma unroll
    for (int jj=0;jj<4;jj++){
      float sc = 2.f*s[qi][jj] - mmv[jj];
      if (sc >= tq){
        int p = atomicAdd(&qcnt[qg], 1);
        if (p < QCAP){
          qcv[(size_t)qg*QCAP+p] = sc;
          qci[(size_t)qg*QCAP+p] = jw + jj;
        }
      }
    }
  }
}

// ---------------- K4_pre: survivors -> v16 (lane-max bitonic) -> threshold compaction
__global__ __launch_bounds__(256) void k4_pre(
    const int* __restrict__ qcnt, const float* __restrict__ qcv, const int* __restrict__ qci,
    int* __restrict__ candjG, int* __restrict__ nc2G)
{
  int t = threadIdx.x, l = t&63, q = blockIdx.x;
  __shared__ float  svv[QCAP];
  __shared__ int    sii[QCAP];
  __shared__ float  v16s;
  __shared__ int    ncnt2;
  int NC = qcnt[q]; NC = NC < QCAP ? NC : QCAP;
  for (int i=t; i<NC; i+=256){ svv[i]=qcv[(size_t)q*QCAP+i]; sii[i]=qci[(size_t)q*QCAP+i]; }
  if (t==0) ncnt2 = 0;
  __syncthreads();
  if (t < 64){
    float vm = -3.0e38f;
    for (int i=l; i<NC; i+=64) vm = fmaxf(vm, svv[i]);
    vm = bitonic_sort64(vm, l);
    if (l == 48) v16s = vm;
  }
  __syncthreads();
  {
    float thr = v16s - 2e-6f;   // covers f32-stream vs f64 score discrepancy (~5e-7 worst)
    for (int i=t; i<NC; i+=256){
      if (svv[i] >= thr && (unsigned)sii[i] < (unsigned)N_MEM){
        int p = atomicAdd(&ncnt2, 1);
        if (p < NCAND) candjG[(size_t)q*NCAND + p] = sii[i];
      }
    }
  }
  __syncthreads();
  if (t==0) nc2G[q] = ncnt2 < NCAND ? ncnt2 : NCAND;
}

// ---------------- K4_emb: f64 re-rank of candidates; weights LDS-staged; 8 waves/query
__global__ __launch_bounds__(256) void k4_emb(
    const int* __restrict__ candjG, const int* __restrict__ nc2G,
    const double* __restrict__ qwd_g, const double* __restrict__ qqd_g,
    const float* __restrict__ mi,
    const float* __restrict__ le_w1, const float* __restrict__ le_b1,
    const float* __restrict__ le_w2, const float* __restrict__ le_b2,
    const float* __restrict__ fw, double* __restrict__ cd2G)
{
  int t = threadIdx.x, w = t>>6, l = t&63, q = blockIdx.x;
  __shared__ float  lw1[4096], lw2[4096];
  __shared__ double hdw[4][64];
  for (int i=t; i<4096; i+=256){ lw1[i]=le_w1[i]; lw2[i]=le_w2[i]; }
  __syncthreads();
  int NC2 = nc2G[q];
  double qwl = qwd_g[q*64+l];
  double swl = sqrt(log1p(exp((double)fw[l])) + 1e-9);
  double qq  = qqd_g[q];
  double lb1 = (double)le_b1[l], lb2 = (double)le_b2[l];
  for (int c = blockIdx.y*4 + w; c < NC2; c += 8){
    int jc = __builtin_amdgcn_readfirstlane(candjG[(size_t)q*NCAND + c]);
    const float* mrow = mi + (size_t)jc*64;   // wave-uniform -> s_load
    double b0=0,b1=0,b2=0,b3=0,b4=0,b5=0,b6=0,b7=0;
    #pragma unroll
    for (int d=0; d<64; d+=8){
      b0 = fma((double)mrow[d  ], (double)lw1[(d  )*64+l], b0);
      b1 = fma((double)mrow[d+1], (double)lw1[(d+1)*64+l], b1);
      b2 = fma((double)mrow[d+2], (double)lw1[(d+2)*64+l], b2);
      b3 = fma((double)mrow[d+3], (double)lw1[(d+3)*64+l], b3);
      b4 = fma((double)mrow[d+4], (double)lw1[(d+4)*64+l], b4);
      b5 = fma((double)mrow[d+5], (double)lw1[(d+5)*64+l], b5);
      b6 = fma((double)mrow[d+6], (double)lw1[(d+6)*64+l], b6);
      b7 = fma((double)mrow[d+7], (double)lw1[(d+7)*64+l], b7);
    }
    double h = (((b0+b1)+(b2+b3)) + ((b4+b5)+(b6+b7))) + lb1;
    h = h>0.0 ? h : 0.0;
    hdw[w][l] = h;   // wave-private; lockstep + lgkmcnt ordering suffice
    double c0=0,c1=0,c2=0,c3=0,c4=0,c5=0,c6=0,c7=0;
    #pragma unroll
    for (int d=0; d<64; d+=8){
      c0 = fma(hdw[w][d  ], (double)lw2[(d  )*64+l], c0);
      c1 = fma(hdw[w][d+1], (double)lw2[(d+1)*64+l], c1);
      c2 = fma(hdw[w][d+2], (double)lw2[(d+2)*64+l], c2);
      c3 = fma(hdw[w][d+3], (double)lw2[(d+3)*64+l], c3);
      c4 = fma(hdw[w][d+4], (double)lw2[(d+4)*64+l], c4);
      c5 = fma(hdw[w][d+5], (double)lw2[(d+5)*64+l], c5);
      c6 = fma(hdw[w][d+6], (double)lw2[(d+6)*64+l], c6);
      c7 = fma(hdw[w][d+7], (double)lw2[(d+7)*64+l], c7);
    }
    double o  = (((c0+c1)+(c2+c3)) + ((c4+c5)+(c6+c7))) + lb2;
    double mw = o * swl;
    double sc = wave_sum_d(mw*(mw - 2.0*qwl));
    if (l==0) cd2G[(size_t)q*NCAND + c] = qq + sc;
  }
}

// ---------------- K4_fin: f32-quantized select (raw desc, idx asc) -> softmax/blend/refine
__global__ __launch_bounds__(64) void k4_fin(
    const int* __restrict__ candjG, const int* __restrict__ nc2G,
    const double* __restrict__ cd2G,
    const double* __restrict__ ggd_g, const double* __restrict__ gpd_g,
    const float* __restrict__ mt, const float* __restrict__ itp,
    const float* __restrict__ rw1, const float* __restrict__ rb1,
    const float* __restrict__ rw2, const float* __restrict__ rb2,
    float* __restrict__ out)
{
  int l = threadIdx.x, q = blockIdx.x;
  __shared__ float  selr[16];
  __shared__ int    selj[16];
  __shared__ double hh[32];
  int NC2 = nc2G[q];
  {
    float e32  = (float)exp((double)itp[0]);
    float sp32 = (float)log1p((double)e32);
    float t32  = __fadd_rn(sp32, 1e-9f);
    float dn32 = __fadd_rn(t32, 1e-9f);
    double denom = (double)dn32;
    float r0=-2.f, r1=-2.f; int j0=0x7fffffff, j1=0x7fffffff;
    if (l < NC2){
      double d2 = cd2G[(size_t)q*NCAND + l]; if (d2 < 0.0) d2 = 0.0;
      float ratio32 = (float)(d2 / denom);
      r0 = (float)exp(-(double)ratio32);
      j0 = candjG[(size_t)q*NCAND + l];
    }
    if (l+64 < NC2){
      double d2 = cd2G[(size_t)q*NCAND + l+64]; if (d2 < 0.0) d2 = 0.0;
      float ratio32 = (float)(d2 / denom);
      r1 = (float)exp(-(double)ratio32);
      j1 = candjG[(size_t)q*NCAND + l+64];
    }
    bool u0=false, u1=false;
    for (int it=0; it<16; it++){
      float a0 = u0 ? -2.f : r0;
      float a1 = u1 ? -2.f : r1;
      float v; int j; int p;
      if (a0 > a1 || (a0 == a1 && j0 <= j1)) { v=a0; j=j0; p=l*2; }
      else                                   { v=a1; j=j1; p=l*2+1; }
      wave_argmax3(v, j, p);
      if ((p>>1) == l){ if (p&1) u1=true; else u0=true; }
      if (l == it){ selr[it]=v; selj[it]=j; }
    }
  }
  __syncthreads();
  double raw = (l<16) ? (double)selr[l] : -1.0e300;
  double mv = raw;
  #pragma unroll
  for (int o=32;o;o>>=1){ double ov = __shfl_xor(mv,o,64); mv = ov>mv?ov:mv; }
  double e  = (l<16) ? exp(raw - mv) : 0.0;
  double se = wave_sum_d(e);
  double wgt = e / se;
  double lp[8] = {0,0,0,0,0,0,0,0};
  if (l < 16){
    const float* tr = mt + (size_t)selj[l]*8;
    #pragma unroll
    for (int tt=0; tt<8; tt++) lp[tt] = wgt * (double)tr[tt];
  }
  #pragma unroll
  for (int tt=0; tt<8; tt++) lp[tt] = wave_sum_d(lp[tt]);
  double g = ggd_g[q];
  double bl[8];
  #pragma unroll
  for (int tt=0; tt<8; tt++) bl[tt] = g*lp[tt] + (1.0-g)*gpd_g[q*8+tt];
  if (l < 32){
    double a = (double)rb1[l];
    #pragma unroll
    for (int tt=0; tt<8; tt++) a = fma(bl[tt], (double)rw1[tt*32+l], a);
    hh[l] = a>0.0?a:0.0;
  }
  __syncthreads();
  if (l < 8){
    double a = (double)rb2[l];
    #pragma unroll
    for (int i=0; i<32; i++) a = fma(hh[i], (double)rw2[i*8+l], a);
    out[q*8+l] = (float)a;
  }
}

extern "C" void kernel_launch(void* const* d_in, const int* in_sizes, int n_in,
                              void* d_out, int out_size, void* d_ws, size_t ws_size,
                              hipStream_t stream)
{
  const float* x     = (const float*)d_in[0];
  const float* mi    = (const float*)d_in[1];
  const float* mt    = (const float*)d_in[2];
  const float* le_w1 = (const float*)d_in[3];
  const float* le_b1 = (const float*)d_in[4];
  const float* le_w2 = (const float*)d_in[5];
  const float* le_b2 = (const float*)d_in[6];
  const float* fw    = (const float*)d_in[7];
  const float* itp   = (const float*)d_in[8];
  const float* ge_w1 = (const float*)d_in[9];
  const float* ge_b1 = (const float*)d_in[10];
  const float* ge_w2 = (const float*)d_in[11];
  const float* ge_b2 = (const float*)d_in[12];
  const float* ge_w3 = (const float*)d_in[13];
  const float* ge_b3 = (const float*)d_in[14];
  const float* gr_w1 = (const float*)d_in[15];
  const float* gr_b1 = (const float*)d_in[16];
  const float* gr_w2 = (const float*)d_in[17];
  const float* gr_b2 = (const float*)d_in[18];
  const float* ga_w1 = (const float*)d_in[19];
  const float* ga_b1 = (const float*)d_in[20];
  const float* ga_w2 = (const float*)d_in[21];
  const float* ga_b2 = (const float*)d_in[22];
  const float* rh_w1 = (const float*)d_in[23];
  const float* rh_b1 = (const float*)d_in[24];
  const float* rh_w2 = (const float*)d_in[25];
  const float* rh_b2 = (const float*)d_in[26];

  double* dws = (double*)d_ws;
  double* qwd = dws;                                // 1024*64
  double* qqd = qwd + (size_t)1024*64;              // 1024
  double* ggd = qqd + 1024;                         // 1024
  double* gpd = ggd + 1024;                         // 8192
  double* cd2G= gpd + 8192;                         // 1024*128
  float*  fws = (float*)(cd2G + (size_t)1024*128);
  float* mwT = fws;                                 // 64*NP
  float* mm  = mwT + (size_t)64*NP;                 // NP
  float* qwf = mm  + NP;                            // 1024*64
  float* tau = qwf + (size_t)1024*64;               // 1024
  float* ssc = tau + 1024;                          // 1024*4096
  int*   qcnt= (int*)(ssc + (size_t)1024*4096);     // 1024
  float* qcv = (float*)(qcnt + 1024);               // 1024*QCAP
  int*   qci = (int*)(qcv + (size_t)1024*QCAP);     // 1024*QCAP
  int*   candjG = qci + (size_t)1024*QCAP;          // 1024*128
  int*   nc2G   = candjG + (size_t)1024*NCAND;      // 1024

  k1_mem    <<<dim3(NP/128), dim3(128), 0, stream>>>(mi, le_w1, le_b1, le_w2, le_b2, fw, mwT, mm);
  k2_query  <<<dim3(1024),   dim3(64),  0, stream>>>(x, le_w1, le_b1, le_w2, le_b2, fw,
                ge_w1, ge_b1, ge_w2, ge_b2, ge_w3, ge_b3,
                gr_w1, gr_b1, gr_w2, gr_b2,
                ga_w1, ga_b1, ga_w2, ga_b2,
                qwf, qwd, qqd, ggd, gpd, qcnt);
  k_tau     <<<dim3(64,4),   dim3(256), 0, stream>>>(mwT, mm, qwf, ssc);
  k_tau_sel <<<dim3(1024),   dim3(256), 0, stream>>>(ssc, tau);
  k3_main   <<<dim3(64,NJB), dim3(256), 0, stream>>>(mwT, mm, qwf, tau, qcnt, qcv, qci);
  k4_pre    <<<dim3(1024),   dim3(256), 0, stream>>>(qcnt, qcv, qci, candjG, nc2G);
  k4_emb    <<<dim3(1024,2), dim3(256), 0, stream>>>(candjG, nc2G, qwd, qqd, mi,
                le_w1, le_b1, le_w2, le_b2, fw, cd2G);
  k4_fin    <<<dim3(1024),   dim3(64),  0, stream>>>(candjG, nc2G, cd2G, ggd, gpd, mt, itp,
                rh_w1, rh_b1, rh_w2, rh_b2, (float*)d_out);
}

// Round 16
// 469.439 us; speedup vs baseline: 7.9168x; 1.1032x over previous
//
#include <hip/hip_runtime.h>
#include <math.h>

#define N_MEM 100000
#define NP    100352      // 98 * 1024 (padded)
#define JBLK  1024
#define NJB   98
#define QCAP  1024        // per-query survivor buffer (expected ~390)
#define NCAND 128         // max re-rank set size

__device__ __forceinline__ float softplusf_(float x){ return log1pf(expf(x)); }

__device__ __forceinline__ double wave_sum_d(double v){
  #pragma unroll
  for (int o=32;o;o>>=1) v += __shfl_xor(v, o, 64);
  return v;
}
__device__ __forceinline__ int wave_sum_i(int v){
  #pragma unroll
  for (int o=32;o;o>>=1) v += __shfl_xor(v, o, 64);
  return v;
}

// argmax carrying (value, global-index tie-break, position meta)
__device__ __forceinline__ void wave_argmax3(float& v, int& j, int& p){
  #pragma unroll
  for (int o=32;o;o>>=1){
    float ov = __shfl_xor(v, o, 64);
    int   oj = __shfl_xor(j, o, 64);
    int   op = __shfl_xor(p, o, 64);
    if (ov > v || (ov == v && oj < j)) { v = ov; j = oj; p = op; }
  }
}

// full ascending bitonic sort across 64 lanes; lane 48 = 16th-largest
__device__ __forceinline__ float bitonic_sort64(float v, int lane){
  #pragma unroll
  for (int k=2;k<=64;k<<=1){
    #pragma unroll
    for (int j=k>>1;j>0;j>>=1){
      float o = __shfl_xor(v, j, 64);
      float mn = fminf(v,o), mx = fmaxf(v,o);
      bool upper = (lane & j) != 0;
      bool asc   = ((lane & k) == 0);
      v = (upper == asc) ? mx : mn;
    }
  }
  return v;
}

// 16q x 4j score accumulation over 64 d; q operand is WAVE-UNIFORM, read from
// global (scalar-cache s_load path); per-(q,j) fmaf chain sequential in d.
// Bit-identical ordering shared by k_tau and k3.
#define SCORE_LOOP_16x4_SQ() { \
  _Pragma("unroll 4") \
  for (int d=0; d<64; d++){ \
    float4 mv4 = *(const float4*)(rowbase + (size_t)d*NP); \
    float marr[4]={mv4.x,mv4.y,mv4.z,mv4.w}; \
    _Pragma("unroll") \
    for (int qi_=0;qi_<16;qi_++){ \
      float qv_ = qbase[qi_*64 + d]; \
      _Pragma("unroll") \
      for (int jj_=0;jj_<4;jj_++) s[qi_][jj_] = fmaf(qv_, marr[jj_], s[qi_][jj_]); \
    } \
  } }

// ---------------- K1 (k3-style tiles): memory embeddings -> mwT (64 x NP), mm
// block: 128 points, 256 thr; wave w owns output-chunk e0=w*16; lane owns 2 points.
// Per-element FMA chains (bias-init, d-ascending) bit-identical to original k1;
// mm uses 4 sequential partials (rounding-free change: self-consistent pipeline).
__global__ __launch_bounds__(256) void k1_mem(
    const float* __restrict__ mi,
    const float* __restrict__ w1, const float* __restrict__ b1,
    const float* __restrict__ w2, const float* __restrict__ b2,
    const float* __restrict__ fw,
    float* __restrict__ mwT, float* __restrict__ mm)
{
  __shared__ float xs[64*132];     // [d][j] layer-1 input; reused as [e][j] for layer-2
  __shared__ float mms[4][132];
  int t = threadIdx.x, w = t>>6, lane = t&63;
  int jb = blockIdx.x*128;
  {
    int jl = t & 127; int j = jb + jl; int d0 = (t>>7)*32;
    bool real = (j < N_MEM);
    const float4* xp = (const float4*)(mi + (size_t)(real?j:0)*64 + d0);
    #pragma unroll
    for (int k=0;k<8;k++){
      float4 v = xp[k];
      if (!real){ v.x=0.f; v.y=0.f; v.z=0.f; v.w=0.f; }
      xs[(d0+4*k+0)*132 + jl] = v.x;
      xs[(d0+4*k+1)*132 + jl] = v.y;
      xs[(d0+4*k+2)*132 + jl] = v.z;
      xs[(d0+4*k+3)*132 + jl] = v.w;
    }
  }
  __syncthreads();
  int e0 = w*16;
  int jc = 2*lane;
  float s[16][2];
  #pragma unroll
  for (int qi=0;qi<16;qi++){ float b = b1[e0+qi]; s[qi][0]=b; s[qi][1]=b; }
  for (int d=0; d<64; d++){
    float x0 = xs[d*132 + jc], x1 = xs[d*132 + jc+1];
    #pragma unroll
    for (int qi=0;qi<16;qi++){
      float wv = w1[d*64 + e0 + qi];
      s[qi][0] = fmaf(x0, wv, s[qi][0]);
      s[qi][1] = fmaf(x1, wv, s[qi][1]);
    }
  }
  __syncthreads();   // all xs reads complete
  #pragma unroll
  for (int qi=0;qi<16;qi++){
    xs[(e0+qi)*132 + jc]   = fmaxf(s[qi][0], 0.f);
    xs[(e0+qi)*132 + jc+1] = fmaxf(s[qi][1], 0.f);
  }
  __syncthreads();
  #pragma unroll
  for (int qi=0;qi<16;qi++){ float b = b2[e0+qi]; s[qi][0]=b; s[qi][1]=b; }
  for (int d=0; d<64; d++){
    float x0 = xs[d*132 + jc], x1 = xs[d*132 + jc+1];
    #pragma unroll
    for (int qi=0;qi<16;qi++){
      float wv = w2[d*64 + e0 + qi];
      s[qi][0] = fmaf(x0, wv, s[qi][0]);
      s[qi][1] = fmaf(x1, wv, s[qi][1]);
    }
  }
  int j0g = jb + jc;
  bool r0 = (j0g < N_MEM), r1 = (j0g+1 < N_MEM);
  float p0 = 0.f, p1 = 0.f;
  #pragma unroll
  for (int qi=0;qi<16;qi++){
    int e = e0 + qi;
    float sw = sqrtf(softplusf_(fw[e]) + 1e-9f);
    float v0 = r0 ? s[qi][0]*sw : 0.f;
    float v1 = r1 ? s[qi][1]*sw : 0.f;
    p0 = fmaf(v0,v0,p0);
    p1 = fmaf(v1,v1,p1);
    float2 o2; o2.x = v0; o2.y = v1;
    *(float2*)(mwT + (size_t)e*NP + j0g) = o2;
  }
  mms[w][jc] = p0; mms[w][jc+1] = p1;
  __syncthreads();
  if (t < 128){
    int j = jb + t;
    float v = ((mms[0][t] + mms[1][t]) + mms[2][t]) + mms[3][t];
    mm[j] = (j < N_MEM) ? v : 3.0e38f;
  }
}

// ---------------- K2: per-query f64 embedding/global/gate (ILP-4 chains); zero qcnt
__global__ __launch_bounds__(64) void k2_query(
  const float* __restrict__ x,
  const float* __restrict__ le_w1, const float* __restrict__ le_b1,
  const float* __restrict__ le_w2, const float* __restrict__ le_b2,
  const float* __restrict__ fw,
  const float* __restrict__ ge_w1, const float* __restrict__ ge_b1,
  const float* __restrict__ ge_w2, const float* __restrict__ ge_b2,
  const float* __restrict__ ge_w3, const float* __restrict__ ge_b3,
  const float* __restrict__ gr_w1, const float* __restrict__ gr_b1,
  const float* __restrict__ gr_w2, const float* __restrict__ gr_b2,
  const float* __restrict__ ga_w1, const float* __restrict__ ga_b1,
  const float* __restrict__ ga_w2, const float* __restrict__ ga_b2,
  float* __restrict__ qwf, double* __restrict__ qwd,
  double* __restrict__ qqd, double* __restrict__ ggd, double* __restrict__ gpd,
  int* __restrict__ qcnt)
{
  int l = threadIdx.x, q = blockIdx.x;
  if (l==0) qcnt[q] = 0;
  __shared__ double xs[64], qe[64], h1[128], t1[64], t2[64];
  xs[l] = (double)x[q*64+l];
  __syncthreads();
  double a0,a1,a2,a3,a;
  a0=a1=a2=a3=0.0;
  for (int d=0; d<64; d+=4){
    a0 = fma(xs[d  ], (double)le_w1[(d  )*64+l], a0);
    a1 = fma(xs[d+1], (double)le_w1[(d+1)*64+l], a1);
    a2 = fma(xs[d+2], (double)le_w1[(d+2)*64+l], a2);
    a3 = fma(xs[d+3], (double)le_w1[(d+3)*64+l], a3);
  }
  a = ((a0+a1)+(a2+a3)) + (double)le_b1[l];
  t1[l] = a > 0.0 ? a : 0.0;
  __syncthreads();
  a0=a1=a2=a3=0.0;
  for (int d=0; d<64; d+=4){
    a0 = fma(t1[d  ], (double)le_w2[(d  )*64+l], a0);
    a1 = fma(t1[d+1], (double)le_w2[(d+1)*64+l], a1);
    a2 = fma(t1[d+2], (double)le_w2[(d+2)*64+l], a2);
    a3 = fma(t1[d+3], (double)le_w2[(d+3)*64+l], a3);
  }
  a = ((a0+a1)+(a2+a3)) + (double)le_b2[l];
  qe[l] = a;
  double sw = sqrt(log1p(exp((double)fw[l])) + 1e-9);
  double qv = a * sw;
  qwd[q*64+l] = qv;
  qwf[q*64+l] = (float)qv;
  double ss = wave_sum_d(qv*qv);
  if (l==0) qqd[q] = ss;
  double b0=0,b1v=0,c0=0,c1=0;
  for (int d=0; d<64; d+=2){
    double x0 = xs[d], x1 = xs[d+1];
    b0  = fma(x0, (double)ge_w1[(d  )*128+l],    b0);
    b1v = fma(x1, (double)ge_w1[(d+1)*128+l],    b1v);
    c0  = fma(x0, (double)ge_w1[(d  )*128+64+l], c0);
    c1  = fma(x1, (double)ge_w1[(d+1)*128+64+l], c1);
  }
  a = (b0+b1v) + (double)ge_b1[l];
  double c = (c0+c1) + (double)ge_b1[64+l];
  h1[l] = a>0.0?a:0.0; h1[64+l] = c>0.0?c:0.0;
  __syncthreads();
  a0=a1=a2=a3=0.0;
  for (int d=0; d<128; d+=4){
    a0 = fma(h1[d  ], (double)ge_w2[(d  )*64+l], a0);
    a1 = fma(h1[d+1], (double)ge_w2[(d+1)*64+l], a1);
    a2 = fma(h1[d+2], (double)ge_w2[(d+2)*64+l], a2);
    a3 = fma(h1[d+3], (double)ge_w2[(d+3)*64+l], a3);
  }
  a = ((a0+a1)+(a2+a3)) + (double)ge_b2[l];
  __syncthreads();
  t1[l] = a>0.0?a:0.0;
  __syncthreads();
  a0=a1=a2=a3=0.0;
  for (int d=0; d<64; d+=4){
    a0 = fma(t1[d  ], (double)ge_w3[(d  )*64+l], a0);
    a1 = fma(t1[d+1], (double)ge_w3[(d+1)*64+l], a1);
    a2 = fma(t1[d+2], (double)ge_w3[(d+2)*64+l], a2);
    a3 = fma(t1[d+3], (double)ge_w3[(d+3)*64+l], a3);
  }
  a = ((a0+a1)+(a2+a3)) + (double)ge_b3[l];
  t2[l] = a;                // global_repr
  __syncthreads();
  a0=a1=a2=a3=0.0;
  for (int d=0; d<64; d+=4){
    a0 = fma(t2[d  ], (double)gr_w1[(d  )*64+l], a0);
    a1 = fma(t2[d+1], (double)gr_w1[(d+1)*64+l], a1);
    a2 = fma(t2[d+2], (double)gr_w1[(d+2)*64+l], a2);
    a3 = fma(t2[d+3], (double)gr_w1[(d+3)*64+l], a3);
  }
  a = ((a0+a1)+(a2+a3)) + (double)gr_b1[l];
  __syncthreads();
  t1[l] = a>0.0?a:0.0;
  __syncthreads();
  if (l < 8){
    a0=a1=a2=a3=0.0;
    for (int d=0; d<64; d+=4){
      a0 = fma(t1[d  ], (double)gr_w2[(d  )*8+l], a0);
      a1 = fma(t1[d+1], (double)gr_w2[(d+1)*8+l], a1);
      a2 = fma(t1[d+2], (double)gr_w2[(d+2)*8+l], a2);
      a3 = fma(t1[d+3], (double)gr_w2[(d+3)*8+l], a3);
    }
    gpd[q*8+l] = ((a0+a1)+(a2+a3)) + (double)gr_b2[l];
  }
  a0=a1=a2=a3=0.0;
  for (int d=0; d<64; d+=4){
    a0 = fma(t2[d  ], (double)ga_w1[(d  )*64+l], a0);
    a1 = fma(t2[d+1], (double)ga_w1[(d+1)*64+l], a1);
    a2 = fma(t2[d+2], (double)ga_w1[(d+2)*64+l], a2);
    a3 = fma(t2[d+3], (double)ga_w1[(d+3)*64+l], a3);
  }
  for (int d=0; d<64; d+=4){
    a0 = fma(qe[d  ], (double)ga_w1[(64+d  )*64+l], a0);
    a1 = fma(qe[d+1], (double)ga_w1[(64+d+1)*64+l], a1);
    a2 = fma(qe[d+2], (double)ga_w1[(64+d+2)*64+l], a2);
    a3 = fma(qe[d+3], (double)ga_w1[(64+d+3)*64+l], a3);
  }
  a = ((a0+a1)+(a2+a3)) + (double)ga_b1[l];
  a = a>0.0?a:0.0;
  double p = wave_sum_d(a * (double)ga_w2[l]);
  if (l==0) ggd[q] = 1.0/(1.0 + exp(-(p + (double)ga_b2[0])));
}

// ---------------- K_tau: dump sample scores (j in [0,4096)) bit-identical to k3
__global__ __launch_bounds__(256) void k_tau(
    const float* __restrict__ mwT, const float* __restrict__ mm,
    const float* __restrict__ qw, float* __restrict__ ssc)
{
  int t = threadIdx.x, w = t>>6, lane = t&63;
  int q0 = blockIdx.x*16;
  int jb = blockIdx.y*JBLK;
  const float* qbase = qw + (size_t)q0*64;   // wave-uniform -> scalar loads
  int jw = jb + w*256 + 4*lane;
  const float* rowbase = mwT + jw;
  float s[16][4];
  #pragma unroll
  for (int a=0;a<16;a++){
    #pragma unroll
    for (int b=0;b<4;b++) s[a][b]=0.f;
  }
  SCORE_LOOP_16x4_SQ();
  float4 mmv4 = *(const float4*)(mm + jw);
  float mmv[4] = {mmv4.x, mmv4.y, mmv4.z, mmv4.w};
  #pragma unroll
  for (int qi=0;qi<16;qi++){
    int qg = q0 + qi;
    float4 o0;
    o0.x = 2.f*s[qi][0]-mmv[0]; o0.y = 2.f*s[qi][1]-mmv[1];
    o0.z = 2.f*s[qi][2]-mmv[2]; o0.w = 2.f*s[qi][3]-mmv[3];
    *(float4*)(ssc + (size_t)qg*4096 + jw) = o0;
  }
}

// ---------------- K_tau_sel: exact 16th-largest of the 4096 sample scores per query
__global__ __launch_bounds__(256) void k_tau_sel(
    const float* __restrict__ ssc, float* __restrict__ tau)
{
  int t = threadIdx.x, w = t>>6, l = t&63, q = blockIdx.x;
  __shared__ unsigned su[4096];
  __shared__ int rs[4];
  const float* base = ssc + (size_t)q*4096;
  for (int i=t; i<4096; i+=256){
    unsigned f = __float_as_uint(base[i]);
    su[i] = f ^ ((f >> 31) ? 0xFFFFFFFFu : 0x80000000u);   // monotone key
  }
  __syncthreads();
  unsigned T = 0u;
  for (int b=31; b>=0; b--){
    unsigned cand = T | (1u<<b);
    int c = 0;
    for (int i=t; i<4096; i+=256) c += (su[i] >= cand) ? 1 : 0;
    c = wave_sum_i(c);
    if (l==0) rs[w] = c;
    __syncthreads();
    int tot = rs[0]+rs[1]+rs[2]+rs[3];
    if (tot >= 16) T = cand;
    __syncthreads();
  }
  if (t==0){
    unsigned f = (T & 0x80000000u) ? (T ^ 0x80000000u) : ~T;
    tau[q] = __uint_as_float(f);
  }
}

// ---------------- K3: all 98 j-blocks, filter >= tau - margin, append to buffer
__global__ __launch_bounds__(256) void k3_main(
    const float* __restrict__ mwT, const float* __restrict__ mm,
    const float* __restrict__ qw,  const float* __restrict__ tau,
    int* __restrict__ qcnt, float* __restrict__ qcv, int* __restrict__ qci)
{
  int t=threadIdx.x, w=t>>6, lane=t&63;
  int q0 = blockIdx.x*16;
  int jb = blockIdx.y*JBLK;
  __shared__ float taus[16];
  const float* qbase = qw + (size_t)q0*64;   // wave-uniform -> scalar loads
  if (t < 16){ taus[t] = tau[q0+t] - 5e-6f; }
  __syncthreads();
  int jw = jb + w*256 + 4*lane;
  const float* rowbase = mwT + jw;
  float s[16][4];
  #pragma unroll
  for (int a=0;a<16;a++){
    #pragma unroll
    for (int b=0;b<4;b++) s[a][b]=0.f;
  }
  SCORE_LOOP_16x4_SQ();
  float4 mmv4 = *(const float4*)(mm + jw);
  float mmv[4] = {mmv4.x, mmv4.y, mmv4.z, mmv4.w};
  #pragma unroll
  for (int qi=0;qi<16;qi++){
    float tq = taus[qi];
    int qg = q0 + qi;
    #pragma unroll
    for (int jj=0;jj<4;jj++){
      float sc = 2.f*s[qi][jj] - mmv[jj];
      if (sc >= tq){
        int p = atomicAdd(&qcnt[qg], 1);
        if (p < QCAP){
          qcv[(size_t)qg*QCAP+p] = sc;
          qci[(size_t)qg*QCAP+p] = jw + jj;
        }
      }
    }
  }
}

// ---------------- K4_pre: survivors -> v16 (lane-max bitonic) -> threshold compaction
__global__ __launch_bounds__(256) void k4_pre(
    const int* __restrict__ qcnt, const float* __restrict__ qcv, const int* __restrict__ qci,
    int* __restrict__ candjG, int* __restrict__ nc2G)
{
  int t = threadIdx.x, l = t&63, q = blockIdx.x;
  __shared__ float  svv[QCAP];
  __shared__ int    sii[QCAP];
  __shared__ float  v16s;
  __shared__ int    ncnt2;
  int NC = qcnt[q]; NC = NC < QCAP ? NC : QCAP;
  for (int i=t; i<NC; i+=256){ svv[i]=qcv[(size_t)q*QCAP+i]; sii[i]=qci[(size_t)q*QCAP+i]; }
  if (t==0) ncnt2 = 0;
  __syncthreads();
  if (t < 64){
    float vm = -3.0e38f;
    for (int i=l; i<NC; i+=64) vm = fmaxf(vm, svv[i]);
    vm = bitonic_sort64(vm, l);
    if (l == 48) v16s = vm;
  }
  __syncthreads();
  {
    float thr = v16s - 2e-6f;   // covers f32-stream vs f64 score discrepancy (~5e-7 worst)
    for (int i=t; i<NC; i+=256){
      if (svv[i] >= thr && (unsigned)sii[i] < (unsigned)N_MEM){
        int p = atomicAdd(&ncnt2, 1);
        if (p < NCAND) candjG[(size_t)q*NCAND + p] = sii[i];
      }
    }
  }
  __syncthreads();
  if (t==0) nc2G[q] = ncnt2 < NCAND ? ncnt2 : NCAND;
}

// ---------------- K4_emb: f64 re-rank of candidates; weights LDS-staged; 8 waves/query
__global__ __launch_bounds__(256) void k4_emb(
    const int* __restrict__ candjG, const int* __restrict__ nc2G,
    const double* __restrict__ qwd_g, const double* __restrict__ qqd_g,
    const float* __restrict__ mi,
    const float* __restrict__ le_w1, const float* __restrict__ le_b1,
    const float* __restrict__ le_w2, const float* __restrict__ le_b2,
    const float* __restrict__ fw, double* __restrict__ cd2G)
{
  int t = threadIdx.x, w = t>>6, l = t&63, q = blockIdx.x;
  __shared__ float  lw1[4096], lw2[4096];
  __shared__ double hdw[4][64];
  for (int i=t; i<4096; i+=256){ lw1[i]=le_w1[i]; lw2[i]=le_w2[i]; }
  __syncthreads();
  int NC2 = nc2G[q];
  double qwl = qwd_g[q*64+l];
  double swl = sqrt(log1p(exp((double)fw[l])) + 1e-9);
  double qq  = qqd_g[q];
  double lb1 = (double)le_b1[l], lb2 = (double)le_b2[l];
  for (int c = blockIdx.y*4 + w; c < NC2; c += 8){
    int jc = __builtin_amdgcn_readfirstlane(candjG[(size_t)q*NCAND + c]);
    const float* mrow = mi + (size_t)jc*64;   // wave-uniform -> s_load
    double b0=0,b1=0,b2=0,b3=0,b4=0,b5=0,b6=0,b7=0;
    #pragma unroll
    for (int d=0; d<64; d+=8){
      b0 = fma((double)mrow[d  ], (double)lw1[(d  )*64+l], b0);
      b1 = fma((double)mrow[d+1], (double)lw1[(d+1)*64+l], b1);
      b2 = fma((double)mrow[d+2], (double)lw1[(d+2)*64+l], b2);
      b3 = fma((double)mrow[d+3], (double)lw1[(d+3)*64+l], b3);
      b4 = fma((double)mrow[d+4], (double)lw1[(d+4)*64+l], b4);
      b5 = fma((double)mrow[d+5], (double)lw1[(d+5)*64+l], b5);
      b6 = fma((double)mrow[d+6], (double)lw1[(d+6)*64+l], b6);
      b7 = fma((double)mrow[d+7], (double)lw1[(d+7)*64+l], b7);
    }
    double h = (((b0+b1)+(b2+b3)) + ((b4+b5)+(b6+b7))) + lb1;
    h = h>0.0 ? h : 0.0;
    hdw[w][l] = h;   // wave-private; lockstep + lgkmcnt ordering suffice
    double c0=0,c1=0,c2=0,c3=0,c4=0,c5=0,c6=0,c7=0;
    #pragma unroll
    for (int d=0; d<64; d+=8){
      c0 = fma(hdw[w][d  ], (double)lw2[(d  )*64+l], c0);
      c1 = fma(hdw[w][d+1], (double)lw2[(d+1)*64+l], c1);
      c2 = fma(hdw[w][d+2], (double)lw2[(d+2)*64+l], c2);
      c3 = fma(hdw[w][d+3], (double)lw2[(d+3)*64+l], c3);
      c4 = fma(hdw[w][d+4], (double)lw2[(d+4)*64+l], c4);
      c5 = fma(hdw[w][d+5], (double)lw2[(d+5)*64+l], c5);
      c6 = fma(hdw[w][d+6], (double)lw2[(d+6)*64+l], c6);
      c7 = fma(hdw[w][d+7], (double)lw2[(d+7)*64+l], c7);
    }
    double o  = (((c0+c1)+(c2+c3)) + ((c4+c5)+(c6+c7))) + lb2;
    double mw = o * swl;
    double sc = wave_sum_d(mw*(mw - 2.0*qwl));
    if (l==0) cd2G[(size_t)q*NCAND + c] = qq + sc;
  }
}

// ---------------- K4_fin: f32-quantized select (raw desc, idx asc) -> softmax/blend/refine
__global__ __launch_bounds__(64) void k4_fin(
    const int* __restrict__ candjG, const int* __restrict__ nc2G,
    const double* __restrict__ cd2G,
    const double* __restrict__ ggd_g, const double* __restrict__ gpd_g,
    const float* __restrict__ mt, const float* __restrict__ itp,
    const float* __restrict__ rw1, const float* __restrict__ rb1,
    const float* __restrict__ rw2, const float* __restrict__ rb2,
    float* __restrict__ out)
{
  int l = threadIdx.x, q = blockIdx.x;
  __shared__ float  selr[16];
  __shared__ int    selj[16];
  __shared__ double hh[32];
  int NC2 = nc2G[q];
  {
    float e32  = (float)exp((double)itp[0]);
    float sp32 = (float)log1p((double)e32);
    float t32  = __fadd_rn(sp32, 1e-9f);
    float dn32 = __fadd_rn(t32, 1e-9f);
    double denom = (double)dn32;
    float r0=-2.f, r1=-2.f; int j0=0x7fffffff, j1=0x7fffffff;
    if (l < NC2){
      double d2 = cd2G[(size_t)q*NCAND + l]; if (d2 < 0.0) d2 = 0.0;
      float ratio32 = (float)(d2 / denom);
      r0 = (float)exp(-(double)ratio32);
      j0 = candjG[(size_t)q*NCAND + l];
    }
    if (l+64 < NC2){
      double d2 = cd2G[(size_t)q*NCAND + l+64]; if (d2 < 0.0) d2 = 0.0;
      float ratio32 = (float)(d2 / denom);
      r1 = (float)exp(-(double)ratio32);
      j1 = candjG[(size_t)q*NCAND + l+64];
    }
    bool u0=false, u1=false;
    for (int it=0; it<16; it++){
      float a0 = u0 ? -2.f : r0;
      float a1 = u1 ? -2.f : r1;
      float v; int j; int p;
      if (a0 > a1 || (a0 == a1 && j0 <= j1)) { v=a0; j=j0; p=l*2; }
      else                                   { v=a1; j=j1; p=l*2+1; }
      wave_argmax3(v, j, p);
      if ((p>>1) == l){ if (p&1) u1=true; else u0=true; }
      if (l == it){ selr[it]=v; selj[it]=j; }
    }
  }
  __syncthreads();
  double raw = (l<16) ? (double)selr[l] : -1.0e300;
  double mv = raw;
  #pragma unroll
  for (int o=32;o;o>>=1){ double ov = __shfl_xor(mv,o,64); mv = ov>mv?ov:mv; }
  double e  = (l<16) ? exp(raw - mv) : 0.0;
  double se = wave_sum_d(e);
  double wgt = e / se;
  double lp[8] = {0,0,0,0,0,0,0,0};
  if (l < 16){
    const float* tr = mt + (size_t)selj[l]*8;
    #pragma unroll
    for (int tt=0; tt<8; tt++) lp[tt] = wgt * (double)tr[tt];
  }
  #pragma unroll
  for (int tt=0; tt<8; tt++) lp[tt] = wave_sum_d(lp[tt]);
  double g = ggd_g[q];
  double bl[8];
  #pragma unroll
  for (int tt=0; tt<8; tt++) bl[tt] = g*lp[tt] + (1.0-g)*gpd_g[q*8+tt];
  if (l < 32){
    double a = (double)rb1[l];
    #pragma unroll
    for (int tt=0; tt<8; tt++) a = fma(bl[tt], (double)rw1[tt*32+l], a);
    hh[l] = a>0.0?a:0.0;
  }
  __syncthreads();
  if (l < 8){
    double a = (double)rb2[l];
    #pragma unroll
    for (int i=0; i<32; i++) a = fma(hh[i], (double)rw2[i*8+l], a);
    out[q*8+l] = (float)a;
  }
}

extern "C" void kernel_launch(void* const* d_in, const int* in_sizes, int n_in,
                              void* d_out, int out_size, void* d_ws, size_t ws_size,
                              hipStream_t stream)
{
  const float* x     = (const float*)d_in[0];
  const float* mi    = (const float*)d_in[1];
  const float* mt    = (const float*)d_in[2];
  const float* le_w1 = (const float*)d_in[3];
  const float* le_b1 = (const float*)d_in[4];
  const float* le_w2 = (const float*)d_in[5];
  const float* le_b2 = (const float*)d_in[6];
  const float* fw    = (const float*)d_in[7];
  const float* itp   = (const float*)d_in[8];
  const float* ge_w1 = (const float*)d_in[9];
  const float* ge_b1 = (const float*)d_in[10];
  const float* ge_w2 = (const float*)d_in[11];
  const float* ge_b2 = (const float*)d_in[12];
  const float* ge_w3 = (const float*)d_in[13];
  const float* ge_b3 = (const float*)d_in[14];
  const float* gr_w1 = (const float*)d_in[15];
  const float* gr_b1 = (const float*)d_in[16];
  const float* gr_w2 = (const float*)d_in[17];
  const float* gr_b2 = (const float*)d_in[18];
  const float* ga_w1 = (const float*)d_in[19];
  const float* ga_b1 = (const float*)d_in[20];
  const float* ga_w2 = (const float*)d_in[21];
  const float* ga_b2 = (const float*)d_in[22];
  const float* rh_w1 = (const float*)d_in[23];
  const float* rh_b1 = (const float*)d_in[24];
  const float* rh_w2 = (const float*)d_in[25];
  const float* rh_b2 = (const float*)d_in[26];

  double* dws = (double*)d_ws;
  double* qwd = dws;                                // 1024*64
  double* qqd = qwd + (size_t)1024*64;              // 1024
  double* ggd = qqd + 1024;                         // 1024
  double* gpd = ggd + 1024;                         // 8192
  double* cd2G= gpd + 8192;                         // 1024*128
  float*  fws = (float*)(cd2G + (size_t)1024*128);
  float* mwT = fws;                                 // 64*NP
  float* mm  = mwT + (size_t)64*NP;                 // NP
  float* qwf = mm  + NP;                            // 1024*64
  float* tau = qwf + (size_t)1024*64;               // 1024
  float* ssc = tau + 1024;                          // 1024*4096
  int*   qcnt= (int*)(ssc + (size_t)1024*4096);     // 1024
  float* qcv = (float*)(qcnt + 1024);               // 1024*QCAP
  int*   qci = (int*)(qcv + (size_t)1024*QCAP);     // 1024*QCAP
  int*   candjG = qci + (size_t)1024*QCAP;          // 1024*128
  int*   nc2G   = candjG + (size_t)1024*NCAND;      // 1024

  k1_mem    <<<dim3(NP/128), dim3(256), 0, stream>>>(mi, le_w1, le_b1, le_w2, le_b2, fw, mwT, mm);
  k2_query  <<<dim3(1024),   dim3(64),  0, stream>>>(x, le_w1, le_b1, le_w2, le_b2, fw,
                ge_w1, ge_b1, ge_w2, ge_b2, ge_w3, ge_b3,
                gr_w1, gr_b1, gr_w2, gr_b2,
                ga_w1, ga_b1, ga_w2, ga_b2,
                qwf, qwd, qqd, ggd, gpd, qcnt);
  k_tau     <<<dim3(64,4),   dim3(256), 0, stream>>>(mwT, mm, qwf, ssc);
  k_tau_sel <<<dim3(1024),   dim3(256), 0, stream>>>(ssc, tau);
  k3_main   <<<dim3(64,NJB), dim3(256), 0, stream>>>(mwT, mm, qwf, tau, qcnt, qcv, qci);
  k4_pre    <<<dim3(1024),   dim3(256), 0, stream>>>(qcnt, qcv, qci, candjG, nc2G);
  k4_emb    <<<dim3(1024,2), dim3(256), 0, stream>>>(candjG, nc2G, qwd, qqd, mi,
                le_w1, le_b1, le_w2, le_b2, fw, cd2G);
  k4_fin    <<<dim3(1024),   dim3(64),  0, stream>>>(candjG, nc2G, cd2G, ggd, gpd, mt, itp,
                rh_w1, rh_b1, rh_w2, rh_b2, (float*)d_out);
}

// Round 17
// 436.470 us; speedup vs baseline: 8.5148x; 1.0755x over previous
//
#include <hip/hip_runtime.h>
#include <math.h>

#define N_MEM 100000
#define NP    100352      // 98 * 1024 (padded)
#define JBLK  1024
#define NJB   98
#define QCAP  1024        // per-query survivor buffer (expected ~390)
#define NCAND 128         // max re-rank set size

__device__ __forceinline__ float softplusf_(float x){ return log1pf(expf(x)); }

__device__ __forceinline__ double wave_sum_d(double v){
  #pragma unroll
  for (int o=32;o;o>>=1) v += __shfl_xor(v, o, 64);
  return v;
}
__device__ __forceinline__ int wave_sum_i(int v){
  #pragma unroll
  for (int o=32;o;o>>=1) v += __shfl_xor(v, o, 64);
  return v;
}

// argmax carrying (value, global-index tie-break, position meta)
__device__ __forceinline__ void wave_argmax3(float& v, int& j, int& p){
  #pragma unroll
  for (int o=32;o;o>>=1){
    float ov = __shfl_xor(v, o, 64);
    int   oj = __shfl_xor(j, o, 64);
    int   op = __shfl_xor(p, o, 64);
    if (ov > v || (ov == v && oj < j)) { v = ov; j = oj; p = op; }
  }
}

// full ascending bitonic sort across 64 lanes; lane 48 = 16th-largest
__device__ __forceinline__ float bitonic_sort64(float v, int lane){
  #pragma unroll
  for (int k=2;k<=64;k<<=1){
    #pragma unroll
    for (int j=k>>1;j>0;j>>=1){
      float o = __shfl_xor(v, j, 64);
      float mn = fminf(v,o), mx = fmaxf(v,o);
      bool upper = (lane & j) != 0;
      bool asc   = ((lane & k) == 0);
      v = (upper == asc) ? mx : mn;
    }
  }
  return v;
}

// 16q x 4j score accumulation over 64 d; q operand is WAVE-UNIFORM (blockIdx-derived),
// read from global (scalar-cache s_load path); per-(q,j) fmaf chain sequential in d.
// Bit-identical ordering shared by k_tau and k3.
#define SCORE_LOOP_16x4_SQ() { \
  _Pragma("unroll 8") \
  for (int d=0; d<64; d++){ \
    float4 mv4 = *(const float4*)(rowbase + (size_t)d*NP); \
    float marr[4]={mv4.x,mv4.y,mv4.z,mv4.w}; \
    _Pragma("unroll") \
    for (int qi_=0;qi_<16;qi_++){ \
      float qv_ = qbase[qi_*64 + d]; \
      _Pragma("unroll") \
      for (int jj_=0;jj_<4;jj_++) s[qi_][jj_] = fmaf(qv_, marr[jj_], s[qi_][jj_]); \
    } \
  } }

// ---------------- K1 (k3-style tiles): memory embeddings -> mwT (64 x NP), mm
// block: 128 points, 256 thr; wave w owns output-chunk e0=w*16 (readfirstlane ->
// provably wave-uniform -> weight reads take the scalar-cache path); lane owns 2 pts.
// Per-element FMA chains (bias-init, d-ascending) bit-identical to original k1.
__global__ __launch_bounds__(256) void k1_mem(
    const float* __restrict__ mi,
    const float* __restrict__ w1, const float* __restrict__ b1,
    const float* __restrict__ w2, const float* __restrict__ b2,
    const float* __restrict__ fw,
    float* __restrict__ mwT, float* __restrict__ mm)
{
  __shared__ float xs[64*132];     // [d][j] layer-1 input; reused as [e][j] for layer-2
  __shared__ float mms[4][132];
  int t = threadIdx.x, w = t>>6, lane = t&63;
  int jb = blockIdx.x*128;
  {
    int jl = t & 127; int j = jb + jl; int d0 = (t>>7)*32;
    bool real = (j < N_MEM);
    const float4* xp = (const float4*)(mi + (size_t)(real?j:0)*64 + d0);
    #pragma unroll
    for (int k=0;k<8;k++){
      float4 v = xp[k];
      if (!real){ v.x=0.f; v.y=0.f; v.z=0.f; v.w=0.f; }
      xs[(d0+4*k+0)*132 + jl] = v.x;
      xs[(d0+4*k+1)*132 + jl] = v.y;
      xs[(d0+4*k+2)*132 + jl] = v.z;
      xs[(d0+4*k+3)*132 + jl] = v.w;
    }
  }
  __syncthreads();
  int e0 = __builtin_amdgcn_readfirstlane(w*16);   // provably wave-uniform
  int jc = 2*lane;
  float s[16][2];
  #pragma unroll
  for (int qi=0;qi<16;qi++){ float b = b1[e0+qi]; s[qi][0]=b; s[qi][1]=b; }
  #pragma unroll 4
  for (int d=0; d<64; d++){
    float x0 = xs[d*132 + jc], x1 = xs[d*132 + jc+1];
    #pragma unroll
    for (int qi=0;qi<16;qi++){
      float wv = w1[d*64 + e0 + qi];
      s[qi][0] = fmaf(x0, wv, s[qi][0]);
      s[qi][1] = fmaf(x1, wv, s[qi][1]);
    }
  }
  __syncthreads();   // all xs reads complete
  #pragma unroll
  for (int qi=0;qi<16;qi++){
    xs[(e0+qi)*132 + jc]   = fmaxf(s[qi][0], 0.f);
    xs[(e0+qi)*132 + jc+1] = fmaxf(s[qi][1], 0.f);
  }
  __syncthreads();
  #pragma unroll
  for (int qi=0;qi<16;qi++){ float b = b2[e0+qi]; s[qi][0]=b; s[qi][1]=b; }
  #pragma unroll 4
  for (int d=0; d<64; d++){
    float x0 = xs[d*132 + jc], x1 = xs[d*132 + jc+1];
    #pragma unroll
    for (int qi=0;qi<16;qi++){
      float wv = w2[d*64 + e0 + qi];
      s[qi][0] = fmaf(x0, wv, s[qi][0]);
      s[qi][1] = fmaf(x1, wv, s[qi][1]);
    }
  }
  int j0g = jb + jc;
  bool r0 = (j0g < N_MEM), r1 = (j0g+1 < N_MEM);
  float p0 = 0.f, p1 = 0.f;
  #pragma unroll
  for (int qi=0;qi<16;qi++){
    int e = e0 + qi;
    float sw = sqrtf(softplusf_(fw[e]) + 1e-9f);
    float v0 = r0 ? s[qi][0]*sw : 0.f;
    float v1 = r1 ? s[qi][1]*sw : 0.f;
    p0 = fmaf(v0,v0,p0);
    p1 = fmaf(v1,v1,p1);
    float2 o2; o2.x = v0; o2.y = v1;
    *(float2*)(mwT + (size_t)e*NP + j0g) = o2;
  }
  mms[w][jc] = p0; mms[w][jc+1] = p1;
  __syncthreads();
  if (t < 128){
    int j = jb + t;
    float v = ((mms[0][t] + mms[1][t]) + mms[2][t]) + mms[3][t];
    mm[j] = (j < N_MEM) ? v : 3.0e38f;
  }
}

// ---------------- K2: per-query f64 embedding/global/gate (ILP-4 chains); zero qcnt
__global__ __launch_bounds__(64) void k2_query(
  const float* __restrict__ x,
  const float* __restrict__ le_w1, const float* __restrict__ le_b1,
  const float* __restrict__ le_w2, const float* __restrict__ le_b2,
  const float* __restrict__ fw,
  const float* __restrict__ ge_w1, const float* __restrict__ ge_b1,
  const float* __restrict__ ge_w2, const float* __restrict__ ge_b2,
  const float* __restrict__ ge_w3, const float* __restrict__ ge_b3,
  const float* __restrict__ gr_w1, const float* __restrict__ gr_b1,
  const float* __restrict__ gr_w2, const float* __restrict__ gr_b2,
  const float* __restrict__ ga_w1, const float* __restrict__ ga_b1,
  const float* __restrict__ ga_w2, const float* __restrict__ ga_b2,
  float* __restrict__ qwf, double* __restrict__ qwd,
  double* __restrict__ qqd, double* __restrict__ ggd, double* __restrict__ gpd,
  int* __restrict__ qcnt)
{
  int l = threadIdx.x, q = blockIdx.x;
  if (l==0) qcnt[q] = 0;
  __shared__ double xs[64], qe[64], h1[128], t1[64], t2[64];
  xs[l] = (double)x[q*64+l];
  __syncthreads();
  double a0,a1,a2,a3,a;
  a0=a1=a2=a3=0.0;
  for (int d=0; d<64; d+=4){
    a0 = fma(xs[d  ], (double)le_w1[(d  )*64+l], a0);
    a1 = fma(xs[d+1], (double)le_w1[(d+1)*64+l], a1);
    a2 = fma(xs[d+2], (double)le_w1[(d+2)*64+l], a2);
    a3 = fma(xs[d+3], (double)le_w1[(d+3)*64+l], a3);
  }
  a = ((a0+a1)+(a2+a3)) + (double)le_b1[l];
  t1[l] = a > 0.0 ? a : 0.0;
  __syncthreads();
  a0=a1=a2=a3=0.0;
  for (int d=0; d<64; d+=4){
    a0 = fma(t1[d  ], (double)le_w2[(d  )*64+l], a0);
    a1 = fma(t1[d+1], (double)le_w2[(d+1)*64+l], a1);
    a2 = fma(t1[d+2], (double)le_w2[(d+2)*64+l], a2);
    a3 = fma(t1[d+3], (double)le_w2[(d+3)*64+l], a3);
  }
  a = ((a0+a1)+(a2+a3)) + (double)le_b2[l];
  qe[l] = a;
  double sw = sqrt(log1p(exp((double)fw[l])) + 1e-9);
  double qv = a * sw;
  qwd[q*64+l] = qv;
  qwf[q*64+l] = (float)qv;
  double ss = wave_sum_d(qv*qv);
  if (l==0) qqd[q] = ss;
  double b0=0,b1v=0,c0=0,c1=0;
  for (int d=0; d<64; d+=2){
    double x0 = xs[d], x1 = xs[d+1];
    b0  = fma(x0, (double)ge_w1[(d  )*128+l],    b0);
    b1v = fma(x1, (double)ge_w1[(d+1)*128+l],    b1v);
    c0  = fma(x0, (double)ge_w1[(d  )*128+64+l], c0);
    c1  = fma(x1, (double)ge_w1[(d+1)*128+64+l], c1);
  }
  a = (b0+b1v) + (double)ge_b1[l];
  double c = (c0+c1) + (double)ge_b1[64+l];
  h1[l] = a>0.0?a:0.0; h1[64+l] = c>0.0?c:0.0;
  __syncthreads();
  a0=a1=a2=a3=0.0;
  for (int d=0; d<128; d+=4){
    a0 = fma(h1[d  ], (double)ge_w2[(d  )*64+l], a0);
    a1 = fma(h1[d+1], (double)ge_w2[(d+1)*64+l], a1);
    a2 = fma(h1[d+2], (double)ge_w2[(d+2)*64+l], a2);
    a3 = fma(h1[d+3], (double)ge_w2[(d+3)*64+l], a3);
  }
  a = ((a0+a1)+(a2+a3)) + (double)ge_b2[l];
  __syncthreads();
  t1[l] = a>0.0?a:0.0;
  __syncthreads();
  a0=a1=a2=a3=0.0;
  for (int d=0; d<64; d+=4){
    a0 = fma(t1[d  ], (double)ge_w3[(d  )*64+l], a0);
    a1 = fma(t1[d+1], (double)ge_w3[(d+1)*64+l], a1);
    a2 = fma(t1[d+2], (double)ge_w3[(d+2)*64+l], a2);
    a3 = fma(t1[d+3], (double)ge_w3[(d+3)*64+l], a3);
  }
  a = ((a0+a1)+(a2+a3)) + (double)ge_b3[l];
  t2[l] = a;                // global_repr
  __syncthreads();
  a0=a1=a2=a3=0.0;
  for (int d=0; d<64; d+=4){
    a0 = fma(t2[d  ], (double)gr_w1[(d  )*64+l], a0);
    a1 = fma(t2[d+1], (double)gr_w1[(d+1)*64+l], a1);
    a2 = fma(t2[d+2], (double)gr_w1[(d+2)*64+l], a2);
    a3 = fma(t2[d+3], (double)gr_w1[(d+3)*64+l], a3);
  }
  a = ((a0+a1)+(a2+a3)) + (double)gr_b1[l];
  __syncthreads();
  t1[l] = a>0.0?a:0.0;
  __syncthreads();
  if (l < 8){
    a0=a1=a2=a3=0.0;
    for (int d=0; d<64; d+=4){
      a0 = fma(t1[d  ], (double)gr_w2[(d  )*8+l], a0);
      a1 = fma(t1[d+1], (double)gr_w2[(d+1)*8+l], a1);
      a2 = fma(t1[d+2], (double)gr_w2[(d+2)*8+l], a2);
      a3 = fma(t1[d+3], (double)gr_w2[(d+3)*8+l], a3);
    }
    gpd[q*8+l] = ((a0+a1)+(a2+a3)) + (double)gr_b2[l];
  }
  a0=a1=a2=a3=0.0;
  for (int d=0; d<64; d+=4){
    a0 = fma(t2[d  ], (double)ga_w1[(d  )*64+l], a0);
    a1 = fma(t2[d+1], (double)ga_w1[(d+1)*64+l], a1);
    a2 = fma(t2[d+2], (double)ga_w1[(d+2)*64+l], a2);
    a3 = fma(t2[d+3], (double)ga_w1[(d+3)*64+l], a3);
  }
  for (int d=0; d<64; d+=4){
    a0 = fma(qe[d  ], (double)ga_w1[(64+d  )*64+l], a0);
    a1 = fma(qe[d+1], (double)ga_w1[(64+d+1)*64+l], a1);
    a2 = fma(qe[d+2], (double)ga_w1[(64+d+2)*64+l], a2);
    a3 = fma(qe[d+3], (double)ga_w1[(64+d+3)*64+l], a3);
  }
  a = ((a0+a1)+(a2+a3)) + (double)ga_b1[l];
  a = a>0.0?a:0.0;
  double p = wave_sum_d(a * (double)ga_w2[l]);
  if (l==0) ggd[q] = 1.0/(1.0 + exp(-(p + (double)ga_b2[0])));
}

// ---------------- K_tau: dump sample scores (j in [0,4096)) bit-identical to k3
__global__ __launch_bounds__(256) void k_tau(
    const float* __restrict__ mwT, const float* __restrict__ mm,
    const float* __restrict__ qw, float* __restrict__ ssc)
{
  int t = threadIdx.x, w = t>>6, lane = t&63;
  int q0 = blockIdx.x*16;
  int jb = blockIdx.y*JBLK;
  const float* qbase = qw + (size_t)q0*64;   // blockIdx-uniform -> scalar loads
  int jw = jb + w*256 + 4*lane;
  const float* rowbase = mwT + jw;
  float s[16][4];
  #pragma unroll
  for (int a=0;a<16;a++){
    #pragma unroll
    for (int b=0;b<4;b++) s[a][b]=0.f;
  }
  SCORE_LOOP_16x4_SQ();
  float4 mmv4 = *(const float4*)(mm + jw);
  float mmv[4] = {mmv4.x, mmv4.y, mmv4.z, mmv4.w};
  #pragma unroll
  for (int qi=0;qi<16;qi++){
    int qg = q0 + qi;
    float4 o0;
    o0.x = 2.f*s[qi][0]-mmv[0]; o0.y = 2.f*s[qi][1]-mmv[1];
    o0.z = 2.f*s[qi][2]-mmv[2]; o0.w = 2.f*s[qi][3]-mmv[3];
    *(float4*)(ssc + (size_t)qg*4096 + jw) = o0;
  }
}

// ---------------- K_tau_sel: exact 16th-largest of the 4096 sample scores per query
__global__ __launch_bounds__(256) void k_tau_sel(
    const float* __restrict__ ssc, float* __restrict__ tau)
{
  int t = threadIdx.x, w = t>>6, l = t&63, q = blockIdx.x;
  __shared__ unsigned su[4096];
  __shared__ int rs[4];
  const float* base = ssc + (size_t)q*4096;
  for (int i=t; i<4096; i+=256){
    unsigned f = __float_as_uint(base[i]);
    su[i] = f ^ ((f >> 31) ? 0xFFFFFFFFu : 0x80000000u);   // monotone key
  }
  __syncthreads();
  unsigned T = 0u;
  for (int b=31; b>=0; b--){
    unsigned cand = T | (1u<<b);
    int c = 0;
    for (int i=t; i<4096; i+=256) c += (su[i] >= cand) ? 1 : 0;
    c = wave_sum_i(c);
    if (l==0) rs[w] = c;
    __syncthreads();
    int tot = rs[0]+rs[1]+rs[2]+rs[3];
    if (tot >= 16) T = cand;
    __syncthreads();
  }
  if (t==0){
    unsigned f = (T & 0x80000000u) ? (T ^ 0x80000000u) : ~T;
    tau[q] = __uint_as_float(f);
  }
}

// ---------------- K3: all 98 j-blocks, filter >= tau - margin, append to buffer
__global__ __launch_bounds__(256) void k3_main(
    const float* __restrict__ mwT, const float* __restrict__ mm,
    const float* __restrict__ qw,  const float* __restrict__ tau,
    int* __restrict__ qcnt, float* __restrict__ qcv, int* __restrict__ qci)
{
  int t=threadIdx.x, w=t>>6, lane=t&63;
  int q0 = blockIdx.x*16;
  int jb = blockIdx.y*JBLK;
  __shared__ float taus[16];
  const float* qbase = qw + (size_t)q0*64;   // blockIdx-uniform -> scalar loads
  if (t < 16){ taus[t] = tau[q0+t] - 5e-6f; }
  __syncthreads();
  int jw = jb + w*256 + 4*lane;
  const float* rowbase = mwT + jw;
  float s[16][4];
  #pragma unroll
  for (int a=0;a<16;a++){
    #pragma unroll
    for (int b=0;b<4;b++) s[a][b]=0.f;
  }
  SCORE_LOOP_16x4_SQ();
  float4 mmv4 = *(const float4*)(mm + jw);
  float mmv[4] = {mmv4.x, mmv4.y, mmv4.z, mmv4.w};
  #pragma unroll
  for (int qi=0;qi<16;qi++){
    float tq = taus[qi];
    int qg = q0 + qi;
    #pragma unroll
    for (int jj=0;jj<4;jj++){
      float sc = 2.f*s[qi][jj] - mmv[jj];
      if (sc >= tq){
        int p = atomicAdd(&qcnt[qg], 1);
        if (p < QCAP){
          qcv[(size_t)qg*QCAP+p] = sc;
          qci[(size_t)qg*QCAP+p] = jw + jj;
        }
      }
    }
  }
}

// ---------------- K4_pre: survivors -> v16 (lane-max bitonic) -> threshold compaction
__global__ __launch_bounds__(256) void k4_pre(
    const int* __restrict__ qcnt, const float* __restrict__ qcv, const int* __restrict__ qci,
    int* __restrict__ candjG, int* __restrict__ nc2G)
{
  int t = threadIdx.x, l = t&63, q = blockIdx.x;
  __shared__ float  svv[QCAP];
  __shared__ int    sii[QCAP];
  __shared__ float  v16s;
  __shared__ int    ncnt2;
  int NC = qcnt[q]; NC = NC < QCAP ? NC : QCAP;
  for (int i=t; i<NC; i+=256){ svv[i]=qcv[(size_t)q*QCAP+i]; sii[i]=qci[(size_t)q*QCAP+i]; }
  if (t==0) ncnt2 = 0;
  __syncthreads();
  if (t < 64){
    float vm = -3.0e38f;
    for (int i=l; i<NC; i+=64) vm = fmaxf(vm, svv[i]);
    vm = bitonic_sort64(vm, l);
    if (l == 48) v16s = vm;
  }
  __syncthreads();
  {
    float thr = v16s - 2e-6f;   // covers f32-stream vs f64 score discrepancy (~5e-7 worst)
    for (int i=t; i<NC; i+=256){
      if (svv[i] >= thr && (unsigned)sii[i] < (unsigned)N_MEM){
        int p = atomicAdd(&ncnt2, 1);
        if (p < NCAND) candjG[(size_t)q*NCAND + p] = sii[i];
      }
    }
  }
  __syncthreads();
  if (t==0) nc2G[q] = ncnt2 < NCAND ? ncnt2 : NCAND;
}

// ---------------- K4_emb: f64 re-rank of candidates; weights LDS-staged; 8 waves/query
__global__ __launch_bounds__(256) void k4_emb(
    const int* __restrict__ candjG, const int* __restrict__ nc2G,
    const double* __restrict__ qwd_g, const double* __restrict__ qqd_g,
    const float* __restrict__ mi,
    const float* __restrict__ le_w1, const float* __restrict__ le_b1,
    const float* __restrict__ le_w2, const float* __restrict__ le_b2,
    const float* __restrict__ fw, double* __restrict__ cd2G)
{
  int t = threadIdx.x, w = t>>6, l = t&63, q = blockIdx.x;
  __shared__ float  lw1[4096], lw2[4096];
  __shared__ double hdw[4][64];
  for (int i=t; i<4096; i+=256){ lw1[i]=le_w1[i]; lw2[i]=le_w2[i]; }
  __syncthreads();
  int NC2 = nc2G[q];
  double qwl = qwd_g[q*64+l];
  double swl = sqrt(log1p(exp((double)fw[l])) + 1e-9);
  double qq  = qqd_g[q];
  double lb1 = (double)le_b1[l], lb2 = (double)le_b2[l];
  for (int c = blockIdx.y*4 + w; c < NC2; c += 8){
    int jc = __builtin_amdgcn_readfirstlane(candjG[(size_t)q*NCAND + c]);
    const float* mrow = mi + (size_t)jc*64;   // wave-uniform -> s_load
    double b0=0,b1=0,b2=0,b3=0,b4=0,b5=0,b6=0,b7=0;
    #pragma unroll
    for (int d=0; d<64; d+=8){
      b0 = fma((double)mrow[d  ], (double)lw1[(d  )*64+l], b0);
      b1 = fma((double)mrow[d+1], (double)lw1[(d+1)*64+l], b1);
      b2 = fma((double)mrow[d+2], (double)lw1[(d+2)*64+l], b2);
      b3 = fma((double)mrow[d+3], (double)lw1[(d+3)*64+l], b3);
      b4 = fma((double)mrow[d+4], (double)lw1[(d+4)*64+l], b4);
      b5 = fma((double)mrow[d+5], (double)lw1[(d+5)*64+l], b5);
      b6 = fma((double)mrow[d+6], (double)lw1[(d+6)*64+l], b6);
      b7 = fma((double)mrow[d+7], (double)lw1[(d+7)*64+l], b7);
    }
    double h = (((b0+b1)+(b2+b3)) + ((b4+b5)+(b6+b7))) + lb1;
    h = h>0.0 ? h : 0.0;
    hdw[w][l] = h;   // wave-private; lockstep + lgkmcnt ordering suffice
    double c0=0,c1=0,c2=0,c3=0,c4=0,c5=0,c6=0,c7=0;
    #pragma unroll
    for (int d=0; d<64; d+=8){
      c0 = fma(hdw[w][d  ], (double)lw2[(d  )*64+l], c0);
      c1 = fma(hdw[w][d+1], (double)lw2[(d+1)*64+l], c1);
      c2 = fma(hdw[w][d+2], (double)lw2[(d+2)*64+l], c2);
      c3 = fma(hdw[w][d+3], (double)lw2[(d+3)*64+l], c3);
      c4 = fma(hdw[w][d+4], (double)lw2[(d+4)*64+l], c4);
      c5 = fma(hdw[w][d+5], (double)lw2[(d+5)*64+l], c5);
      c6 = fma(hdw[w][d+6], (double)lw2[(d+6)*64+l], c6);
      c7 = fma(hdw[w][d+7], (double)lw2[(d+7)*64+l], c7);
    }
    double o  = (((c0+c1)+(c2+c3)) + ((c4+c5)+(c6+c7))) + lb2;
    double mw = o * swl;
    double sc = wave_sum_d(mw*(mw - 2.0*qwl));
    if (l==0) cd2G[(size_t)q*NCAND + c] = qq + sc;
  }
}

// ---------------- K4_fin: f32-quantized select (raw desc, idx asc) -> softmax/blend/refine
__global__ __launch_bounds__(64) void k4_fin(
    const int* __restrict__ candjG, const int* __restrict__ nc2G,
    const double* __restrict__ cd2G,
    const double* __restrict__ ggd_g, const double* __restrict__ gpd_g,
    const float* __restrict__ mt, const float* __restrict__ itp,
    const float* __restrict__ rw1, const float* __restrict__ rb1,
    const float* __restrict__ rw2, const float* __restrict__ rb2,
    float* __restrict__ out)
{
  int l = threadIdx.x, q = blockIdx.x;
  __shared__ float  selr[16];
  __shared__ int    selj[16];
  __shared__ double hh[32];
  int NC2 = nc2G[q];
  {
    float e32  = (float)exp((double)itp[0]);
    float sp32 = (float)log1p((double)e32);
    float t32  = __fadd_rn(sp32, 1e-9f);
    float dn32 = __fadd_rn(t32, 1e-9f);
    double denom = (double)dn32;
    float r0=-2.f, r1=-2.f; int j0=0x7fffffff, j1=0x7fffffff;
    if (l < NC2){
      double d2 = cd2G[(size_t)q*NCAND + l]; if (d2 < 0.0) d2 = 0.0;
      float ratio32 = (float)(d2 / denom);
      r0 = (float)exp(-(double)ratio32);
      j0 = candjG[(size_t)q*NCAND + l];
    }
    if (l+64 < NC2){
      double d2 = cd2G[(size_t)q*NCAND + l+64]; if (d2 < 0.0) d2 = 0.0;
      float ratio32 = (float)(d2 / denom);
      r1 = (float)exp(-(double)ratio32);
      j1 = candjG[(size_t)q*NCAND + l+64];
    }
    bool u0=false, u1=false;
    for (int it=0; it<16; it++){
      float a0 = u0 ? -2.f : r0;
      float a1 = u1 ? -2.f : r1;
      float v; int j; int p;
      if (a0 > a1 || (a0 == a1 && j0 <= j1)) { v=a0; j=j0; p=l*2; }
      else                                   { v=a1; j=j1; p=l*2+1; }
      wave_argmax3(v, j, p);
      if ((p>>1) == l){ if (p&1) u1=true; else u0=true; }
      if (l == it){ selr[it]=v; selj[it]=j; }
    }
  }
  __syncthreads();
  double raw = (l<16) ? (double)selr[l] : -1.0e300;
  double mv = raw;
  #pragma unroll
  for (int o=32;o;o>>=1){ double ov = __shfl_xor(mv,o,64); mv = ov>mv?ov:mv; }
  double e  = (l<16) ? exp(raw - mv) : 0.0;
  double se = wave_sum_d(e);
  double wgt = e / se;
  double lp[8] = {0,0,0,0,0,0,0,0};
  if (l < 16){
    const float* tr = mt + (size_t)selj[l]*8;
    #pragma unroll
    for (int tt=0; tt<8; tt++) lp[tt] = wgt * (double)tr[tt];
  }
  #pragma unroll
  for (int tt=0; tt<8; tt++) lp[tt] = wave_sum_d(lp[tt]);
  double g = ggd_g[q];
  double bl[8];
  #pragma unroll
  for (int tt=0; tt<8; tt++) bl[tt] = g*lp[tt] + (1.0-g)*gpd_g[q*8+tt];
  if (l < 32){
    double a = (double)rb1[l];
    #pragma unroll
    for (int tt=0; tt<8; tt++) a = fma(bl[tt], (double)rw1[tt*32+l], a);
    hh[l] = a>0.0?a:0.0;
  }
  __syncthreads();
  if (l < 8){
    double a = (double)rb2[l];
    #pragma unroll
    for (int i=0; i<32; i++) a = fma(hh[i], (double)rw2[i*8+l], a);
    out[q*8+l] = (float)a;
  }
}

extern "C" void kernel_launch(void* const* d_in, const int* in_sizes, int n_in,
                              void* d_out, int out_size, void* d_ws, size_t ws_size,
                              hipStream_t stream)
{
  const float* x     = (const float*)d_in[0];
  const float* mi    = (const float*)d_in[1];
  const float* mt    = (const float*)d_in[2];
  const float* le_w1 = (const float*)d_in[3];
  const float* le_b1 = (const float*)d_in[4];
  const float* le_w2 = (const float*)d_in[5];
  const float* le_b2 = (const float*)d_in[6];
  const float* fw    = (const float*)d_in[7];
  const float* itp   = (const float*)d_in[8];
  const float* ge_w1 = (const float*)d_in[9];
  const float* ge_b1 = (const float*)d_in[10];
  const float* ge_w2 = (const float*)d_in[11];
  const float* ge_b2 = (const float*)d_in[12];
  const float* ge_w3 = (const float*)d_in[13];
  const float* ge_b3 = (const float*)d_in[14];
  const float* gr_w1 = (const float*)d_in[15];
  const float* gr_b1 = (const float*)d_in[16];
  const float* gr_w2 = (const float*)d_in[17];
  const float* gr_b2 = (const float*)d_in[18];
  const float* ga_w1 = (const float*)d_in[19];
  const float* ga_b1 = (const float*)d_in[20];
  const float* ga_w2 = (const float*)d_in[21];
  const float* ga_b2 = (const float*)d_in[22];
  const float* rh_w1 = (const float*)d_in[23];
  const float* rh_b1 = (const float*)d_in[24];
  const float* rh_w2 = (const float*)d_in[25];
  const float* rh_b2 = (const float*)d_in[26];

  double* dws = (double*)d_ws;
  double* qwd = dws;                                // 1024*64
  double* qqd = qwd + (size_t)1024*64;              // 1024
  double* ggd = qqd + 1024;                         // 1024
  double* gpd = ggd + 1024;                         // 8192
  double* cd2G= gpd + 8192;                         // 1024*128
  float*  fws = (float*)(cd2G + (size_t)1024*128);
  float* mwT = fws;                                 // 64*NP
  float* mm  = mwT + (size_t)64*NP;                 // NP
  float* qwf = mm  + NP;                            // 1024*64
  float* tau = qwf + (size_t)1024*64;               // 1024
  float* ssc = tau + 1024;                          // 1024*4096
  int*   qcnt= (int*)(ssc + (size_t)1024*4096);     // 1024
  float* qcv = (float*)(qcnt + 1024);               // 1024*QCAP
  int*   qci = (int*)(qcv + (size_t)1024*QCAP);     // 1024*QCAP
  int*   candjG = qci + (size_t)1024*QCAP;          // 1024*128
  int*   nc2G   = candjG + (size_t)1024*NCAND;      // 1024

  k1_mem    <<<dim3(NP/128), dim3(256), 0, stream>>>(mi, le_w1, le_b1, le_w2, le_b2, fw, mwT, mm);
  k2_query  <<<dim3(1024),   dim3(64),  0, stream>>>(x, le_w1, le_b1, le_w2, le_b2, fw,
                ge_w1, ge_b1, ge_w2, ge_b2, ge_w3, ge_b3,
                gr_w1, gr_b1, gr_w2, gr_b2,
                ga_w1, ga_b1, ga_w2, ga_b2,
                qwf, qwd, qqd, ggd, gpd, qcnt);
  k_tau     <<<dim3(64,4),   dim3(256), 0, stream>>>(mwT, mm, qwf, ssc);
  k_tau_sel <<<dim3(1024),   dim3(256), 0, stream>>>(ssc, tau);
  k3_main   <<<dim3(64,NJB), dim3(256), 0, stream>>>(mwT, mm, qwf, tau, qcnt, qcv, qci);
  k4_pre    <<<dim3(1024),   dim3(256), 0, stream>>>(qcnt, qcv, qci, candjG, nc2G);
  k4_emb    <<<dim3(1024,2), dim3(256), 0, stream>>>(candjG, nc2G, qwd, qqd, mi,
                le_w1, le_b1, le_w2, le_b2, fw, cd2G);
  k4_fin    <<<dim3(1024),   dim3(64),  0, stream>>>(candjG, nc2G, cd2G, ggd, gpd, mt, itp,
                rh_w1, rh_b1, rh_w2, rh_b2, (float*)d_out);
}

// Round 18
// 430.902 us; speedup vs baseline: 8.6249x; 1.0129x over previous
//
#include <hip/hip_runtime.h>
#include <math.h>

#define N_MEM 100000
#define NP    100352      // 98 * 1024 (padded)
#define JBLK  1024
#define NJB   98
#define QCAP  1024        // per-query survivor buffer (expected ~390)
#define NCAND 128         // max re-rank set size

__device__ __forceinline__ float softplusf_(float x){ return log1pf(expf(x)); }

__device__ __forceinline__ double wave_sum_d(double v){
  #pragma unroll
  for (int o=32;o;o>>=1) v += __shfl_xor(v, o, 64);
  return v;
}
__device__ __forceinline__ int wave_sum_i(int v){
  #pragma unroll
  for (int o=32;o;o>>=1) v += __shfl_xor(v, o, 64);
  return v;
}

// argmax carrying (value, global-index tie-break, position meta)
__device__ __forceinline__ void wave_argmax3(float& v, int& j, int& p){
  #pragma unroll
  for (int o=32;o;o>>=1){
    float ov = __shfl_xor(v, o, 64);
    int   oj = __shfl_xor(j, o, 64);
    int   op = __shfl_xor(p, o, 64);
    if (ov > v || (ov == v && oj < j)) { v = ov; j = oj; p = op; }
  }
}

// full ascending bitonic sort across 64 lanes; lane 48 = 16th-largest
__device__ __forceinline__ float bitonic_sort64(float v, int lane){
  #pragma unroll
  for (int k=2;k<=64;k<<=1){
    #pragma unroll
    for (int j=k>>1;j>0;j>>=1){
      float o = __shfl_xor(v, j, 64);
      float mn = fminf(v,o), mx = fmaxf(v,o);
      bool upper = (lane & j) != 0;
      bool asc   = ((lane & k) == 0);
      v = (upper == asc) ? mx : mn;
    }
  }
  return v;
}

// 16q x 4j score accumulation over 64 d; q operand is WAVE-UNIFORM (blockIdx-derived),
// read from global (scalar-cache s_load path); per-(q,j) fmaf chain sequential in d.
// Bit-identical ordering shared by k_tau and k3.
#define SCORE_LOOP_16x4_SQ() { \
  _Pragma("unroll 4") \
  for (int d=0; d<64; d++){ \
    float4 mv4 = *(const float4*)(rowbase + (size_t)d*NP); \
    float marr[4]={mv4.x,mv4.y,mv4.z,mv4.w}; \
    _Pragma("unroll") \
    for (int qi_=0;qi_<16;qi_++){ \
      float qv_ = qbase[qi_*64 + d]; \
      _Pragma("unroll") \
      for (int jj_=0;jj_<4;jj_++) s[qi_][jj_] = fmaf(qv_, marr[jj_], s[qi_][jj_]); \
    } \
  } }

#define XPAD 129

// ---------------- K1 (k3-style tiles): memory embeddings -> mwT (64 x NP), mm
// block: 128 points, 256 thr; wave w owns output-chunk e0=w*16 (readfirstlane ->
// provably wave-uniform -> scalar-cache weight loads); lane owns 2 points.
// Staging: 16 threads cooperatively load one contiguous 256B row (fully coalesced).
// Per-element FMA chains (bias-init, d-ascending) bit-identical to original k1.
__global__ __launch_bounds__(256) void k1_mem(
    const float* __restrict__ mi,
    const float* __restrict__ w1, const float* __restrict__ b1,
    const float* __restrict__ w2, const float* __restrict__ b2,
    const float* __restrict__ fw,
    float* __restrict__ mwT, float* __restrict__ mm)
{
  __shared__ float xs[64*XPAD];    // [d][j] layer-1 input; reused as [e][j] for layer-2
  __shared__ float mms[4][132];
  int t = threadIdx.x, w = t>>6, lane = t&63;
  int jb = blockIdx.x*128;
  {
    int fi = t & 15;               // float4 index within a row
    int jr = t >> 4;               // row within a 16-row group
    #pragma unroll
    for (int pass=0; pass<8; pass++){
      int jl = pass*16 + jr;
      int j  = jb + jl;
      bool real = (j < N_MEM);
      float4 v = *(const float4*)(mi + (size_t)(real?j:0)*64 + 4*fi);
      if (!real){ v.x=0.f; v.y=0.f; v.z=0.f; v.w=0.f; }
      xs[(4*fi+0)*XPAD + jl] = v.x;
      xs[(4*fi+1)*XPAD + jl] = v.y;
      xs[(4*fi+2)*XPAD + jl] = v.z;
      xs[(4*fi+3)*XPAD + jl] = v.w;
    }
  }
  __syncthreads();
  int e0 = __builtin_amdgcn_readfirstlane(w*16);   // provably wave-uniform
  int jc = 2*lane;
  float s[16][2];
  #pragma unroll
  for (int qi=0;qi<16;qi++){ float b = b1[e0+qi]; s[qi][0]=b; s[qi][1]=b; }
  #pragma unroll 4
  for (int d=0; d<64; d++){
    float x0 = xs[d*XPAD + jc], x1 = xs[d*XPAD + jc+1];
    #pragma unroll
    for (int qi=0;qi<16;qi++){
      float wv = w1[d*64 + e0 + qi];
      s[qi][0] = fmaf(x0, wv, s[qi][0]);
      s[qi][1] = fmaf(x1, wv, s[qi][1]);
    }
  }
  __syncthreads();   // all xs reads complete
  #pragma unroll
  for (int qi=0;qi<16;qi++){
    xs[(e0+qi)*XPAD + jc]   = fmaxf(s[qi][0], 0.f);
    xs[(e0+qi)*XPAD + jc+1] = fmaxf(s[qi][1], 0.f);
  }
  __syncthreads();
  #pragma unroll
  for (int qi=0;qi<16;qi++){ float b = b2[e0+qi]; s[qi][0]=b; s[qi][1]=b; }
  #pragma unroll 4
  for (int d=0; d<64; d++){
    float x0 = xs[d*XPAD + jc], x1 = xs[d*XPAD + jc+1];
    #pragma unroll
    for (int qi=0;qi<16;qi++){
      float wv = w2[d*64 + e0 + qi];
      s[qi][0] = fmaf(x0, wv, s[qi][0]);
      s[qi][1] = fmaf(x1, wv, s[qi][1]);
    }
  }
  int j0g = jb + jc;
  bool r0 = (j0g < N_MEM), r1 = (j0g+1 < N_MEM);
  float p0 = 0.f, p1 = 0.f;
  #pragma unroll
  for (int qi=0;qi<16;qi++){
    int e = e0 + qi;
    float sw = sqrtf(softplusf_(fw[e]) + 1e-9f);
    float v0 = r0 ? s[qi][0]*sw : 0.f;
    float v1 = r1 ? s[qi][1]*sw : 0.f;
    p0 = fmaf(v0,v0,p0);
    p1 = fmaf(v1,v1,p1);
    float2 o2; o2.x = v0; o2.y = v1;
    *(float2*)(mwT + (size_t)e*NP + j0g) = o2;
  }
  mms[w][jc] = p0; mms[w][jc+1] = p1;
  __syncthreads();
  if (t < 128){
    int j = jb + t;
    float v = ((mms[0][t] + mms[1][t]) + mms[2][t]) + mms[3][t];
    mm[j] = (j < N_MEM) ? v : 3.0e38f;
  }
}

// ---------------- K2: per-query f64 embedding/global/gate (ILP-4 chains); zero qcnt
__global__ __launch_bounds__(64) void k2_query(
  const float* __restrict__ x,
  const float* __restrict__ le_w1, const float* __restrict__ le_b1,
  const float* __restrict__ le_w2, const float* __restrict__ le_b2,
  const float* __restrict__ fw,
  const float* __restrict__ ge_w1, const float* __restrict__ ge_b1,
  const float* __restrict__ ge_w2, const float* __restrict__ ge_b2,
  const float* __restrict__ ge_w3, const float* __restrict__ ge_b3,
  const float* __restrict__ gr_w1, const float* __restrict__ gr_b1,
  const float* __restrict__ gr_w2, const float* __restrict__ gr_b2,
  const float* __restrict__ ga_w1, const float* __restrict__ ga_b1,
  const float* __restrict__ ga_w2, const float* __restrict__ ga_b2,
  float* __restrict__ qwf, double* __restrict__ qwd,
  double* __restrict__ qqd, double* __restrict__ ggd, double* __restrict__ gpd,
  int* __restrict__ qcnt)
{
  int l = threadIdx.x, q = blockIdx.x;
  if (l==0) qcnt[q] = 0;
  __shared__ double xs[64], qe[64], h1[128], t1[64], t2[64];
  xs[l] = (double)x[q*64+l];
  __syncthreads();
  double a0,a1,a2,a3,a;
  a0=a1=a2=a3=0.0;
  for (int d=0; d<64; d+=4){
    a0 = fma(xs[d  ], (double)le_w1[(d  )*64+l], a0);
    a1 = fma(xs[d+1], (double)le_w1[(d+1)*64+l], a1);
    a2 = fma(xs[d+2], (double)le_w1[(d+2)*64+l], a2);
    a3 = fma(xs[d+3], (double)le_w1[(d+3)*64+l], a3);
  }
  a = ((a0+a1)+(a2+a3)) + (double)le_b1[l];
  t1[l] = a > 0.0 ? a : 0.0;
  __syncthreads();
  a0=a1=a2=a3=0.0;
  for (int d=0; d<64; d+=4){
    a0 = fma(t1[d  ], (double)le_w2[(d  )*64+l], a0);
    a1 = fma(t1[d+1], (double)le_w2[(d+1)*64+l], a1);
    a2 = fma(t1[d+2], (double)le_w2[(d+2)*64+l], a2);
    a3 = fma(t1[d+3], (double)le_w2[(d+3)*64+l], a3);
  }
  a = ((a0+a1)+(a2+a3)) + (double)le_b2[l];
  qe[l] = a;
  double sw = sqrt(log1p(exp((double)fw[l])) + 1e-9);
  double qv = a * sw;
  qwd[q*64+l] = qv;
  qwf[q*64+l] = (float)qv;
  double ss = wave_sum_d(qv*qv);
  if (l==0) qqd[q] = ss;
  double b0=0,b1v=0,c0=0,c1=0;
  for (int d=0; d<64; d+=2){
    double x0 = xs[d], x1 = xs[d+1];
    b0  = fma(x0, (double)ge_w1[(d  )*128+l],    b0);
    b1v = fma(x1, (double)ge_w1[(d+1)*128+l],    b1v);
    c0  = fma(x0, (double)ge_w1[(d  )*128+64+l], c0);
    c1  = fma(x1, (double)ge_w1[(d+1)*128+64+l], c1);
  }
  a = (b0+b1v) + (double)ge_b1[l];
  double c = (c0+c1) + (double)ge_b1[64+l];
  h1[l] = a>0.0?a:0.0; h1[64+l] = c>0.0?c:0.0;
  __syncthreads();
  a0=a1=a2=a3=0.0;
  for (int d=0; d<128; d+=4){
    a0 = fma(h1[d  ], (double)ge_w2[(d  )*64+l], a0);
    a1 = fma(h1[d+1], (double)ge_w2[(d+1)*64+l], a1);
    a2 = fma(h1[d+2], (double)ge_w2[(d+2)*64+l], a2);
    a3 = fma(h1[d+3], (double)ge_w2[(d+3)*64+l], a3);
  }
  a = ((a0+a1)+(a2+a3)) + (double)ge_b2[l];
  __syncthreads();
  t1[l] = a>0.0?a:0.0;
  __syncthreads();
  a0=a1=a2=a3=0.0;
  for (int d=0; d<64; d+=4){
    a0 = fma(t1[d  ], (double)ge_w3[(d  )*64+l], a0);
    a1 = fma(t1[d+1], (double)ge_w3[(d+1)*64+l], a1);
    a2 = fma(t1[d+2], (double)ge_w3[(d+2)*64+l], a2);
    a3 = fma(t1[d+3], (double)ge_w3[(d+3)*64+l], a3);
  }
  a = ((a0+a1)+(a2+a3)) + (double)ge_b3[l];
  t2[l] = a;                // global_repr
  __syncthreads();
  a0=a1=a2=a3=0.0;
  for (int d=0; d<64; d+=4){
    a0 = fma(t2[d  ], (double)gr_w1[(d  )*64+l], a0);
    a1 = fma(t2[d+1], (double)gr_w1[(d+1)*64+l], a1);
    a2 = fma(t2[d+2], (double)gr_w1[(d+2)*64+l], a2);
    a3 = fma(t2[d+3], (double)gr_w1[(d+3)*64+l], a3);
  }
  a = ((a0+a1)+(a2+a3)) + (double)gr_b1[l];
  __syncthreads();
  t1[l] = a>0.0?a:0.0;
  __syncthreads();
  if (l < 8){
    a0=a1=a2=a3=0.0;
    for (int d=0; d<64; d+=4){
      a0 = fma(t1[d  ], (double)gr_w2[(d  )*8+l], a0);
      a1 = fma(t1[d+1], (double)gr_w2[(d+1)*8+l], a1);
      a2 = fma(t1[d+2], (double)gr_w2[(d+2)*8+l], a2);
      a3 = fma(t1[d+3], (double)gr_w2[(d+3)*8+l], a3);
    }
    gpd[q*8+l] = ((a0+a1)+(a2+a3)) + (double)gr_b2[l];
  }
  a0=a1=a2=a3=0.0;
  for (int d=0; d<64; d+=4){
    a0 = fma(t2[d  ], (double)ga_w1[(d  )*64+l], a0);
    a1 = fma(t2[d+1], (double)ga_w1[(d+1)*64+l], a1);
    a2 = fma(t2[d+2], (double)ga_w1[(d+2)*64+l], a2);
    a3 = fma(t2[d+3], (double)ga_w1[(d+3)*64+l], a3);
  }
  for (int d=0; d<64; d+=4){
    a0 = fma(qe[d  ], (double)ga_w1[(64+d  )*64+l], a0);
    a1 = fma(qe[d+1], (double)ga_w1[(64+d+1)*64+l], a1);
    a2 = fma(qe[d+2], (double)ga_w1[(64+d+2)*64+l], a2);
    a3 = fma(qe[d+3], (double)ga_w1[(64+d+3)*64+l], a3);
  }
  a = ((a0+a1)+(a2+a3)) + (double)ga_b1[l];
  a = a>0.0?a:0.0;
  double p = wave_sum_d(a * (double)ga_w2[l]);
  if (l==0) ggd[q] = 1.0/(1.0 + exp(-(p + (double)ga_b2[0])));
}

// ---------------- K_tau: dump sample scores (j in [0,4096)) bit-identical to k3
__global__ __launch_bounds__(256) void k_tau(
    const float* __restrict__ mwT, const float* __restrict__ mm,
    const float* __restrict__ qw, float* __restrict__ ssc)
{
  int t = threadIdx.x, w = t>>6, lane = t&63;
  int q0 = blockIdx.x*16;
  int jb = blockIdx.y*JBLK;
  const float* qbase = qw + (size_t)q0*64;   // blockIdx-uniform -> scalar loads
  int jw = jb + w*256 + 4*lane;
  const float* rowbase = mwT + jw;
  float s[16][4];
  #pragma unroll
  for (int a=0;a<16;a++){
    #pragma unroll
    for (int b=0;b<4;b++) s[a][b]=0.f;
  }
  SCORE_LOOP_16x4_SQ();
  float4 mmv4 = *(const float4*)(mm + jw);
  float mmv[4] = {mmv4.x, mmv4.y, mmv4.z, mmv4.w};
  #pragma unroll
  for (int qi=0;qi<16;qi++){
    int qg = q0 + qi;
    float4 o0;
    o0.x = 2.f*s[qi][0]-mmv[0]; o0.y = 2.f*s[qi][1]-mmv[1];
    o0.z = 2.f*s[qi][2]-mmv[2]; o0.w = 2.f*s[qi][3]-mmv[3];
    *(float4*)(ssc + (size_t)qg*4096 + jw) = o0;
  }
}

// ---------------- K_tau_sel: exact 16th-largest of the 4096 sample scores per query
__global__ __launch_bounds__(256) void k_tau_sel(
    const float* __restrict__ ssc, float* __restrict__ tau)
{
  int t = threadIdx.x, w = t>>6, l = t&63, q = blockIdx.x;
  __shared__ unsigned su[4096];
  __shared__ int rs[4];
  const float* base = ssc + (size_t)q*4096;
  for (int i=t; i<4096; i+=256){
    unsigned f = __float_as_uint(base[i]);
    su[i] = f ^ ((f >> 31) ? 0xFFFFFFFFu : 0x80000000u);   // monotone key
  }
  __syncthreads();
  unsigned T = 0u;
  for (int b=31; b>=0; b--){
    unsigned cand = T | (1u<<b);
    int c = 0;
    for (int i=t; i<4096; i+=256) c += (su[i] >= cand) ? 1 : 0;
    c = wave_sum_i(c);
    if (l==0) rs[w] = c;
    __syncthreads();
    int tot = rs[0]+rs[1]+rs[2]+rs[3];
    if (tot >= 16) T = cand;
    __syncthreads();
  }
  if (t==0){
    unsigned f = (T & 0x80000000u) ? (T ^ 0x80000000u) : ~T;
    tau[q] = __uint_as_float(f);
  }
}

// ---------------- K3: all 98 j-blocks, filter >= tau - margin, append to buffer
__global__ __launch_bounds__(256) void k3_main(
    const float* __restrict__ mwT, const float* __restrict__ mm,
    const float* __restrict__ qw,  const float* __restrict__ tau,
    int* __restrict__ qcnt, float* __restrict__ qcv, int* __restrict__ qci)
{
  int t=threadIdx.x, w=t>>6, lane=t&63;
  int q0 = blockIdx.x*16;
  int jb = blockIdx.y*JBLK;
  __shared__ float taus[16];
  const float* qbase = qw + (size_t)q0*64;   // blockIdx-uniform -> scalar loads
  if (t < 16){ taus[t] = tau[q0+t] - 5e-6f; }
  __syncthreads();
  int jw = jb + w*256 + 4*lane;
  const float* rowbase = mwT + jw;
  float s[16][4];
  #pragma unroll
  for (int a=0;a<16;a++){
    #pragma unroll
    for (int b=0;b<4;b++) s[a][b]=0.f;
  }
  SCORE_LOOP_16x4_SQ();
  float4 mmv4 = *(const float4*)(mm + jw);
  float mmv[4] = {mmv4.x, mmv4.y, mmv4.z, mmv4.w};
  #pragma unroll
  for (int qi=0;qi<16;qi++){
    float tq = taus[qi];
    int qg = q0 + qi;
    #pragma unroll
    for (int jj=0;jj<4;jj++){
      float sc = 2.f*s[qi][jj] - mmv[jj];
      if (sc >= tq){
        int p = atomicAdd(&qcnt[qg], 1);
        if (p < QCAP){
          qcv[(size_t)qg*QCAP+p] = sc;
          qci[(size_t)qg*QCAP+p] = jw + jj;
        }
      }
    }
  }
}

// ---------------- K4_pre: survivors -> v16 (lane-max bitonic) -> threshold compaction
__global__ __launch_bounds__(256) void k4_pre(
    const int* __restrict__ qcnt, const float* __restrict__ qcv, const int* __restrict__ qci,
    int* __restrict__ candjG, int* __restrict__ nc2G)
{
  int t = threadIdx.x, l = t&63, q = blockIdx.x;
  __shared__ float  svv[QCAP];
  __shared__ int    sii[QCAP];
  __shared__ float  v16s;
  __shared__ int    ncnt2;
  int NC = qcnt[q]; NC = NC < QCAP ? NC : QCAP;
  for (int i=t; i<NC; i+=256){ svv[i]=qcv[(size_t)q*QCAP+i]; sii[i]=qci[(size_t)q*QCAP+i]; }
  if (t==0) ncnt2 = 0;
  __syncthreads();
  if (t < 64){
    float vm = -3.0e38f;
    for (int i=l; i<NC; i+=64) vm = fmaxf(vm, svv[i]);
    vm = bitonic_sort64(vm, l);
    if (l == 48) v16s = vm;
  }
  __syncthreads();
  {
    float thr = v16s - 2e-6f;   // covers f32-stream vs f64 score discrepancy (~5e-7 worst)
    for (int i=t; i<NC; i+=256){
      if (svv[i] >= thr && (unsigned)sii[i] < (unsigned)N_MEM){
        int p = atomicAdd(&ncnt2, 1);
        if (p < NCAND) candjG[(size_t)q*NCAND + p] = sii[i];
      }
    }
  }
  __syncthreads();
  if (t==0) nc2G[q] = ncnt2 < NCAND ? ncnt2 : NCAND;
}

// ---------------- K4_emb: f64 re-rank of candidates; weights LDS-staged; 8 waves/query
__global__ __launch_bounds__(256) void k4_emb(
    const int* __restrict__ candjG, const int* __restrict__ nc2G,
    const double* __restrict__ qwd_g, const double* __restrict__ qqd_g,
    const float* __restrict__ mi,
    const float* __restrict__ le_w1, const float* __restrict__ le_b1,
    const float* __restrict__ le_w2, const float* __restrict__ le_b2,
    const float* __restrict__ fw, double* __restrict__ cd2G)
{
  int t = threadIdx.x, w = t>>6, l = t&63, q = blockIdx.x;
  __shared__ float  lw1[4096], lw2[4096];
  __shared__ double hdw[4][64];
  for (int i=t; i<4096; i+=256){ lw1[i]=le_w1[i]; lw2[i]=le_w2[i]; }
  __syncthreads();
  int NC2 = nc2G[q];
  double qwl = qwd_g[q*64+l];
  double swl = sqrt(log1p(exp((double)fw[l])) + 1e-9);
  double qq  = qqd_g[q];
  double lb1 = (double)le_b1[l], lb2 = (double)le_b2[l];
  for (int c = blockIdx.y*4 + w; c < NC2; c += 8){
    int jc = __builtin_amdgcn_readfirstlane(candjG[(size_t)q*NCAND + c]);
    const float* mrow = mi + (size_t)jc*64;   // wave-uniform -> s_load
    double b0=0,b1=0,b2=0,b3=0,b4=0,b5=0,b6=0,b7=0;
    #pragma unroll
    for (int d=0; d<64; d+=8){
      b0 = fma((double)mrow[d  ], (double)lw1[(d  )*64+l], b0);
      b1 = fma((double)mrow[d+1], (double)lw1[(d+1)*64+l], b1);
      b2 = fma((double)mrow[d+2], (double)lw1[(d+2)*64+l], b2);
      b3 = fma((double)mrow[d+3], (double)lw1[(d+3)*64+l], b3);
      b4 = fma((double)mrow[d+4], (double)lw1[(d+4)*64+l], b4);
      b5 = fma((double)mrow[d+5], (double)lw1[(d+5)*64+l], b5);
      b6 = fma((double)mrow[d+6], (double)lw1[(d+6)*64+l], b6);
      b7 = fma((double)mrow[d+7], (double)lw1[(d+7)*64+l], b7);
    }
    double h = (((b0+b1)+(b2+b3)) + ((b4+b5)+(b6+b7))) + lb1;
    h = h>0.0 ? h : 0.0;
    hdw[w][l] = h;   // wave-private; lockstep + lgkmcnt ordering suffice
    double c0=0,c1=0,c2=0,c3=0,c4=0,c5=0,c6=0,c7=0;
    #pragma unroll
    for (int d=0; d<64; d+=8){
      c0 = fma(hdw[w][d  ], (double)lw2[(d  )*64+l], c0);
      c1 = fma(hdw[w][d+1], (double)lw2[(d+1)*64+l], c1);
      c2 = fma(hdw[w][d+2], (double)lw2[(d+2)*64+l], c2);
      c3 = fma(hdw[w][d+3], (double)lw2[(d+3)*64+l], c3);
      c4 = fma(hdw[w][d+4], (double)lw2[(d+4)*64+l], c4);
      c5 = fma(hdw[w][d+5], (double)lw2[(d+5)*64+l], c5);
      c6 = fma(hdw[w][d+6], (double)lw2[(d+6)*64+l], c6);
      c7 = fma(hdw[w][d+7], (double)lw2[(d+7)*64+l], c7);
    }
    double o  = (((c0+c1)+(c2+c3)) + ((c4+c5)+(c6+c7))) + lb2;
    double mw = o * swl;
    double sc = wave_sum_d(mw*(mw - 2.0*qwl));
    if (l==0) cd2G[(size_t)q*NCAND + c] = qq + sc;
  }
}

// ---------------- K4_fin: f32-quantized select (raw desc, idx asc) -> softmax/blend/refine
__global__ __launch_bounds__(64) void k4_fin(
    const int* __restrict__ candjG, const int* __restrict__ nc2G,
    const double* __restrict__ cd2G,
    const double* __restrict__ ggd_g, const double* __restrict__ gpd_g,
    const float* __restrict__ mt, const float* __restrict__ itp,
    const float* __restrict__ rw1, const float* __restrict__ rb1,
    const float* __restrict__ rw2, const float* __restrict__ rb2,
    float* __restrict__ out)
{
  int l = threadIdx.x, q = blockIdx.x;
  __shared__ float  selr[16];
  __shared__ int    selj[16];
  __shared__ double hh[32];
  int NC2 = nc2G[q];
  {
    float e32  = (float)exp((double)itp[0]);
    float sp32 = (float)log1p((double)e32);
    float t32  = __fadd_rn(sp32, 1e-9f);
    float dn32 = __fadd_rn(t32, 1e-9f);
    double denom = (double)dn32;
    float r0=-2.f, r1=-2.f; int j0=0x7fffffff, j1=0x7fffffff;
    if (l < NC2){
      double d2 = cd2G[(size_t)q*NCAND + l]; if (d2 < 0.0) d2 = 0.0;
      float ratio32 = (float)(d2 / denom);
      r0 = (float)exp(-(double)ratio32);
      j0 = candjG[(size_t)q*NCAND + l];
    }
    if (l+64 < NC2){
      double d2 = cd2G[(size_t)q*NCAND + l+64]; if (d2 < 0.0) d2 = 0.0;
      float ratio32 = (float)(d2 / denom);
      r1 = (float)exp(-(double)ratio32);
      j1 = candjG[(size_t)q*NCAND + l+64];
    }
    bool u0=false, u1=false;
    for (int it=0; it<16; it++){
      float a0 = u0 ? -2.f : r0;
      float a1 = u1 ? -2.f : r1;
      float v; int j; int p;
      if (a0 > a1 || (a0 == a1 && j0 <= j1)) { v=a0; j=j0; p=l*2; }
      else                                   { v=a1; j=j1; p=l*2+1; }
      wave_argmax3(v, j, p);
      if ((p>>1) == l){ if (p&1) u1=true; else u0=true; }
      if (l == it){ selr[it]=v; selj[it]=j; }
    }
  }
  __syncthreads();
  double raw = (l<16) ? (double)selr[l] : -1.0e300;
  double mv = raw;
  #pragma unroll
  for (int o=32;o;o>>=1){ double ov = __shfl_xor(mv,o,64); mv = ov>mv?ov:mv; }
  double e  = (l<16) ? exp(raw - mv) : 0.0;
  double se = wave_sum_d(e);
  double wgt = e / se;
  double lp[8] = {0,0,0,0,0,0,0,0};
  if (l < 16){
    const float* tr = mt + (size_t)selj[l]*8;
    #pragma unroll
    for (int tt=0; tt<8; tt++) lp[tt] = wgt * (double)tr[tt];
  }
  #pragma unroll
  for (int tt=0; tt<8; tt++) lp[tt] = wave_sum_d(lp[tt]);
  double g = ggd_g[q];
  double bl[8];
  #pragma unroll
  for (int tt=0; tt<8; tt++) bl[tt] = g*lp[tt] + (1.0-g)*gpd_g[q*8+tt];
  if (l < 32){
    double a = (double)rb1[l];
    #pragma unroll
    for (int tt=0; tt<8; tt++) a = fma(bl[tt], (double)rw1[tt*32+l], a);
    hh[l] = a>0.0?a:0.0;
  }
  __syncthreads();
  if (l < 8){
    double a = (double)rb2[l];
    #pragma unroll
    for (int i=0; i<32; i++) a = fma(hh[i], (double)rw2[i*8+l], a);
    out[q*8+l] = (float)a;
  }
}

extern "C" void kernel_launch(void* const* d_in, const int* in_sizes, int n_in,
                              void* d_out, int out_size, void* d_ws, size_t ws_size,
                              hipStream_t stream)
{
  const float* x     = (const float*)d_in[0];
  const float* mi    = (const float*)d_in[1];
  const float* mt    = (const float*)d_in[2];
  const float* le_w1 = (const float*)d_in[3];
  const float* le_b1 = (const float*)d_in[4];
  const float* le_w2 = (const float*)d_in[5];
  const float* le_b2 = (const float*)d_in[6];
  const float* fw    = (const float*)d_in[7];
  const float* itp   = (const float*)d_in[8];
  const float* ge_w1 = (const float*)d_in[9];
  const float* ge_b1 = (const float*)d_in[10];
  const float* ge_w2 = (const float*)d_in[11];
  const float* ge_b2 = (const float*)d_in[12];
  const float* ge_w3 = (const float*)d_in[13];
  const float* ge_b3 = (const float*)d_in[14];
  const float* gr_w1 = (const float*)d_in[15];
  const float* gr_b1 = (const float*)d_in[16];
  const float* gr_w2 = (const float*)d_in[17];
  const float* gr_b2 = (const float*)d_in[18];
  const float* ga_w1 = (const float*)d_in[19];
  const float* ga_b1 = (const float*)d_in[20];
  const float* ga_w2 = (const float*)d_in[21];
  const float* ga_b2 = (const float*)d_in[22];
  const float* rh_w1 = (const float*)d_in[23];
  const float* rh_b1 = (const float*)d_in[24];
  const float* rh_w2 = (const float*)d_in[25];
  const float* rh_b2 = (const float*)d_in[26];

  double* dws = (double*)d_ws;
  double* qwd = dws;                                // 1024*64
  double* qqd = qwd + (size_t)1024*64;              // 1024
  double* ggd = qqd + 1024;                         // 1024
  double* gpd = ggd + 1024;                         // 8192
  double* cd2G= gpd + 8192;                         // 1024*128
  float*  fws = (float*)(cd2G + (size_t)1024*128);
  float* mwT = fws;                                 // 64*NP
  float* mm  = mwT + (size_t)64*NP;                 // NP
  float* qwf = mm  + NP;                            // 1024*64
  float* tau = qwf + (size_t)1024*64;               // 1024
  float* ssc = tau + 1024;                          // 1024*4096
  int*   qcnt= (int*)(ssc + (size_t)1024*4096);     // 1024
  float* qcv = (float*)(qcnt + 1024);               // 1024*QCAP
  int*   qci = (int*)(qcv + (size_t)1024*QCAP);     // 1024*QCAP
  int*   candjG = qci + (size_t)1024*QCAP;          // 1024*128
  int*   nc2G   = candjG + (size_t)1024*NCAND;      // 1024

  k1_mem    <<<dim3(NP/128), dim3(256), 0, stream>>>(mi, le_w1, le_b1, le_w2, le_b2, fw, mwT, mm);
  k2_query  <<<dim3(1024),   dim3(64),  0, stream>>>(x, le_w1, le_b1, le_w2, le_b2, fw,
                ge_w1, ge_b1, ge_w2, ge_b2, ge_w3, ge_b3,
                gr_w1, gr_b1, gr_w2, gr_b2,
                ga_w1, ga_b1, ga_w2, ga_b2,
                qwf, qwd, qqd, ggd, gpd, qcnt);
  k_tau     <<<dim3(64,4),   dim3(256), 0, stream>>>(mwT, mm, qwf, ssc);
  k_tau_sel <<<dim3(1024),   dim3(256), 0, stream>>>(ssc, tau);
  k3_main   <<<dim3(64,NJB), dim3(256), 0, stream>>>(mwT, mm, qwf, tau, qcnt, qcv, qci);
  k4_pre    <<<dim3(1024),   dim3(256), 0, stream>>>(qcnt, qcv, qci, candjG, nc2G);
  k4_emb    <<<dim3(1024,2), dim3(256), 0, stream>>>(candjG, nc2G, qwd, qqd, mi,
                le_w1, le_b1, le_w2, le_b2, fw, cd2G);
  k4_fin    <<<dim3(1024),   dim3(64),  0, stream>>>(candjG, nc2G, cd2G, ggd, gpd, mt, itp,
                rh_w1, rh_b1, rh_w2, rh_b2, (float*)d_out);
}